// Round 1
// 979.725 us; speedup vs baseline: 1.1523x; 1.1523x over previous
//
#include <hip/hip_runtime.h>
#include <math.h>

// AFNO2D: out = x + fuse_w @ (x + irfft2(masked_delta))
// masked_delta = (softshrink(W2*gelu(W1*Z+b1)+b2) - Z) on modes [0:64, 0:33].
// Only the 64x33 masked modes are transformed (irfft2(rfft2(x)) == x).
// DFTs: per-thread twiddle rotation in registers. Conv: bf16 MFMA GEMM.
//
// Workspace layout (bytes), peak 168,820,736:
//   zm    @ 0          : B*C*64*33 float2  = 34,603,008  (Z modes, then delta)
//   hbuf  @ 34,603,008 : B*C*64*33 float2  = 34,603,008  (MLP hidden; dead after mlp2)
//   zwg   @ 34,603,008 : B*C*128*33 float2 = 69,206,016  (dead after fwd2; temporal overlap ok)
//   yy_bf @ 34,603,008 : B*C*128*128 bf16  = 67,108,864  (y = x + D, bf16; dead after k_tr)
//   yy_t  @101,711,872 : B*16384*512 bf16  = 67,108,864  (y transposed [b][p][c])
//   fw_bf @ 34,603,008 : 512*512 bf16      = 524,288     (written after k_tr; yy_bf dead)

#define LAMB 0.01f
#define TWO_PI_OVER_128 0.049087385212340517f

typedef __attribute__((ext_vector_type(8))) short s8bf;           // 8 bf16 (4 VGPRs)
typedef __attribute__((ext_vector_type(8))) unsigned short us8;
typedef __attribute__((ext_vector_type(4))) float f32x4;

static __device__ __forceinline__ float gelu_exact(float v) {
    return 0.5f * v * (1.0f + erff(v * 0.7071067811865475f));
}
static __device__ __forceinline__ float softshrink01(float v) {
    float a = fabsf(v) - LAMB;
    a = a > 0.0f ? a : 0.0f;
    return v >= 0.0f ? a : -a;
}
static __device__ __forceinline__ unsigned short f2bf(float f) {
    union { float f; unsigned int u; } v; v.f = f;
    unsigned int r = v.u + 0x7FFFu + ((v.u >> 16) & 1u);   // RNE
    return (unsigned short)(r >> 16);
}

// ---------------------------------------------------------------------------
// Kernel 1a: W-axis DFT (128 real -> 33 complex), ortho 1/128.
// ---------------------------------------------------------------------------
__global__ __launch_bounds__(256) void k_fwd1(const float* __restrict__ x,
                                              float2* __restrict__ zwg) {
    __shared__ float xs[64][132];
    const int bc   = blockIdx.x;
    const int half = blockIdx.y;
    const int tid  = threadIdx.x;
    const int rg = tid >> 4;
    const int kg = tid & 15;

    const float* xim = x + (size_t)bc * 16384 + half * 8192;
    for (int i = tid; i < 2048; i += 256) {
        int row = i >> 5, f4 = i & 31;
        *(float4*)&xs[row][f4 * 4] = *(const float4*)&xim[row * 128 + f4 * 4];
    }
    __syncthreads();

    float2* zrow = zwg + (size_t)bc * 4224 + half * (64 * 33);
    for (int t = 0; t < 3; ++t) {
        if (t == 2 && kg != 0) break;
        const int k = (t < 2) ? (kg + 16 * t) : 32;
        float sc, ss;
        sincosf((float)k * TWO_PI_OVER_128, &ss, &sc);
        float c = 1.0f, s = 0.0f;
        float cr[4] = {0.f, 0.f, 0.f, 0.f}, ci[4] = {0.f, 0.f, 0.f, 0.f};
        for (int w = 0; w < 128; ++w) {
            float xv0 = xs[rg * 4 + 0][w];
            float xv1 = xs[rg * 4 + 1][w];
            float xv2 = xs[rg * 4 + 2][w];
            float xv3 = xs[rg * 4 + 3][w];
            cr[0] += xv0 * c; ci[0] -= xv0 * s;
            cr[1] += xv1 * c; ci[1] -= xv1 * s;
            cr[2] += xv2 * c; ci[2] -= xv2 * s;
            cr[3] += xv3 * c; ci[3] -= xv3 * s;
            float cn = c * sc - s * ss;
            s = s * sc + c * ss;
            c = cn;
        }
        #pragma unroll
        for (int i = 0; i < 4; ++i)
            zrow[(rg * 4 + i) * 33 + k] =
                make_float2(cr[i] * 0.0078125f, ci[i] * 0.0078125f);
    }
}

// ---------------------------------------------------------------------------
// Kernel 1b: H-axis DFT (128 -> 64 rows) on 33 k-columns.
// ---------------------------------------------------------------------------
__global__ __launch_bounds__(256) void k_fwd2(const float2* __restrict__ zwg,
                                              float2* __restrict__ zm) {
    __shared__ float2 zw[128][34];
    const int bc  = blockIdx.x;
    const int tid = threadIdx.x;

    const float2* src = zwg + (size_t)bc * 4224;
    for (int t = tid; t < 4224; t += 256) {
        int h = t / 33;
        int k = t - h * 33;
        zw[h][k] = src[t];
    }
    __syncthreads();

    const int r  = tid >> 2;
    const int kq = tid & 3;
    float sc, ss;
    sincosf((float)r * TWO_PI_OVER_128, &ss, &sc);
    float c = 1.0f, s = 0.0f;
    float ar[8] = {}, ai[8] = {};
    float tr = 0.f, tiv = 0.f;

    for (int h = 0; h < 128; ++h) {
        const float4* rowp = (const float4*)&zw[h][kq * 8];
        float4 v0 = rowp[0], v1 = rowp[1], v2 = rowp[2], v3 = rowp[3];
        ar[0] += v0.x * c + v0.y * s;  ai[0] += v0.y * c - v0.x * s;
        ar[1] += v0.z * c + v0.w * s;  ai[1] += v0.w * c - v0.z * s;
        ar[2] += v1.x * c + v1.y * s;  ai[2] += v1.y * c - v1.x * s;
        ar[3] += v1.z * c + v1.w * s;  ai[3] += v1.w * c - v1.z * s;
        ar[4] += v2.x * c + v2.y * s;  ai[4] += v2.y * c - v2.x * s;
        ar[5] += v2.z * c + v2.w * s;  ai[5] += v2.w * c - v2.z * s;
        ar[6] += v3.x * c + v3.y * s;  ai[6] += v3.y * c - v3.x * s;
        ar[7] += v3.z * c + v3.w * s;  ai[7] += v3.w * c - v3.z * s;
        if (kq == 0) {
            float2 v = zw[h][32];
            tr  += v.x * c + v.y * s;
            tiv += v.y * c - v.x * s;
        }
        float cn = c * sc - s * ss;
        s = s * sc + c * ss;
        c = cn;
    }

    float2* zrow = zm + (size_t)bc * 2112 + r * 33;
    #pragma unroll
    for (int j = 0; j < 8; ++j) zrow[kq * 8 + j] = make_float2(ar[j], ai[j]);
    if (kq == 0) zrow[32] = make_float2(tr, tiv);
}

// ---------------------------------------------------------------------------
// Kernel 2a: MLP layer 1 + exact GELU -> hbuf.
// ---------------------------------------------------------------------------
__global__ __launch_bounds__(256) void k_mlp1(const float* __restrict__ w1r_g,
                                              const float* __restrict__ w1i_g,
                                              const float* __restrict__ b1r_g,
                                              const float* __restrict__ b1i_g,
                                              const float2* __restrict__ zm,
                                              float2* __restrict__ hbuf) {
    __shared__ float w1r[4096], w1i[4096];
    __shared__ float b1r[64], b1i[64];
    __shared__ float zr[4][64], zi[4][64];
    const int chunk = blockIdx.x;
    const int nb    = blockIdx.y;
    const int b     = blockIdx.z;
    const int tid   = threadIdx.x;
    const int lane  = tid & 63;
    const int q     = tid >> 6;

    for (int t = tid; t < 4096; t += 256) {
        w1r[t] = w1r_g[nb * 4096 + t];
        w1i[t] = w1i_g[nb * 4096 + t];
    }
    if (tid < 64) { b1r[tid] = b1r_g[nb * 64 + tid]; b1i[tid] = b1i_g[nb * 64 + tid]; }
    __syncthreads();

    for (int g = 0; g < 16; ++g) {
        int pos = chunk * 64 + g * 4 + q;
        int r = pos / 33;
        int k = pos - r * 33;
        size_t idx = ((size_t)((b * 512 + nb * 64 + lane) * 64 + r)) * 33 + k;
        float2 z = zm[idx];
        zr[q][lane] = z.x; zi[q][lane] = z.y;
        __syncthreads();
        float yr = b1r[lane], yi = b1i[lane];
        #pragma unroll 16
        for (int i = 0; i < 64; ++i) {
            float arv = zr[q][i], aiv = zi[q][i];
            float wr = w1r[i * 64 + lane], wi = w1i[i * 64 + lane];
            yr += arv * wr - aiv * wi;
            yi += arv * wi + aiv * wr;
        }
        hbuf[idx] = make_float2(gelu_exact(yr), gelu_exact(yi));
        __syncthreads();
    }
}

// ---------------------------------------------------------------------------
// Kernel 2b: MLP layer 2 + softshrink; zm <- delta = softshrink(y2) - z
// ---------------------------------------------------------------------------
__global__ __launch_bounds__(256) void k_mlp2(const float* __restrict__ w2r_g,
                                              const float* __restrict__ w2i_g,
                                              const float* __restrict__ b2r_g,
                                              const float* __restrict__ b2i_g,
                                              const float2* __restrict__ hbuf,
                                              float2* __restrict__ zm) {
    __shared__ float w2r[4096], w2i[4096];
    __shared__ float b2r[64], b2i[64];
    __shared__ float hr[4][64], hi[4][64];
    const int chunk = blockIdx.x;
    const int nb    = blockIdx.y;
    const int b     = blockIdx.z;
    const int tid   = threadIdx.x;
    const int lane  = tid & 63;
    const int q     = tid >> 6;

    for (int t = tid; t < 4096; t += 256) {
        w2r[t] = w2r_g[nb * 4096 + t];
        w2i[t] = w2i_g[nb * 4096 + t];
    }
    if (tid < 64) { b2r[tid] = b2r_g[nb * 64 + tid]; b2i[tid] = b2i_g[nb * 64 + tid]; }
    __syncthreads();

    for (int g = 0; g < 16; ++g) {
        int pos = chunk * 64 + g * 4 + q;
        int r = pos / 33;
        int k = pos - r * 33;
        size_t idx = ((size_t)((b * 512 + nb * 64 + lane) * 64 + r)) * 33 + k;
        float2 h = hbuf[idx];
        hr[q][lane] = h.x; hi[q][lane] = h.y;
        __syncthreads();
        float yr = b2r[lane], yi = b2i[lane];
        #pragma unroll 16
        for (int i = 0; i < 64; ++i) {
            float arv = hr[q][i], aiv = hi[q][i];
            float wr = w2r[i * 64 + lane], wi = w2i[i * 64 + lane];
            yr += arv * wr - aiv * wi;
            yi += arv * wi + aiv * wr;
        }
        float2 z = zm[idx];
        zm[idx] = make_float2(softshrink01(yr) - z.x, softshrink01(yi) - z.y);
        __syncthreads();
    }
}

// ---------------------------------------------------------------------------
// Kernel 3: inverse per (b,c); writes yy_bf = bf16(x + D).
// Radix-2 symmetry in both phases (half the FMAs + half the LDS reads of the
// naive version):
//   phase 1: T[h] = E + O, T[h+64] = E - O, E/O = even/odd-r partial sums.
//   phase 2: columns (w, w+64) share |cos/sin| up to (-1)^k -> parity split.
// Single aliased LDS buffer S[128][34] (34.8 KB): delta occupies rows 0..63
// during phase 1 (accumulated fully in registers), then T overwrites it.
// LDS 51.7 KB -> 34.8 KB raises occupancy 3 -> 4 blocks/CU.
// ---------------------------------------------------------------------------
__global__ __launch_bounds__(256) void k_inv(const float2* __restrict__ zm,
                                             const float* __restrict__ x,
                                             unsigned short* __restrict__ yb) {
    __shared__ float2 S[128][34];   // phase 0/1: D in rows 0..63; phase 2: T at col k+1
    const int bc  = blockIdx.x;
    const int tid = threadIdx.x;

    // Load delta D[64][33] into S rows 0..63 (row-padded to 34 for b128 align).
    const float2* src = zm + (size_t)bc * 2112;
    for (int t = tid; t < 2112; t += 256) {
        int r = t / 33;
        int k = t - r * 33;
        S[r][k] = src[t];
    }
    __syncthreads();

    // ---- phase 1: T[h][k] = sum_r D[r][k] e^{+i 2pi h r / 128}, r-parity split.
    {
        const int h  = tid & 63;        // h in [0,64); also produces row h+64
        const int kg = tid >> 6;        // 0..3 -> k in [8kg, 8kg+8); kg==3 adds k=32
        const int k0 = kg * 8;
        float sc, ss;
        sincosf((float)h * TWO_PI_OVER_128, &ss, &sc);
        float c = 1.0f, s = 0.0f;       // angle h*r, starting r = 0
        float er[9] = {}, ei[9] = {}, orr[9] = {}, oi[9] = {};

        for (int r = 0; r < 64; r += 2) {
            // even r -> E
            const float4* p0 = (const float4*)&S[r][k0];
            #pragma unroll
            for (int j = 0; j < 4; ++j) {
                float4 v = p0[j];
                er[2*j]   += v.x * c - v.y * s;
                ei[2*j]   += v.y * c + v.x * s;
                er[2*j+1] += v.z * c - v.w * s;
                ei[2*j+1] += v.w * c + v.z * s;
            }
            if (kg == 3) {
                float2 v = S[r][32];
                er[8] += v.x * c - v.y * s;
                ei[8] += v.y * c + v.x * s;
            }
            float cn = c * sc - s * ss; s = s * sc + c * ss; c = cn;
            // odd r -> O
            const float4* p1 = (const float4*)&S[r + 1][k0];
            #pragma unroll
            for (int j = 0; j < 4; ++j) {
                float4 v = p1[j];
                orr[2*j]   += v.x * c - v.y * s;
                oi[2*j]    += v.y * c + v.x * s;
                orr[2*j+1] += v.z * c - v.w * s;
                oi[2*j+1]  += v.w * c + v.z * s;
            }
            if (kg == 3) {
                float2 v = S[r + 1][32];
                orr[8] += v.x * c - v.y * s;
                oi[8]  += v.y * c + v.x * s;
            }
            cn = c * sc - s * ss; s = s * sc + c * ss; c = cn;
        }
        __syncthreads();                // all reads of D complete; S reusable
        #pragma unroll
        for (int j = 0; j < 8; ++j) {
            int col = k0 + j + 1;       // T_k stored at col k+1 (b128-aligned reads)
            S[h][col]      = make_float2(er[j] + orr[j], ei[j] + oi[j]);
            S[h + 64][col] = make_float2(er[j] - orr[j], ei[j] - oi[j]);
        }
        if (kg == 3) {
            S[h][33]      = make_float2(er[8] + orr[8], ei[8] + oi[8]);
            S[h + 64][33] = make_float2(er[8] - orr[8], ei[8] - oi[8]);
        }
    }
    __syncthreads();

    // ---- phase 2: y[h][w] = (1/64)[0.5 A0 + sum_{k=1..32} (A_k cos - B_k sin)]
    // columns w and w+64 from one k-pass via k-parity accumulators.
    {
        const int w    = tid & 63;      // w in [0,64); also produces column w+64
        const int quad = tid >> 6;      // rows [32*quad, 32*quad+32)
        float sc, ss;
        sincosf((float)w * TWO_PI_OVER_128, &ss, &sc);
        const size_t base = (size_t)bc * 16384;
        #pragma unroll
        for (int ch = 0; ch < 4; ++ch) {
            const int h0 = quad * 32 + ch * 8;
            float pe[8], po[8], qe[8], qo[8];
            #pragma unroll
            for (int i = 0; i < 8; ++i) {
                pe[i] = 0.5f * S[h0 + i][1].x;   // k=0 term (even, sin=0)
                po[i] = 0.f; qe[i] = 0.f; qo[i] = 0.f;
            }
            float c = sc, s = ss;                // angle for k=1
            #pragma unroll
            for (int p = 0; p < 16; ++p) {
                float c2 = c * sc - s * ss;      // k = 2p+2
                float s2 = s * sc + c * ss;
                #pragma unroll
                for (int i = 0; i < 8; ++i) {
                    float4 v = *(const float4*)&S[h0 + i][2 + 2 * p]; // (A,B)_{2p+1},(A,B)_{2p+2}
                    po[i] += v.x * c;  qo[i] += v.y * s;
                    pe[i] += v.z * c2; qe[i] += v.w * s2;
                }
                c = c2 * sc - s2 * ss;           // advance to k = 2p+3
                s = s2 * sc + c2 * ss;
            }
            #pragma unroll
            for (int i = 0; i < 8; ++i) {
                float y1 = (pe[i] + po[i] - qe[i] - qo[i]) * 0.015625f;
                float y2 = (pe[i] - po[i] - qe[i] + qo[i]) * 0.015625f;
                size_t i1 = base + (size_t)(h0 + i) * 128 + w;
                yb[i1]      = f2bf(x[i1] + y1);
                yb[i1 + 64] = f2bf(x[i1 + 64] + y2);
            }
        }
    }
}

// ---------------------------------------------------------------------------
// Kernel 3b: transpose yy_bf[b][c][p] -> yy_t[b][p][c] (bf16), 64x64 tiles.
// ---------------------------------------------------------------------------
__global__ __launch_bounds__(256) void k_tr(const unsigned short* __restrict__ yb,
                                            unsigned short* __restrict__ yt) {
    __shared__ float ts[64][65];   // [p][c]
    const int p0 = blockIdx.x * 64;
    const int c0 = blockIdx.y * 64;
    const int b  = blockIdx.z;
    const int t  = threadIdx.x;
    const int lane = t & 63;

    const unsigned short* src = yb + (((size_t)(b * 512 + c0 + lane)) << 14) + p0;
    #pragma unroll
    for (int cc = 0; cc < 2; ++cc) {
        int ch = (t >> 6) * 2 + cc;          // p-chunk 0..7
        us8 v = *(const us8*)&src[ch * 8];
        #pragma unroll
        for (int j = 0; j < 8; ++j)
            ts[ch * 8 + j][lane] = __uint_as_float((unsigned)v[j] << 16);
    }
    __syncthreads();

    const int pr   = t >> 2;
    const int coff = (t & 3) * 16;
    us8 o0v, o1v;
    #pragma unroll
    for (int i = 0; i < 8; ++i) o0v[i] = f2bf(ts[pr][coff + i]);
    #pragma unroll
    for (int i = 0; i < 8; ++i) o1v[i] = f2bf(ts[pr][coff + 8 + i]);
    unsigned short* dst = yt + ((size_t)(b * 16384 + p0 + pr)) * 512 + c0 + coff;
    *(us8*)&dst[0] = o0v;
    *(us8*)&dst[8] = o1v;
}

// ---------------------------------------------------------------------------
// Kernel 3c: fw fp32 -> bf16 (row-major [o][c] unchanged).
// ---------------------------------------------------------------------------
__global__ __launch_bounds__(256) void k_prep(const float* __restrict__ fw,
                                              unsigned short* __restrict__ fb) {
    int i = (blockIdx.x * 256 + threadIdx.x) * 4;
    float4 v = *(const float4*)&fw[i];
    ushort4 o;
    o.x = f2bf(v.x); o.y = f2bf(v.y); o.z = f2bf(v.z); o.w = f2bf(v.w);
    *(ushort4*)&fb[i] = o;
}

// ---------------------------------------------------------------------------
// Kernel 4: MFMA conv GEMM. out[b][o][p] = x[b][o][p] + sum_c fb[o][c]*yt[b][p][c]
// 128x128 tile, BK=32, 4 waves (2x2 of 64x64), mfma_f32_16x16x32_bf16.
// LDS rows padded to 40 bf16 (80 B) -> b128 frag reads bank-uniform.
// Fragment maps (m89/m91/m120-verified): A: m=lane&15,k=quad*8+j;
// B: n=lane&15,k=quad*8+j; C/D: col(n)=lane&15, row(m)=quad*4+reg.
// ---------------------------------------------------------------------------
__global__ __launch_bounds__(256) void k_gemm(const unsigned short* __restrict__ fb,
                                              const unsigned short* __restrict__ yt,
                                              const float* __restrict__ x,
                                              float* __restrict__ out) {
    __shared__ short Al[128 * 40];
    __shared__ short Bl[128 * 40];
    const int p0  = blockIdx.x * 128;
    const int o0  = blockIdx.y * 128;
    const int b   = blockIdx.z;
    const int tid = threadIdx.x;
    const int lane = tid & 63;
    const int w    = tid >> 6;
    const int wo = (w >> 1) * 64, wp = (w & 1) * 64;

    f32x4 acc[4][4];
    #pragma unroll
    for (int i = 0; i < 4; ++i)
        #pragma unroll
        for (int j = 0; j < 4; ++j)
            acc[i][j] = (f32x4){0.f, 0.f, 0.f, 0.f};

    const int m15 = lane & 15, quad = lane >> 4;

    for (int kc = 0; kc < 512; kc += 32) {
        __syncthreads();
        #pragma unroll
        for (int cc = 0; cc < 2; ++cc) {
            int ch = tid + cc * 256;          // 0..511
            int r  = ch >> 2;                 // row 0..127
            int pt = ch & 3;                  // 8-bf16 part
            *(s8bf*)&Al[r * 40 + pt * 8] =
                *(const s8bf*)&fb[(size_t)(o0 + r) * 512 + kc + pt * 8];
            *(s8bf*)&Bl[r * 40 + pt * 8] =
                *(const s8bf*)&yt[((size_t)(b * 16384 + p0 + r)) * 512 + kc + pt * 8];
        }
        __syncthreads();

        s8bf af[4], bfr[4];
        #pragma unroll
        for (int i = 0; i < 4; ++i) {
            af[i]  = *(const s8bf*)&Al[(wo + i * 16 + m15) * 40 + quad * 8];
            bfr[i] = *(const s8bf*)&Bl[(wp + i * 16 + m15) * 40 + quad * 8];
        }
        #pragma unroll
        for (int mi = 0; mi < 4; ++mi)
            #pragma unroll
            for (int ni = 0; ni < 4; ++ni)
                acc[mi][ni] = __builtin_amdgcn_mfma_f32_16x16x32_bf16(
                    af[mi], bfr[ni], acc[mi][ni], 0, 0, 0);
    }

    #pragma unroll
    for (int mi = 0; mi < 4; ++mi) {
        #pragma unroll
        for (int ni = 0; ni < 4; ++ni) {
            #pragma unroll
            for (int r = 0; r < 4; ++r) {
                int o = o0 + wo + mi * 16 + quad * 4 + r;
                int p = p0 + wp + ni * 16 + m15;
                size_t idx = (((size_t)(b * 512 + o)) << 14) + p;
                out[idx] = x[idx] + acc[mi][ni][r];
            }
        }
    }
}

// ---------------------------------------------------------------------------
extern "C" void kernel_launch(void* const* d_in, const int* in_sizes, int n_in,
                              void* d_out, int out_size, void* d_ws, size_t ws_size,
                              hipStream_t stream) {
    const float* x   = (const float*)d_in[0];
    const float* w1r = (const float*)d_in[1];
    const float* w1i = (const float*)d_in[2];
    const float* b1r = (const float*)d_in[3];
    const float* b1i = (const float*)d_in[4];
    const float* w2r = (const float*)d_in[5];
    const float* w2i = (const float*)d_in[6];
    const float* b2r = (const float*)d_in[7];
    const float* b2i = (const float*)d_in[8];
    const float* fw  = (const float*)d_in[9];
    float* out = (float*)d_out;

    char* ws = (char*)d_ws;
    float2* zm          = (float2*)ws;                         // [0, 34.6MB)
    float2* hbuf        = (float2*)(ws + 34603008);            // dead after mlp2
    float2* zwg         = (float2*)(ws + 34603008);            // dead after fwd2
    unsigned short* ybf = (unsigned short*)(ws + 34603008);    // dead after k_tr
    unsigned short* yt  = (unsigned short*)(ws + 101711872);   // [101.7MB, 168.8MB)
    unsigned short* fb  = (unsigned short*)(ws + 34603008);    // written after k_tr

    k_fwd1<<<dim3(2048, 2), 256, 0, stream>>>(x, zwg);
    k_fwd2<<<2048, 256, 0, stream>>>(zwg, zm);
    k_mlp1<<<dim3(33, 8, 4), 256, 0, stream>>>(w1r, w1i, b1r, b1i, zm, hbuf);
    k_mlp2<<<dim3(33, 8, 4), 256, 0, stream>>>(w2r, w2i, b2r, b2i, hbuf, zm);
    k_inv<<<2048, 256, 0, stream>>>(zm, x, ybf);
    k_tr<<<dim3(256, 8, 4), 256, 0, stream>>>(ybf, yt);
    k_prep<<<256, 256, 0, stream>>>(fw, fb);
    k_gemm<<<dim3(128, 4, 4), 256, 0, stream>>>(fb, yt, x, out);
}

// Round 2
// 837.960 us; speedup vs baseline: 1.3472x; 1.1692x over previous
//
#include <hip/hip_runtime.h>
#include <math.h>

// AFNO2D: out = x + fuse_w @ (x + irfft2(masked_delta))
// masked_delta = (softshrink(W2*gelu(W1*Z+b1)+b2) - Z) on modes [0:64, 0:33].
// Only the 64x33 masked modes are transformed (irfft2(rfft2(x)) == x).
// DFTs: per-thread twiddle rotation in registers, radix-2 parity split on the
// 128-sample axis (halves FMAs). Conv: bf16 MFMA GEMM.
//
// Workspace layout (bytes), peak 168,820,736:
//   zm    @ 0          : B*C*64*33 float2  = 34,603,008  (Z modes, then delta)
//   hbuf  @ 34,603,008 : B*C*64*33 float2  = 34,603,008  (MLP hidden; dead after mlp2)
//   zwg   @ 34,603,008 : B*C*128*33 float2 = 69,206,016  (dead after fwd2; temporal overlap ok)
//   yy_bf @ 34,603,008 : B*C*128*128 bf16  = 67,108,864  (y = x + D, bf16; dead after k_tr)
//   yy_t  @101,711,872 : B*16384*512 bf16  = 67,108,864  (y transposed [b][p][c])
//   fw_bf @ 34,603,008 : 512*512 bf16      = 524,288     (written after k_tr; yy_bf dead)

#define LAMB 0.01f
#define TWO_PI_OVER_128 0.049087385212340517f

typedef __attribute__((ext_vector_type(8))) short s8bf;           // 8 bf16 (4 VGPRs)
typedef __attribute__((ext_vector_type(8))) unsigned short us8;
typedef __attribute__((ext_vector_type(4))) float f32x4;

static __device__ __forceinline__ float gelu_exact(float v) {
    return 0.5f * v * (1.0f + erff(v * 0.7071067811865475f));
}
static __device__ __forceinline__ float softshrink01(float v) {
    float a = fabsf(v) - LAMB;
    a = a > 0.0f ? a : 0.0f;
    return v >= 0.0f ? a : -a;
}
static __device__ __forceinline__ unsigned short f2bf(float f) {
    union { float f; unsigned int u; } v; v.f = f;
    unsigned int r = v.u + 0x7FFFu + ((v.u >> 16) & 1u);   // RNE
    return (unsigned short)(r >> 16);
}

// ---------------------------------------------------------------------------
// Kernel 1a: W-axis DFT (128 real -> 33 complex), ortho 1/128.
// Radix-2: X_k = sum_{w<64} (x_w + (-1)^k x_{w+64}) e^{-i 2pi w k/128}.
// u/v stored TRANSPOSED [w][row] so a thread's 4-row fragment is one b128.
// vt offset +16 words -> u-lanes and v-lanes hit disjoint bank groups.
// ---------------------------------------------------------------------------
__global__ __launch_bounds__(256) void k_fwd1(const float* __restrict__ x,
                                              float2* __restrict__ zwg) {
    __shared__ float UV[2 * 64 * 68 + 16];
    float* ut = UV;                       // [w][68] rows 0..63, w<64
    float* vt = UV + 64 * 68 + 16;        // +16 words: bank group +16
    const int bc   = blockIdx.x;
    const int half = blockIdx.y;
    const int tid  = threadIdx.x;
    const int rg = tid >> 4;              // row group 0..15 (rows rg*4..rg*4+3)
    const int kg = tid & 15;

    const float* xim = x + (size_t)bc * 16384 + half * 8192;

    // Load + parity combine + transpose: thread = (rows rg*4..+3) x (w kg*4..+3).
    {
        const int r0 = rg * 4, w0 = kg * 4;
        float av[4][4], bv[4][4];
        #pragma unroll
        for (int i = 0; i < 4; ++i) {
            float4 a = *(const float4*)&xim[(r0 + i) * 128 + w0];
            float4 b = *(const float4*)&xim[(r0 + i) * 128 + w0 + 64];
            av[i][0] = a.x; av[i][1] = a.y; av[i][2] = a.z; av[i][3] = a.w;
            bv[i][0] = b.x; bv[i][1] = b.y; bv[i][2] = b.z; bv[i][3] = b.w;
        }
        #pragma unroll
        for (int j = 0; j < 4; ++j) {
            float4 u4, v4;
            u4.x = av[0][j] + bv[0][j]; v4.x = av[0][j] - bv[0][j];
            u4.y = av[1][j] + bv[1][j]; v4.y = av[1][j] - bv[1][j];
            u4.z = av[2][j] + bv[2][j]; v4.z = av[2][j] - bv[2][j];
            u4.w = av[3][j] + bv[3][j]; v4.w = av[3][j] - bv[3][j];
            *(float4*)&ut[(w0 + j) * 68 + r0] = u4;
            *(float4*)&vt[(w0 + j) * 68 + r0] = v4;
        }
    }
    __syncthreads();

    float2* zrow = zwg + (size_t)bc * 4224 + half * 2112;
    for (int t = 0; t < 3; ++t) {
        if (t == 2 && kg != 0) break;
        const int k = (t < 2) ? (kg + 16 * t) : 32;
        const float* src = (k & 1) ? vt : ut;
        float sc, ss;
        sincosf((float)k * TWO_PI_OVER_128, &ss, &sc);
        float c = 1.0f, s = 0.0f;
        float cr[4] = {0.f, 0.f, 0.f, 0.f}, ci[4] = {0.f, 0.f, 0.f, 0.f};
        for (int w = 0; w < 64; ++w) {
            float4 xv = *(const float4*)&src[w * 68 + rg * 4];
            cr[0] += xv.x * c; ci[0] -= xv.x * s;
            cr[1] += xv.y * c; ci[1] -= xv.y * s;
            cr[2] += xv.z * c; ci[2] -= xv.z * s;
            cr[3] += xv.w * c; ci[3] -= xv.w * s;
            float cn = c * sc - s * ss;
            s = s * sc + c * ss;
            c = cn;
        }
        #pragma unroll
        for (int i = 0; i < 4; ++i)
            zrow[(rg * 4 + i) * 33 + k] =
                make_float2(cr[i] * 0.0078125f, ci[i] * 0.0078125f);
    }
}

// ---------------------------------------------------------------------------
// Kernel 1b: H-axis DFT (128 -> 64 rows) on 33 k-columns.
// Radix-2: Z2[r] = sum_{h<64} (zw[h] + (-1)^r zw[h+64]) e^{-i 2pi r h/128}.
// sv offset so its word base is +8 mod 32 vs su -> u/v lane halves stay at
// free 2-way bank aliasing.
// ---------------------------------------------------------------------------
__global__ __launch_bounds__(256) void k_fwd2(const float2* __restrict__ zwg,
                                              float2* __restrict__ zm) {
    __shared__ float2 UV2[2 * 64 * 34 + 4];
    float2* su = UV2;                     // [h][34], h<64
    float2* sv = UV2 + 64 * 34 + 4;       // word base +8 mod 32
    const int bc  = blockIdx.x;
    const int tid = threadIdx.x;

    const float2* src = zwg + (size_t)bc * 4224;
    for (int t = tid; t < 2112; t += 256) {
        int h = t / 33;
        int k = t - h * 33;
        float2 a = src[t];
        float2 b = src[t + 2112];
        su[h * 34 + k] = make_float2(a.x + b.x, a.y + b.y);
        sv[h * 34 + k] = make_float2(a.x - b.x, a.y - b.y);
    }
    __syncthreads();

    const int r  = tid >> 2;
    const int kq = tid & 3;
    const float2* zp = (r & 1) ? sv : su;
    float sc, ss;
    sincosf((float)r * TWO_PI_OVER_128, &ss, &sc);
    float c = 1.0f, s = 0.0f;
    float ar[8] = {}, ai[8] = {};
    float tr = 0.f, tiv = 0.f;

    for (int h = 0; h < 64; ++h) {
        const float4* rowp = (const float4*)&zp[h * 34 + kq * 8];
        float4 v0 = rowp[0], v1 = rowp[1], v2 = rowp[2], v3 = rowp[3];
        ar[0] += v0.x * c + v0.y * s;  ai[0] += v0.y * c - v0.x * s;
        ar[1] += v0.z * c + v0.w * s;  ai[1] += v0.w * c - v0.z * s;
        ar[2] += v1.x * c + v1.y * s;  ai[2] += v1.y * c - v1.x * s;
        ar[3] += v1.z * c + v1.w * s;  ai[3] += v1.w * c - v1.z * s;
        ar[4] += v2.x * c + v2.y * s;  ai[4] += v2.y * c - v2.x * s;
        ar[5] += v2.z * c + v2.w * s;  ai[5] += v2.w * c - v2.z * s;
        ar[6] += v3.x * c + v3.y * s;  ai[6] += v3.y * c - v3.x * s;
        ar[7] += v3.z * c + v3.w * s;  ai[7] += v3.w * c - v3.z * s;
        if (kq == 0) {
            float2 z = zp[h * 34 + 32];
            tr  += z.x * c + z.y * s;
            tiv += z.y * c - z.x * s;
        }
        float cn = c * sc - s * ss;
        s = s * sc + c * ss;
        c = cn;
    }

    float2* zrow = zm + (size_t)bc * 2112 + r * 33;
    #pragma unroll
    for (int j = 0; j < 8; ++j) zrow[kq * 8 + j] = make_float2(ar[j], ai[j]);
    if (kq == 0) zrow[32] = make_float2(tr, tiv);
}

// ---------------------------------------------------------------------------
// Kernel 2a: MLP layer 1 + exact GELU -> hbuf.
// ---------------------------------------------------------------------------
__global__ __launch_bounds__(256) void k_mlp1(const float* __restrict__ w1r_g,
                                              const float* __restrict__ w1i_g,
                                              const float* __restrict__ b1r_g,
                                              const float* __restrict__ b1i_g,
                                              const float2* __restrict__ zm,
                                              float2* __restrict__ hbuf) {
    __shared__ float w1r[4096], w1i[4096];
    __shared__ float b1r[64], b1i[64];
    __shared__ float zr[4][64], zi[4][64];
    const int chunk = blockIdx.x;
    const int nb    = blockIdx.y;
    const int b     = blockIdx.z;
    const int tid   = threadIdx.x;
    const int lane  = tid & 63;
    const int q     = tid >> 6;

    for (int t = tid; t < 4096; t += 256) {
        w1r[t] = w1r_g[nb * 4096 + t];
        w1i[t] = w1i_g[nb * 4096 + t];
    }
    if (tid < 64) { b1r[tid] = b1r_g[nb * 64 + tid]; b1i[tid] = b1i_g[nb * 64 + tid]; }
    __syncthreads();

    for (int g = 0; g < 16; ++g) {
        int pos = chunk * 64 + g * 4 + q;
        int r = pos / 33;
        int k = pos - r * 33;
        size_t idx = ((size_t)((b * 512 + nb * 64 + lane) * 64 + r)) * 33 + k;
        float2 z = zm[idx];
        zr[q][lane] = z.x; zi[q][lane] = z.y;
        __syncthreads();
        float yr = b1r[lane], yi = b1i[lane];
        #pragma unroll 16
        for (int i = 0; i < 64; ++i) {
            float arv = zr[q][i], aiv = zi[q][i];
            float wr = w1r[i * 64 + lane], wi = w1i[i * 64 + lane];
            yr += arv * wr - aiv * wi;
            yi += arv * wi + aiv * wr;
        }
        hbuf[idx] = make_float2(gelu_exact(yr), gelu_exact(yi));
        __syncthreads();
    }
}

// ---------------------------------------------------------------------------
// Kernel 2b: MLP layer 2 + softshrink; zm <- delta = softshrink(y2) - z
// ---------------------------------------------------------------------------
__global__ __launch_bounds__(256) void k_mlp2(const float* __restrict__ w2r_g,
                                              const float* __restrict__ w2i_g,
                                              const float* __restrict__ b2r_g,
                                              const float* __restrict__ b2i_g,
                                              const float2* __restrict__ hbuf,
                                              float2* __restrict__ zm) {
    __shared__ float w2r[4096], w2i[4096];
    __shared__ float b2r[64], b2i[64];
    __shared__ float hr[4][64], hi[4][64];
    const int chunk = blockIdx.x;
    const int nb    = blockIdx.y;
    const int b     = blockIdx.z;
    const int tid   = threadIdx.x;
    const int lane  = tid & 63;
    const int q     = tid >> 6;

    for (int t = tid; t < 4096; t += 256) {
        w2r[t] = w2r_g[nb * 4096 + t];
        w2i[t] = w2i_g[nb * 4096 + t];
    }
    if (tid < 64) { b2r[tid] = b2r_g[nb * 64 + tid]; b2i[tid] = b2i_g[nb * 64 + tid]; }
    __syncthreads();

    for (int g = 0; g < 16; ++g) {
        int pos = chunk * 64 + g * 4 + q;
        int r = pos / 33;
        int k = pos - r * 33;
        size_t idx = ((size_t)((b * 512 + nb * 64 + lane) * 64 + r)) * 33 + k;
        float2 h = hbuf[idx];
        hr[q][lane] = h.x; hi[q][lane] = h.y;
        __syncthreads();
        float yr = b2r[lane], yi = b2i[lane];
        #pragma unroll 16
        for (int i = 0; i < 64; ++i) {
            float arv = hr[q][i], aiv = hi[q][i];
            float wr = w2r[i * 64 + lane], wi = w2i[i * 64 + lane];
            yr += arv * wr - aiv * wi;
            yi += arv * wi + aiv * wr;
        }
        float2 z = zm[idx];
        zm[idx] = make_float2(softshrink01(yr) - z.x, softshrink01(yi) - z.y);
        __syncthreads();
    }
}

// ---------------------------------------------------------------------------
// Kernel 3: inverse per (b,c); writes yy_bf = bf16(x + D).
// Radix-2 symmetry in both phases; single aliased LDS buffer S[128][34].
// ---------------------------------------------------------------------------
__global__ __launch_bounds__(256) void k_inv(const float2* __restrict__ zm,
                                             const float* __restrict__ x,
                                             unsigned short* __restrict__ yb) {
    __shared__ float2 S[128][34];   // phase 0/1: D in rows 0..63; phase 2: T at col k+1
    const int bc  = blockIdx.x;
    const int tid = threadIdx.x;

    // Load delta D[64][33] into S rows 0..63 (row-padded to 34 for b128 align).
    const float2* src = zm + (size_t)bc * 2112;
    for (int t = tid; t < 2112; t += 256) {
        int r = t / 33;
        int k = t - r * 33;
        S[r][k] = src[t];
    }
    __syncthreads();

    // ---- phase 1: T[h][k] = sum_r D[r][k] e^{+i 2pi h r / 128}, r-parity split.
    {
        const int h  = tid & 63;        // h in [0,64); also produces row h+64
        const int kg = tid >> 6;        // 0..3 -> k in [8kg, 8kg+8); kg==3 adds k=32
        const int k0 = kg * 8;
        float sc, ss;
        sincosf((float)h * TWO_PI_OVER_128, &ss, &sc);
        float c = 1.0f, s = 0.0f;       // angle h*r, starting r = 0
        float er[9] = {}, ei[9] = {}, orr[9] = {}, oi[9] = {};

        for (int r = 0; r < 64; r += 2) {
            // even r -> E
            const float4* p0 = (const float4*)&S[r][k0];
            #pragma unroll
            for (int j = 0; j < 4; ++j) {
                float4 v = p0[j];
                er[2*j]   += v.x * c - v.y * s;
                ei[2*j]   += v.y * c + v.x * s;
                er[2*j+1] += v.z * c - v.w * s;
                ei[2*j+1] += v.w * c + v.z * s;
            }
            if (kg == 3) {
                float2 v = S[r][32];
                er[8] += v.x * c - v.y * s;
                ei[8] += v.y * c + v.x * s;
            }
            float cn = c * sc - s * ss; s = s * sc + c * ss; c = cn;
            // odd r -> O
            const float4* p1 = (const float4*)&S[r + 1][k0];
            #pragma unroll
            for (int j = 0; j < 4; ++j) {
                float4 v = p1[j];
                orr[2*j]   += v.x * c - v.y * s;
                oi[2*j]    += v.y * c + v.x * s;
                orr[2*j+1] += v.z * c - v.w * s;
                oi[2*j+1]  += v.w * c + v.z * s;
            }
            if (kg == 3) {
                float2 v = S[r + 1][32];
                orr[8] += v.x * c - v.y * s;
                oi[8]  += v.y * c + v.x * s;
            }
            cn = c * sc - s * ss; s = s * sc + c * ss; c = cn;
        }
        __syncthreads();                // all reads of D complete; S reusable
        #pragma unroll
        for (int j = 0; j < 8; ++j) {
            int col = k0 + j + 1;       // T_k stored at col k+1 (b128-aligned reads)
            S[h][col]      = make_float2(er[j] + orr[j], ei[j] + oi[j]);
            S[h + 64][col] = make_float2(er[j] - orr[j], ei[j] - oi[j]);
        }
        if (kg == 3) {
            S[h][33]      = make_float2(er[8] + orr[8], ei[8] + oi[8]);
            S[h + 64][33] = make_float2(er[8] - orr[8], ei[8] - oi[8]);
        }
    }
    __syncthreads();

    // ---- phase 2: y[h][w] = (1/64)[0.5 A0 + sum_{k=1..32} (A_k cos - B_k sin)]
    // columns w and w+64 from one k-pass via k-parity accumulators.
    {
        const int w    = tid & 63;      // w in [0,64); also produces column w+64
        const int quad = tid >> 6;      // rows [32*quad, 32*quad+32)
        float sc, ss;
        sincosf((float)w * TWO_PI_OVER_128, &ss, &sc);
        const size_t base = (size_t)bc * 16384;
        #pragma unroll
        for (int ch = 0; ch < 4; ++ch) {
            const int h0 = quad * 32 + ch * 8;
            float pe[8], po[8], qe[8], qo[8];
            #pragma unroll
            for (int i = 0; i < 8; ++i) {
                pe[i] = 0.5f * S[h0 + i][1].x;   // k=0 term (even, sin=0)
                po[i] = 0.f; qe[i] = 0.f; qo[i] = 0.f;
            }
            float c = sc, s = ss;                // angle for k=1
            #pragma unroll
            for (int p = 0; p < 16; ++p) {
                float c2 = c * sc - s * ss;      // k = 2p+2
                float s2 = s * sc + c * ss;
                #pragma unroll
                for (int i = 0; i < 8; ++i) {
                    float4 v = *(const float4*)&S[h0 + i][2 + 2 * p]; // (A,B)_{2p+1},(A,B)_{2p+2}
                    po[i] += v.x * c;  qo[i] += v.y * s;
                    pe[i] += v.z * c2; qe[i] += v.w * s2;
                }
                c = c2 * sc - s2 * ss;           // advance to k = 2p+3
                s = s2 * sc + c2 * ss;
            }
            #pragma unroll
            for (int i = 0; i < 8; ++i) {
                float y1 = (pe[i] + po[i] - qe[i] - qo[i]) * 0.015625f;
                float y2 = (pe[i] - po[i] - qe[i] + qo[i]) * 0.015625f;
                size_t i1 = base + (size_t)(h0 + i) * 128 + w;
                yb[i1]      = f2bf(x[i1] + y1);
                yb[i1 + 64] = f2bf(x[i1 + 64] + y2);
            }
        }
    }
}

// ---------------------------------------------------------------------------
// Kernel 3b: transpose yy_bf[b][c][p] -> yy_t[b][p][c] (bf16), 64x64 tiles.
// ---------------------------------------------------------------------------
__global__ __launch_bounds__(256) void k_tr(const unsigned short* __restrict__ yb,
                                            unsigned short* __restrict__ yt) {
    __shared__ float ts[64][65];   // [p][c]
    const int p0 = blockIdx.x * 64;
    const int c0 = blockIdx.y * 64;
    const int b  = blockIdx.z;
    const int t  = threadIdx.x;
    const int lane = t & 63;

    const unsigned short* src = yb + (((size_t)(b * 512 + c0 + lane)) << 14) + p0;
    #pragma unroll
    for (int cc = 0; cc < 2; ++cc) {
        int ch = (t >> 6) * 2 + cc;          // p-chunk 0..7
        us8 v = *(const us8*)&src[ch * 8];
        #pragma unroll
        for (int j = 0; j < 8; ++j)
            ts[ch * 8 + j][lane] = __uint_as_float((unsigned)v[j] << 16);
    }
    __syncthreads();

    const int pr   = t >> 2;
    const int coff = (t & 3) * 16;
    us8 o0v, o1v;
    #pragma unroll
    for (int i = 0; i < 8; ++i) o0v[i] = f2bf(ts[pr][coff + i]);
    #pragma unroll
    for (int i = 0; i < 8; ++i) o1v[i] = f2bf(ts[pr][coff + 8 + i]);
    unsigned short* dst = yt + ((size_t)(b * 16384 + p0 + pr)) * 512 + c0 + coff;
    *(us8*)&dst[0] = o0v;
    *(us8*)&dst[8] = o1v;
}

// ---------------------------------------------------------------------------
// Kernel 3c: fw fp32 -> bf16 (row-major [o][c] unchanged).
// ---------------------------------------------------------------------------
__global__ __launch_bounds__(256) void k_prep(const float* __restrict__ fw,
                                              unsigned short* __restrict__ fb) {
    int i = (blockIdx.x * 256 + threadIdx.x) * 4;
    float4 v = *(const float4*)&fw[i];
    ushort4 o;
    o.x = f2bf(v.x); o.y = f2bf(v.y); o.z = f2bf(v.z); o.w = f2bf(v.w);
    *(ushort4*)&fb[i] = o;
}

// ---------------------------------------------------------------------------
// Kernel 4: MFMA conv GEMM. out[b][o][p] = x[b][o][p] + sum_c fb[o][c]*yt[b][p][c]
// 128x128 tile, BK=32, 4 waves (2x2 of 64x64), mfma_f32_16x16x32_bf16.
// LDS rows padded to 40 bf16 (80 B) -> b128 frag reads bank-uniform.
// Fragment maps (m89/m91/m120-verified): A: m=lane&15,k=quad*8+j;
// B: n=lane&15,k=quad*8+j; C/D: col(n)=lane&15, row(m)=quad*4+reg.
// ---------------------------------------------------------------------------
__global__ __launch_bounds__(256) void k_gemm(const unsigned short* __restrict__ fb,
                                              const unsigned short* __restrict__ yt,
                                              const float* __restrict__ x,
                                              float* __restrict__ out) {
    __shared__ short Al[128 * 40];
    __shared__ short Bl[128 * 40];
    const int p0  = blockIdx.x * 128;
    const int o0  = blockIdx.y * 128;
    const int b   = blockIdx.z;
    const int tid = threadIdx.x;
    const int lane = tid & 63;
    const int w    = tid >> 6;
    const int wo = (w >> 1) * 64, wp = (w & 1) * 64;

    f32x4 acc[4][4];
    #pragma unroll
    for (int i = 0; i < 4; ++i)
        #pragma unroll
        for (int j = 0; j < 4; ++j)
            acc[i][j] = (f32x4){0.f, 0.f, 0.f, 0.f};

    const int m15 = lane & 15, quad = lane >> 4;

    for (int kc = 0; kc < 512; kc += 32) {
        __syncthreads();
        #pragma unroll
        for (int cc = 0; cc < 2; ++cc) {
            int ch = tid + cc * 256;          // 0..511
            int r  = ch >> 2;                 // row 0..127
            int pt = ch & 3;                  // 8-bf16 part
            *(s8bf*)&Al[r * 40 + pt * 8] =
                *(const s8bf*)&fb[(size_t)(o0 + r) * 512 + kc + pt * 8];
            *(s8bf*)&Bl[r * 40 + pt * 8] =
                *(const s8bf*)&yt[((size_t)(b * 16384 + p0 + r)) * 512 + kc + pt * 8];
        }
        __syncthreads();

        s8bf af[4], bfr[4];
        #pragma unroll
        for (int i = 0; i < 4; ++i) {
            af[i]  = *(const s8bf*)&Al[(wo + i * 16 + m15) * 40 + quad * 8];
            bfr[i] = *(const s8bf*)&Bl[(wp + i * 16 + m15) * 40 + quad * 8];
        }
        #pragma unroll
        for (int mi = 0; mi < 4; ++mi)
            #pragma unroll
            for (int ni = 0; ni < 4; ++ni)
                acc[mi][ni] = __builtin_amdgcn_mfma_f32_16x16x32_bf16(
                    af[mi], bfr[ni], acc[mi][ni], 0, 0, 0);
    }

    #pragma unroll
    for (int mi = 0; mi < 4; ++mi) {
        #pragma unroll
        for (int ni = 0; ni < 4; ++ni) {
            #pragma unroll
            for (int r = 0; r < 4; ++r) {
                int o = o0 + wo + mi * 16 + quad * 4 + r;
                int p = p0 + wp + ni * 16 + m15;
                size_t idx = (((size_t)(b * 512 + o)) << 14) + p;
                out[idx] = x[idx] + acc[mi][ni][r];
            }
        }
    }
}

// ---------------------------------------------------------------------------
extern "C" void kernel_launch(void* const* d_in, const int* in_sizes, int n_in,
                              void* d_out, int out_size, void* d_ws, size_t ws_size,
                              hipStream_t stream) {
    const float* x   = (const float*)d_in[0];
    const float* w1r = (const float*)d_in[1];
    const float* w1i = (const float*)d_in[2];
    const float* b1r = (const float*)d_in[3];
    const float* b1i = (const float*)d_in[4];
    const float* w2r = (const float*)d_in[5];
    const float* w2i = (const float*)d_in[6];
    const float* b2r = (const float*)d_in[7];
    const float* b2i = (const float*)d_in[8];
    const float* fw  = (const float*)d_in[9];
    float* out = (float*)d_out;

    char* ws = (char*)d_ws;
    float2* zm          = (float2*)ws;                         // [0, 34.6MB)
    float2* hbuf        = (float2*)(ws + 34603008);            // dead after mlp2
    float2* zwg         = (float2*)(ws + 34603008);            // dead after fwd2
    unsigned short* ybf = (unsigned short*)(ws + 34603008);    // dead after k_tr
    unsigned short* yt  = (unsigned short*)(ws + 101711872);   // [101.7MB, 168.8MB)
    unsigned short* fb  = (unsigned short*)(ws + 34603008);    // written after k_tr

    k_fwd1<<<dim3(2048, 2), 256, 0, stream>>>(x, zwg);
    k_fwd2<<<2048, 256, 0, stream>>>(zwg, zm);
    k_mlp1<<<dim3(33, 8, 4), 256, 0, stream>>>(w1r, w1i, b1r, b1i, zm, hbuf);
    k_mlp2<<<dim3(33, 8, 4), 256, 0, stream>>>(w2r, w2i, b2r, b2i, hbuf, zm);
    k_inv<<<2048, 256, 0, stream>>>(zm, x, ybf);
    k_tr<<<dim3(256, 8, 4), 256, 0, stream>>>(ybf, yt);
    k_prep<<<256, 256, 0, stream>>>(fw, fb);
    k_gemm<<<dim3(128, 4, 4), 256, 0, stream>>>(fb, yt, x, out);
}

// Round 4
// 803.100 us; speedup vs baseline: 1.4057x; 1.0434x over previous
//
#include <hip/hip_runtime.h>
#include <math.h>

// AFNO2D: out = x + fuse_w @ (x + irfft2(masked_delta))
// masked_delta = (softshrink(W2*gelu(W1*Z+b1)+b2) - Z) on modes [0:64, 0:33].
// Only the 64x33 masked modes are transformed (irfft2(rfft2(x)) == x).
// Forward DFTs: per-thread twiddle rotation, radix-2 parity split.
// Inverse DFT: fp16 MFMA matmuls against precomputed twiddle tables.
// Conv: bf16 MFMA GEMM.
//
// Workspace layout (bytes), peak 168,820,736:
//   zm    @ 0          : B*C*64*33 float2  = 34,603,008  (Z modes, then delta)
//   hbuf  @ 34,603,008 : B*C*64*33 float2  = 34,603,008  (MLP hidden; dead after mlp2)
//   zwg   @ 34,603,008 : B*C*128*33 float2 = 69,206,016  (dead after fwd2)
//   yy_bf @ 34,603,008 : B*C*128*128 bf16  = 67,108,864  (y = x + D, bf16; dead after k_tr)
//   yy_t  @101,711,872 : B*16384*512 bf16  = 67,108,864  (y transposed [b][p][c])
//   fw_bf @ 34,603,008 : 512*512 bf16      = 524,288     (written after k_tr)
//   tw    @168,738,816 : 5*128*64 f16      = 81,920      (irfft twiddles; tail of yt
//                        region: untouched by zwg (ends 103.8MB) and only k_tr
//                        overwrites it, which runs after k_inv)

#define LAMB 0.01f
#define TWO_PI_OVER_128 0.049087385212340517f

typedef __attribute__((ext_vector_type(8))) short s8bf;           // 8 bf16 (4 VGPRs)
typedef __attribute__((ext_vector_type(8))) unsigned short us8;
typedef __attribute__((ext_vector_type(4))) float f32x4;
typedef __attribute__((ext_vector_type(8))) _Float16 f16x8;       // 8 f16 (4 VGPRs)

static __device__ __forceinline__ float gelu_exact(float v) {
    return 0.5f * v * (1.0f + erff(v * 0.7071067811865475f));
}
static __device__ __forceinline__ float softshrink01(float v) {
    float a = fabsf(v) - LAMB;
    a = a > 0.0f ? a : 0.0f;
    return v >= 0.0f ? a : -a;
}
static __device__ __forceinline__ unsigned short f2bf(float f) {
    union { float f; unsigned int u; } v; v.f = f;
    unsigned int r = v.u + 0x7FFFu + ((v.u >> 16) & 1u);   // RNE
    return (unsigned short)(r >> 16);
}

// ---------------------------------------------------------------------------
// Kernel 0: precompute irfft twiddle tables (f16).
//   T1c[h][r] =  cos(2pi h r/128)      (A-operand, phase 1)
//   T1s      =  sin, T1sn = -sin
//   Pt[w][k] =  w_k cos(2pi w k/128)/64   (k<=32, else 0; w_0=0.5)
//   Qt[w][k] = -w_k sin(2pi w k/128)/64
// ---------------------------------------------------------------------------
__global__ __launch_bounds__(256) void k_tw(_Float16* __restrict__ tw) {
    const int idx = blockIdx.x * 256 + threadIdx.x;   // 0..8191
    const int h = idx >> 6, r = idx & 63;
    float ss, sc;
    sincosf((float)((h * r) & 127) * TWO_PI_OVER_128, &ss, &sc);
    tw[idx]         = (_Float16)sc;
    tw[8192 + idx]  = (_Float16)ss;
    tw[16384 + idx] = (_Float16)(-ss);
    const float wk = (r == 0) ? 0.5f : 1.0f;
    const float pv = (r <= 32) ? wk * sc * 0.015625f : 0.f;
    const float qv = (r <= 32) ? -wk * ss * 0.015625f : 0.f;
    tw[24576 + idx] = (_Float16)pv;
    tw[32768 + idx] = (_Float16)qv;
}

// ---------------------------------------------------------------------------
// Kernel 1a: W-axis DFT (128 real -> 33 complex), ortho 1/128.
// Radix-2: X_k = sum_{w<64} (x_w + (-1)^k x_{w+64}) e^{-i 2pi w k/128}.
// ---------------------------------------------------------------------------
__global__ __launch_bounds__(256) void k_fwd1(const float* __restrict__ x,
                                              float2* __restrict__ zwg) {
    __shared__ float UV[2 * 64 * 68 + 16];
    float* ut = UV;                       // [w][68] rows 0..63, w<64
    float* vt = UV + 64 * 68 + 16;        // +16 words: bank group +16
    const int bc   = blockIdx.x;
    const int half = blockIdx.y;
    const int tid  = threadIdx.x;
    const int rg = tid >> 4;              // row group 0..15 (rows rg*4..rg*4+3)
    const int kg = tid & 15;

    const float* xim = x + (size_t)bc * 16384 + half * 8192;

    {
        const int r0 = rg * 4, w0 = kg * 4;
        float av[4][4], bv[4][4];
        #pragma unroll
        for (int i = 0; i < 4; ++i) {
            float4 a = *(const float4*)&xim[(r0 + i) * 128 + w0];
            float4 b = *(const float4*)&xim[(r0 + i) * 128 + w0 + 64];
            av[i][0] = a.x; av[i][1] = a.y; av[i][2] = a.z; av[i][3] = a.w;
            bv[i][0] = b.x; bv[i][1] = b.y; bv[i][2] = b.z; bv[i][3] = b.w;
        }
        #pragma unroll
        for (int j = 0; j < 4; ++j) {
            float4 u4, v4;
            u4.x = av[0][j] + bv[0][j]; v4.x = av[0][j] - bv[0][j];
            u4.y = av[1][j] + bv[1][j]; v4.y = av[1][j] - bv[1][j];
            u4.z = av[2][j] + bv[2][j]; v4.z = av[2][j] - bv[2][j];
            u4.w = av[3][j] + bv[3][j]; v4.w = av[3][j] - bv[3][j];
            *(float4*)&ut[(w0 + j) * 68 + r0] = u4;
            *(float4*)&vt[(w0 + j) * 68 + r0] = v4;
        }
    }
    __syncthreads();

    float2* zrow = zwg + (size_t)bc * 4224 + half * 2112;
    for (int t = 0; t < 3; ++t) {
        if (t == 2 && kg != 0) break;
        const int k = (t < 2) ? (kg + 16 * t) : 32;
        const float* src = (k & 1) ? vt : ut;
        float sc, ss;
        sincosf((float)k * TWO_PI_OVER_128, &ss, &sc);
        float c = 1.0f, s = 0.0f;
        float cr[4] = {0.f, 0.f, 0.f, 0.f}, ci[4] = {0.f, 0.f, 0.f, 0.f};
        for (int w = 0; w < 64; ++w) {
            float4 xv = *(const float4*)&src[w * 68 + rg * 4];
            cr[0] += xv.x * c; ci[0] -= xv.x * s;
            cr[1] += xv.y * c; ci[1] -= xv.y * s;
            cr[2] += xv.z * c; ci[2] -= xv.z * s;
            cr[3] += xv.w * c; ci[3] -= xv.w * s;
            float cn = c * sc - s * ss;
            s = s * sc + c * ss;
            c = cn;
        }
        #pragma unroll
        for (int i = 0; i < 4; ++i)
            zrow[(rg * 4 + i) * 33 + k] =
                make_float2(cr[i] * 0.0078125f, ci[i] * 0.0078125f);
    }
}

// ---------------------------------------------------------------------------
// Kernel 1b: H-axis DFT (128 -> 64 rows) on 33 k-columns.
// Radix-2 parity split over h.
// ---------------------------------------------------------------------------
__global__ __launch_bounds__(256) void k_fwd2(const float2* __restrict__ zwg,
                                              float2* __restrict__ zm) {
    __shared__ float2 UV2[2 * 64 * 34 + 4];
    float2* su = UV2;                     // [h][34], h<64
    float2* sv = UV2 + 64 * 34 + 4;       // word base +8 mod 32
    const int bc  = blockIdx.x;
    const int tid = threadIdx.x;

    const float2* src = zwg + (size_t)bc * 4224;
    for (int t = tid; t < 2112; t += 256) {
        int h = t / 33;
        int k = t - h * 33;
        float2 a = src[t];
        float2 b = src[t + 2112];
        su[h * 34 + k] = make_float2(a.x + b.x, a.y + b.y);
        sv[h * 34 + k] = make_float2(a.x - b.x, a.y - b.y);
    }
    __syncthreads();

    const int r  = tid >> 2;
    const int kq = tid & 3;
    const float2* zp = (r & 1) ? sv : su;
    float sc, ss;
    sincosf((float)r * TWO_PI_OVER_128, &ss, &sc);
    float c = 1.0f, s = 0.0f;
    float ar[8] = {}, ai[8] = {};
    float tr = 0.f, tiv = 0.f;

    for (int h = 0; h < 64; ++h) {
        const float4* rowp = (const float4*)&zp[h * 34 + kq * 8];
        float4 v0 = rowp[0], v1 = rowp[1], v2 = rowp[2], v3 = rowp[3];
        ar[0] += v0.x * c + v0.y * s;  ai[0] += v0.y * c - v0.x * s;
        ar[1] += v0.z * c + v0.w * s;  ai[1] += v0.w * c - v0.z * s;
        ar[2] += v1.x * c + v1.y * s;  ai[2] += v1.y * c - v1.x * s;
        ar[3] += v1.z * c + v1.w * s;  ai[3] += v1.w * c - v1.z * s;
        ar[4] += v2.x * c + v2.y * s;  ai[4] += v2.y * c - v2.x * s;
        ar[5] += v2.z * c + v2.w * s;  ai[5] += v2.w * c - v2.z * s;
        ar[6] += v3.x * c + v3.y * s;  ai[6] += v3.y * c - v3.x * s;
        ar[7] += v3.z * c + v3.w * s;  ai[7] += v3.w * c - v3.z * s;
        if (kq == 0) {
            float2 z = zp[h * 34 + 32];
            tr  += z.x * c + z.y * s;
            tiv += z.y * c - z.x * s;
        }
        float cn = c * sc - s * ss;
        s = s * sc + c * ss;
        c = cn;
    }

    float2* zrow = zm + (size_t)bc * 2112 + r * 33;
    #pragma unroll
    for (int j = 0; j < 8; ++j) zrow[kq * 8 + j] = make_float2(ar[j], ai[j]);
    if (kq == 0) zrow[32] = make_float2(tr, tiv);
}

// ---------------------------------------------------------------------------
// Kernel 2a: MLP layer 1 + exact GELU -> hbuf.
// ---------------------------------------------------------------------------
__global__ __launch_bounds__(256) void k_mlp1(const float* __restrict__ w1r_g,
                                              const float* __restrict__ w1i_g,
                                              const float* __restrict__ b1r_g,
                                              const float* __restrict__ b1i_g,
                                              const float2* __restrict__ zm,
                                              float2* __restrict__ hbuf) {
    __shared__ float w1r[4096], w1i[4096];
    __shared__ float b1r[64], b1i[64];
    __shared__ float zr[4][64], zi[4][64];
    const int chunk = blockIdx.x;
    const int nb    = blockIdx.y;
    const int b     = blockIdx.z;
    const int tid   = threadIdx.x;
    const int lane  = tid & 63;
    const int q     = tid >> 6;

    for (int t = tid; t < 4096; t += 256) {
        w1r[t] = w1r_g[nb * 4096 + t];
        w1i[t] = w1i_g[nb * 4096 + t];
    }
    if (tid < 64) { b1r[tid] = b1r_g[nb * 64 + tid]; b1i[tid] = b1i_g[nb * 64 + tid]; }
    __syncthreads();

    for (int g = 0; g < 16; ++g) {
        int pos = chunk * 64 + g * 4 + q;
        int r = pos / 33;
        int k = pos - r * 33;
        size_t idx = ((size_t)((b * 512 + nb * 64 + lane) * 64 + r)) * 33 + k;
        float2 z = zm[idx];
        zr[q][lane] = z.x; zi[q][lane] = z.y;
        __syncthreads();
        float yr = b1r[lane], yi = b1i[lane];
        #pragma unroll 16
        for (int i = 0; i < 64; ++i) {
            float arv = zr[q][i], aiv = zi[q][i];
            float wr = w1r[i * 64 + lane], wi = w1i[i * 64 + lane];
            yr += arv * wr - aiv * wi;
            yi += arv * wi + aiv * wr;
        }
        hbuf[idx] = make_float2(gelu_exact(yr), gelu_exact(yi));
        __syncthreads();
    }
}

// ---------------------------------------------------------------------------
// Kernel 2b: MLP layer 2 + softshrink; zm <- delta = softshrink(y2) - z
// ---------------------------------------------------------------------------
__global__ __launch_bounds__(256) void k_mlp2(const float* __restrict__ w2r_g,
                                              const float* __restrict__ w2i_g,
                                              const float* __restrict__ b2r_g,
                                              const float* __restrict__ b2i_g,
                                              const float2* __restrict__ hbuf,
                                              float2* __restrict__ zm) {
    __shared__ float w2r[4096], w2i[4096];
    __shared__ float b2r[64], b2i[64];
    __shared__ float hr[4][64], hi[4][64];
    const int chunk = blockIdx.x;
    const int nb    = blockIdx.y;
    const int b     = blockIdx.z;
    const int tid   = threadIdx.x;
    const int lane  = tid & 63;
    const int q     = tid >> 6;

    for (int t = tid; t < 4096; t += 256) {
        w2r[t] = w2r_g[nb * 4096 + t];
        w2i[t] = w2i_g[nb * 4096 + t];
    }
    if (tid < 64) { b2r[tid] = b2r_g[nb * 64 + tid]; b2i[tid] = b2i_g[nb * 64 + tid]; }
    __syncthreads();

    for (int g = 0; g < 16; ++g) {
        int pos = chunk * 64 + g * 4 + q;
        int r = pos / 33;
        int k = pos - r * 33;
        size_t idx = ((size_t)((b * 512 + nb * 64 + lane) * 64 + r)) * 33 + k;
        float2 h = hbuf[idx];
        hr[q][lane] = h.x; hi[q][lane] = h.y;
        __syncthreads();
        float yr = b2r[lane], yi = b2i[lane];
        #pragma unroll 16
        for (int i = 0; i < 64; ++i) {
            float arv = hr[q][i], aiv = hi[q][i];
            float wr = w2r[i * 64 + lane], wi = w2i[i * 64 + lane];
            yr += arv * wr - aiv * wi;
            yi += arv * wi + aiv * wr;
        }
        float2 z = zm[idx];
        zm[idx] = make_float2(softshrink01(yr) - z.x, softshrink01(yi) - z.y);
        __syncthreads();
    }
}

// ---------------------------------------------------------------------------
// Kernel 3: inverse irfft2 on masked modes via fp16 MFMA; yy_bf = bf16(x + y).
//   phase 1: T[h][k] = sum_r D[r][k] e^{+i 2pi h r/128}
//            Tr = T1c@Dr + T1sn@Di ; Ti = T1c@Di + T1s@Dr   (M=128,N=48,K=64)
//   phase 2: y[h][w] = sum_k Tr[h][k] Pt[w][k] + Ti[h][k] Qt[w][k]
//            (M=128,N=128,K=64; k>32 zero-padded)
// LDS: one 32,768 B buffer. Staging D^T (f16, XOR-swizzled rows) aliases the
// low 12,288 B; after phase 1 the buffer is zeroed and holds Tr/Ti (f16,
// swizzled). 5 blocks/CU by LDS. A/B fragment maps per m89/m91.
// ---------------------------------------------------------------------------
__global__ __launch_bounds__(256) void k_inv(const float2* __restrict__ zm,
                                             const float* __restrict__ x,
                                             const _Float16* __restrict__ tw,
                                             unsigned short* __restrict__ yb) {
    __shared__ _Float16 Sh[16384];   // 32,768 B
    const int bc   = blockIdx.x;
    const int tid  = threadIdx.x;
    const int lane = tid & 63;
    const int wv   = tid >> 6;
    const int m15  = lane & 15;
    const int quad = lane >> 4;

    const _Float16* T1c  = tw;            // [128][64]
    const _Float16* T1s  = tw + 8192;
    const _Float16* T1sn = tw + 16384;
    const _Float16* Pt   = tw + 24576;    // [128][64]
    const _Float16* Qt   = tw + 32768;

    // ---- zero D^T staging region: Dr_T,Di_T = 2 x [48][64] f16 = 12,288 B
    for (int t = tid; t < 768; t += 256)
        *(float4*)&Sh[t * 8] = (float4){0.f, 0.f, 0.f, 0.f};
    __syncthreads();

    // ---- stage D^T as f16 (rows = k-col, XOR swizzle keeps b128 reads 2-way)
    const float2* src = zm + (size_t)bc * 2112;
    for (int t = tid; t < 2112; t += 256) {
        int r = t / 33;
        int k = t - r * 33;
        float2 d = src[t];
        int sidx = (k * 64 + r) ^ ((k & 7) << 3);
        Sh[sidx]        = (_Float16)d.x;
        Sh[3072 + sidx] = (_Float16)d.y;
    }
    __syncthreads();

    // ---- phase 1 MFMA: wave handles m-tiles {2wv, 2wv+1} x n-tiles 0..2
    f32x4 aR[2][3], aI[2][3];
    #pragma unroll
    for (int i = 0; i < 2; ++i)
        #pragma unroll
        for (int j = 0; j < 3; ++j) {
            aR[i][j] = (f32x4){0.f, 0.f, 0.f, 0.f};
            aI[i][j] = (f32x4){0.f, 0.f, 0.f, 0.f};
        }
    #pragma unroll
    for (int ks = 0; ks < 2; ++ks) {
        const int ko = ks * 32 + quad * 8;
        f16x8 ac[2], ass[2], asn[2];
        #pragma unroll
        for (int mt = 0; mt < 2; ++mt) {
            const int m = (wv * 2 + mt) * 16 + m15;
            ac[mt]  = *(const f16x8*)&T1c[m * 64 + ko];
            ass[mt] = *(const f16x8*)&T1s[m * 64 + ko];
            asn[mt] = *(const f16x8*)&T1sn[m * 64 + ko];
        }
        #pragma unroll
        for (int nt = 0; nt < 3; ++nt) {
            const int n  = nt * 16 + m15;
            const int sb = (n * 64 + ko) ^ ((n & 7) << 3);
            f16x8 br = *(const f16x8*)&Sh[sb];
            f16x8 bi = *(const f16x8*)&Sh[3072 + sb];
            #pragma unroll
            for (int mt = 0; mt < 2; ++mt) {
                aR[mt][nt] = __builtin_amdgcn_mfma_f32_16x16x32_f16(ac[mt],  br, aR[mt][nt], 0, 0, 0);
                aR[mt][nt] = __builtin_amdgcn_mfma_f32_16x16x32_f16(asn[mt], bi, aR[mt][nt], 0, 0, 0);
                aI[mt][nt] = __builtin_amdgcn_mfma_f32_16x16x32_f16(ac[mt],  bi, aI[mt][nt], 0, 0, 0);
                aI[mt][nt] = __builtin_amdgcn_mfma_f32_16x16x32_f16(ass[mt], br, aI[mt][nt], 0, 0, 0);
            }
        }
    }
    __syncthreads();

    // ---- zero T region (full 32,768 B; cols 48..63 must be 0)
    for (int t = tid; t < 2048; t += 256)
        *(float4*)&Sh[t * 8] = (float4){0.f, 0.f, 0.f, 0.f};
    __syncthreads();

    // ---- write T (f16, swizzled): Tr at 0, Ti at f16-offset 8192.
    // acc C/D map: col = nt*16+m15 (k), row = quad*4+reg (h within tile).
    // Values at k>=33 are exact zeros (B rows were zero).
    #pragma unroll
    for (int mt = 0; mt < 2; ++mt)
        #pragma unroll
        for (int nt = 0; nt < 3; ++nt)
            #pragma unroll
            for (int r = 0; r < 4; ++r) {
                const int h  = (wv * 2 + mt) * 16 + quad * 4 + r;
                const int k  = nt * 16 + m15;
                const int si = (h * 64 + k) ^ ((h & 7) << 3);
                Sh[si]        = (_Float16)aR[mt][nt][r];
                Sh[8192 + si] = (_Float16)aI[mt][nt][r];
            }
    __syncthreads();

    // ---- phase 2 MFMA + epilogue: wave handles m-tiles {2wv,2wv+1} x 8 n-tiles
    const size_t base = (size_t)bc * 16384;
    #pragma unroll
    for (int mt = 0; mt < 2; ++mt) {
        const int h0 = (wv * 2 + mt) * 16;
        f32x4 acc[8];
        #pragma unroll
        for (int nt = 0; nt < 8; ++nt) acc[nt] = (f32x4){0.f, 0.f, 0.f, 0.f};
        #pragma unroll
        for (int ks = 0; ks < 2; ++ks) {
            const int hh = h0 + m15;
            const int sa = (hh * 64 + ks * 32 + quad * 8) ^ ((hh & 7) << 3);
            f16x8 atr = *(const f16x8*)&Sh[sa];
            f16x8 ati = *(const f16x8*)&Sh[8192 + sa];
            #pragma unroll
            for (int nt = 0; nt < 8; ++nt) {
                const int go = (nt * 16 + m15) * 64 + ks * 32 + quad * 8;
                f16x8 bp = *(const f16x8*)&Pt[go];
                f16x8 bq = *(const f16x8*)&Qt[go];
                acc[nt] = __builtin_amdgcn_mfma_f32_16x16x32_f16(atr, bp, acc[nt], 0, 0, 0);
                acc[nt] = __builtin_amdgcn_mfma_f32_16x16x32_f16(ati, bq, acc[nt], 0, 0, 0);
            }
        }
        #pragma unroll
        for (int nt = 0; nt < 8; ++nt)
            #pragma unroll
            for (int r = 0; r < 4; ++r) {
                const int h  = h0 + quad * 4 + r;
                const int wc = nt * 16 + m15;
                size_t idx = base + (size_t)h * 128 + wc;
                yb[idx] = f2bf(x[idx] + acc[nt][r]);
            }
    }
}

// ---------------------------------------------------------------------------
// Kernel 3b: transpose yy_bf[b][c][p] -> yy_t[b][p][c] (bf16), 64x64 tiles.
// ---------------------------------------------------------------------------
__global__ __launch_bounds__(256) void k_tr(const unsigned short* __restrict__ yb,
                                            unsigned short* __restrict__ yt) {
    __shared__ float ts[64][65];   // [p][c]
    const int p0 = blockIdx.x * 64;
    const int c0 = blockIdx.y * 64;
    const int b  = blockIdx.z;
    const int t  = threadIdx.x;
    const int lane = t & 63;

    const unsigned short* src = yb + (((size_t)(b * 512 + c0 + lane)) << 14) + p0;
    #pragma unroll
    for (int cc = 0; cc < 2; ++cc) {
        int ch = (t >> 6) * 2 + cc;          // p-chunk 0..7
        us8 v = *(const us8*)&src[ch * 8];
        #pragma unroll
        for (int j = 0; j < 8; ++j)
            ts[ch * 8 + j][lane] = __uint_as_float((unsigned)v[j] << 16);
    }
    __syncthreads();

    const int pr   = t >> 2;
    const int coff = (t & 3) * 16;
    us8 o0v, o1v;
    #pragma unroll
    for (int i = 0; i < 8; ++i) o0v[i] = f2bf(ts[pr][coff + i]);
    #pragma unroll
    for (int i = 0; i < 8; ++i) o1v[i] = f2bf(ts[pr][coff + 8 + i]);
    unsigned short* dst = yt + ((size_t)(b * 16384 + p0 + pr)) * 512 + c0 + coff;
    *(us8*)&dst[0] = o0v;
    *(us8*)&dst[8] = o1v;
}

// ---------------------------------------------------------------------------
// Kernel 3c: fw fp32 -> bf16 (row-major [o][c] unchanged).
// ---------------------------------------------------------------------------
__global__ __launch_bounds__(256) void k_prep(const float* __restrict__ fw,
                                              unsigned short* __restrict__ fb) {
    int i = (blockIdx.x * 256 + threadIdx.x) * 4;
    float4 v = *(const float4*)&fw[i];
    ushort4 o;
    o.x = f2bf(v.x); o.y = f2bf(v.y); o.z = f2bf(v.z); o.w = f2bf(v.w);
    *(ushort4*)&fb[i] = o;
}

// ---------------------------------------------------------------------------
// Kernel 4: MFMA conv GEMM. out[b][o][p] = x[b][o][p] + sum_c fb[o][c]*yt[b][p][c]
// 128x128 tile, BK=32, 4 waves (2x2 of 64x64), mfma_f32_16x16x32_bf16.
// ---------------------------------------------------------------------------
__global__ __launch_bounds__(256) void k_gemm(const unsigned short* __restrict__ fb,
                                              const unsigned short* __restrict__ yt,
                                              const float* __restrict__ x,
                                              float* __restrict__ out) {
    __shared__ short Al[128 * 40];
    __shared__ short Bl[128 * 40];
    const int p0  = blockIdx.x * 128;
    const int o0  = blockIdx.y * 128;
    const int b   = blockIdx.z;
    const int tid = threadIdx.x;
    const int lane = tid & 63;
    const int w    = tid >> 6;
    const int wo = (w >> 1) * 64, wp = (w & 1) * 64;

    f32x4 acc[4][4];
    #pragma unroll
    for (int i = 0; i < 4; ++i)
        #pragma unroll
        for (int j = 0; j < 4; ++j)
            acc[i][j] = (f32x4){0.f, 0.f, 0.f, 0.f};

    const int m15 = lane & 15, quad = lane >> 4;

    for (int kc = 0; kc < 512; kc += 32) {
        __syncthreads();
        #pragma unroll
        for (int cc = 0; cc < 2; ++cc) {
            int ch = tid + cc * 256;          // 0..511
            int r  = ch >> 2;                 // row 0..127
            int pt = ch & 3;                  // 8-bf16 part
            *(s8bf*)&Al[r * 40 + pt * 8] =
                *(const s8bf*)&fb[(size_t)(o0 + r) * 512 + kc + pt * 8];
            *(s8bf*)&Bl[r * 40 + pt * 8] =
                *(const s8bf*)&yt[((size_t)(b * 16384 + p0 + r)) * 512 + kc + pt * 8];
        }
        __syncthreads();

        s8bf af[4], bfr[4];
        #pragma unroll
        for (int i = 0; i < 4; ++i) {
            af[i]  = *(const s8bf*)&Al[(wo + i * 16 + m15) * 40 + quad * 8];
            bfr[i] = *(const s8bf*)&Bl[(wp + i * 16 + m15) * 40 + quad * 8];
        }
        #pragma unroll
        for (int mi = 0; mi < 4; ++mi)
            #pragma unroll
            for (int ni = 0; ni < 4; ++ni)
                acc[mi][ni] = __builtin_amdgcn_mfma_f32_16x16x32_bf16(
                    af[mi], bfr[ni], acc[mi][ni], 0, 0, 0);
    }

    #pragma unroll
    for (int mi = 0; mi < 4; ++mi) {
        #pragma unroll
        for (int ni = 0; ni < 4; ++ni) {
            #pragma unroll
            for (int r = 0; r < 4; ++r) {
                int o = o0 + wo + mi * 16 + quad * 4 + r;
                int p = p0 + wp + ni * 16 + m15;
                size_t idx = (((size_t)(b * 512 + o)) << 14) + p;
                out[idx] = x[idx] + acc[mi][ni][r];
            }
        }
    }
}

// ---------------------------------------------------------------------------
extern "C" void kernel_launch(void* const* d_in, const int* in_sizes, int n_in,
                              void* d_out, int out_size, void* d_ws, size_t ws_size,
                              hipStream_t stream) {
    const float* x   = (const float*)d_in[0];
    const float* w1r = (const float*)d_in[1];
    const float* w1i = (const float*)d_in[2];
    const float* b1r = (const float*)d_in[3];
    const float* b1i = (const float*)d_in[4];
    const float* w2r = (const float*)d_in[5];
    const float* w2i = (const float*)d_in[6];
    const float* b2r = (const float*)d_in[7];
    const float* b2i = (const float*)d_in[8];
    const float* fw  = (const float*)d_in[9];
    float* out = (float*)d_out;

    char* ws = (char*)d_ws;
    float2* zm          = (float2*)ws;                         // [0, 34.6MB)
    float2* hbuf        = (float2*)(ws + 34603008);            // dead after mlp2
    float2* zwg         = (float2*)(ws + 34603008);            // dead after fwd2
    unsigned short* ybf = (unsigned short*)(ws + 34603008);    // dead after k_tr
    unsigned short* yt  = (unsigned short*)(ws + 101711872);   // [101.7MB, 168.8MB)
    unsigned short* fb  = (unsigned short*)(ws + 34603008);    // written after k_tr
    _Float16* tw        = (_Float16*)(ws + 168738816);         // tail of yt region

    k_tw<<<32, 256, 0, stream>>>(tw);
    k_fwd1<<<dim3(2048, 2), 256, 0, stream>>>(x, zwg);
    k_fwd2<<<2048, 256, 0, stream>>>(zwg, zm);
    k_mlp1<<<dim3(33, 8, 4), 256, 0, stream>>>(w1r, w1i, b1r, b1i, zm, hbuf);
    k_mlp2<<<dim3(33, 8, 4), 256, 0, stream>>>(w2r, w2i, b2r, b2i, hbuf, zm);
    k_inv<<<2048, 256, 0, stream>>>(zm, x, tw, ybf);
    k_tr<<<dim3(256, 8, 4), 256, 0, stream>>>(ybf, yt);
    k_prep<<<256, 256, 0, stream>>>(fw, fb);
    k_gemm<<<dim3(128, 4, 4), 256, 0, stream>>>(fb, yt, x, out);
}

// Round 5
// 705.703 us; speedup vs baseline: 1.5997x; 1.1380x over previous
//
#include <hip/hip_runtime.h>
#include <math.h>

// AFNO2D: out = x + fuse_w @ (x + irfft2(masked_delta))
// masked_delta = (softshrink(W2*gelu(W1*Z+b1)+b2) - Z) on modes [0:64, 0:33].
// Only the 64x33 masked modes are transformed (irfft2(rfft2(x)) == x).
// Forward DFT: fused single kernel, fp16 MFMA vs precomputed twiddle tables.
// Inverse DFT: fp16 MFMA. Conv: bf16 MFMA GEMM.
//
// Workspace layout (bytes), peak 168,820,736:
//   zm    @ 0          : B*C*64*33 float2  = 34,603,008  (Z modes, then delta)
//   hbuf  @ 34,603,008 : B*C*64*33 float2  = 34,603,008  (MLP hidden; dead after mlp2)
//   yy_bf @ 34,603,008 : B*C*128*128 bf16  = 67,108,864  (y = x + D, bf16; dead after k_tr)
//   yy_t  @101,711,872 : B*16384*512 bf16  = 67,108,864  (y transposed [b][p][c])
//   fw_bf @ 34,603,008 : 512*512 bf16      = 524,288     (written after k_tr)
//   tw    @168,665,088 : 77,824 f16        = 155,648     (twiddles; tail of yt region:
//                        only k_tr overwrites it, which runs after k_fwdm/k_inv)
//
// tw f16 offsets: T1c 0, T1s 8192, T1sn 16384, Pt 24576, Qt 32768 (inv, [128][64])
//                 FWr 40960, FWi 47104 ([48][128]); FHc 53248, FHs 61440,
//                 FHsn 69632 ([64][128]).

#define LAMB 0.01f
#define TWO_PI_OVER_128 0.049087385212340517f

typedef __attribute__((ext_vector_type(8))) short s8bf;           // 8 bf16 (4 VGPRs)
typedef __attribute__((ext_vector_type(8))) unsigned short us8;
typedef __attribute__((ext_vector_type(4))) float f32x4;
typedef __attribute__((ext_vector_type(8))) _Float16 f16x8;       // 8 f16 (4 VGPRs)

static __device__ __forceinline__ float gelu_exact(float v) {
    return 0.5f * v * (1.0f + erff(v * 0.7071067811865475f));
}
static __device__ __forceinline__ float softshrink01(float v) {
    float a = fabsf(v) - LAMB;
    a = a > 0.0f ? a : 0.0f;
    return v >= 0.0f ? a : -a;
}
static __device__ __forceinline__ unsigned short f2bf(float f) {
    union { float f; unsigned int u; } v; v.f = f;
    unsigned int r = v.u + 0x7FFFu + ((v.u >> 16) & 1u);   // RNE
    return (unsigned short)(r >> 16);
}

// ---------------------------------------------------------------------------
// Kernel 0: precompute all twiddle tables (f16).
// Inverse:  T1c[h][r]=cos(2pi hr/128), T1s=sin, T1sn=-sin       ([128][64])
//           Pt[w][k]=w_k cos(2pi wk/128)/64, Qt=-w_k sin/64     ([128][64])
// Forward:  FWr[k][w]=cos(2pi wk/128)/128, FWi=-sin/128         ([48][128])
//           FHc[r][h]=cos(2pi rh/128), FHs=sin, FHsn=-sin       ([64][128])
// ---------------------------------------------------------------------------
__global__ __launch_bounds__(256) void k_tw(_Float16* __restrict__ tw) {
    const int idx = blockIdx.x * 256 + threadIdx.x;   // 0..8191
    {
        const int h = idx >> 6, r = idx & 63;
        float ss, sc;
        sincosf((float)((h * r) & 127) * TWO_PI_OVER_128, &ss, &sc);
        tw[idx]         = (_Float16)sc;
        tw[8192 + idx]  = (_Float16)ss;
        tw[16384 + idx] = (_Float16)(-ss);
        const float wk = (r == 0) ? 0.5f : 1.0f;
        const float pv = (r <= 32) ? wk * sc * 0.015625f : 0.f;
        const float qv = (r <= 32) ? -wk * ss * 0.015625f : 0.f;
        tw[24576 + idx] = (_Float16)pv;
        tw[32768 + idx] = (_Float16)qv;
    }
    if (idx < 6144) {                                  // FW [48][128]
        const int k = idx >> 7, w = idx & 127;
        float ss, sc;
        sincosf((float)((w * k) & 127) * TWO_PI_OVER_128, &ss, &sc);
        tw[40960 + idx] = (_Float16)(sc * 0.0078125f);
        tw[47104 + idx] = (_Float16)(-ss * 0.0078125f);
    }
    {                                                  // FH [64][128]
        const int r = idx >> 7, h = idx & 127;
        float ss, sc;
        sincosf((float)((r * h) & 127) * TWO_PI_OVER_128, &ss, &sc);
        tw[53248 + idx] = (_Float16)sc;
        tw[61440 + idx] = (_Float16)ss;
        tw[69632 + idx] = (_Float16)(-ss);
    }
}

// ---------------------------------------------------------------------------
// Kernel 1: fused forward rfft2 (masked 64x33 modes) via fp16 MFMA.
//   phase A: Y[h][k] = sum_w x[h][w] e^{-i 2pi wk/128}/128
//            Yr = X@FWr^T, Yi = X@FWi^T          (M=128, N=48, K=128)
//   phase B: Z[r][k] = sum_h e^{-i 2pi rh/128} Y[h][k]
//            Zr = FHc@Yr + FHs@Yi ; Zi = FHc@Yi + FHsn@Yr   (M=64, N=48, K=128)
// Single 32 KB LDS buffer: x (f16, XOR-swizzled) during phase A; phase-A accs
// live in registers across the barrier, then Y^T (f16, swizzled) overwrites.
// A/B fragment maps per m89/m91: A,B: row=lane&15, k=quad*8+j;
// C/D: col(n)=lane&15, row(m)=quad*4+reg.
// ---------------------------------------------------------------------------
__global__ __launch_bounds__(256) void k_fwdm(const float* __restrict__ x,
                                              const _Float16* __restrict__ tw,
                                              float2* __restrict__ zm) {
    __shared__ _Float16 Xs[16384];   // 32,768 B
    const int bc   = blockIdx.x;
    const int tid  = threadIdx.x;
    const int lane = tid & 63;
    const int wv   = tid >> 6;
    const int m15  = lane & 15;
    const int quad = lane >> 4;

    const _Float16* FWr  = tw + 40960;   // [48][128]
    const _Float16* FWi  = tw + 47104;
    const _Float16* FHc  = tw + 53248;   // [64][128]
    const _Float16* FHs  = tw + 61440;
    const _Float16* FHsn = tw + 69632;

    // ---- stage x -> f16, swizzled: idx = h*128+w ^ ((h&7)<<3)
    const float* xim = x + (size_t)bc * 16384;
    for (int t = tid; t < 2048; t += 256) {
        const int h  = t >> 4;
        const int w0 = (t & 15) * 8;
        float4 a = *(const float4*)&xim[h * 128 + w0];
        float4 b = *(const float4*)&xim[h * 128 + w0 + 4];
        f16x8 v;
        v[0] = (_Float16)a.x; v[1] = (_Float16)a.y;
        v[2] = (_Float16)a.z; v[3] = (_Float16)a.w;
        v[4] = (_Float16)b.x; v[5] = (_Float16)b.y;
        v[6] = (_Float16)b.z; v[7] = (_Float16)b.w;
        *(f16x8*)&Xs[(h * 128 + w0) ^ ((h & 7) << 3)] = v;
    }
    __syncthreads();

    // ---- phase A: m-tiles {2wv, 2wv+1}, n-tiles 0..2, K=128 (w)
    f32x4 yR[2][3], yI[2][3];
    #pragma unroll
    for (int i = 0; i < 2; ++i)
        #pragma unroll
        for (int j = 0; j < 3; ++j) {
            yR[i][j] = (f32x4){0.f, 0.f, 0.f, 0.f};
            yI[i][j] = (f32x4){0.f, 0.f, 0.f, 0.f};
        }
    #pragma unroll
    for (int ks = 0; ks < 4; ++ks) {
        const int ko = ks * 32 + quad * 8;
        f16x8 af[2];
        #pragma unroll
        for (int mt = 0; mt < 2; ++mt) {
            const int h = (wv * 2 + mt) * 16 + m15;
            af[mt] = *(const f16x8*)&Xs[(h * 128 + ko) ^ ((h & 7) << 3)];
        }
        #pragma unroll
        for (int nt = 0; nt < 3; ++nt) {
            const int n = nt * 16 + m15;
            f16x8 br = *(const f16x8*)&FWr[n * 128 + ko];
            f16x8 bi = *(const f16x8*)&FWi[n * 128 + ko];
            #pragma unroll
            for (int mt = 0; mt < 2; ++mt) {
                yR[mt][nt] = __builtin_amdgcn_mfma_f32_16x16x32_f16(af[mt], br, yR[mt][nt], 0, 0, 0);
                yI[mt][nt] = __builtin_amdgcn_mfma_f32_16x16x32_f16(af[mt], bi, yI[mt][nt], 0, 0, 0);
            }
        }
    }
    __syncthreads();             // all phase-A reads of Xs done

    // ---- write Y^T (f16, swizzled): Yr at 0, Yi at 8192; idx=k*128+h ^((k&7)<<3)
    #pragma unroll
    for (int mt = 0; mt < 2; ++mt)
        #pragma unroll
        for (int nt = 0; nt < 3; ++nt)
            #pragma unroll
            for (int r = 0; r < 4; ++r) {
                const int h = (wv * 2 + mt) * 16 + quad * 4 + r;
                const int k = nt * 16 + m15;
                const int si = (k * 128 + h) ^ ((k & 7) << 3);
                Xs[si]        = (_Float16)yR[mt][nt][r];
                Xs[8192 + si] = (_Float16)yI[mt][nt][r];
            }
    __syncthreads();

    // ---- phase B: m-tile = wv (r in [0,64)), n-tiles 0..2, K=128 (h)
    f32x4 zR[3], zI[3];
    #pragma unroll
    for (int j = 0; j < 3; ++j) {
        zR[j] = (f32x4){0.f, 0.f, 0.f, 0.f};
        zI[j] = (f32x4){0.f, 0.f, 0.f, 0.f};
    }
    const int rr = wv * 16 + m15;
    #pragma unroll
    for (int ks = 0; ks < 4; ++ks) {
        const int ko = ks * 32 + quad * 8;
        f16x8 ac  = *(const f16x8*)&FHc[rr * 128 + ko];
        f16x8 as2 = *(const f16x8*)&FHs[rr * 128 + ko];
        f16x8 asn = *(const f16x8*)&FHsn[rr * 128 + ko];
        #pragma unroll
        for (int nt = 0; nt < 3; ++nt) {
            const int n  = nt * 16 + m15;
            const int si = (n * 128 + ko) ^ ((n & 7) << 3);
            f16x8 br = *(const f16x8*)&Xs[si];
            f16x8 bi = *(const f16x8*)&Xs[8192 + si];
            zR[nt] = __builtin_amdgcn_mfma_f32_16x16x32_f16(ac,  br, zR[nt], 0, 0, 0);
            zR[nt] = __builtin_amdgcn_mfma_f32_16x16x32_f16(as2, bi, zR[nt], 0, 0, 0);
            zI[nt] = __builtin_amdgcn_mfma_f32_16x16x32_f16(ac,  bi, zI[nt], 0, 0, 0);
            zI[nt] = __builtin_amdgcn_mfma_f32_16x16x32_f16(asn, br, zI[nt], 0, 0, 0);
        }
    }

    // ---- store Z[r][k], k<33
    float2* zrow = zm + (size_t)bc * 2112;
    #pragma unroll
    for (int nt = 0; nt < 3; ++nt) {
        const int k = nt * 16 + m15;
        if (k < 33) {
            #pragma unroll
            for (int r = 0; r < 4; ++r) {
                const int rw = wv * 16 + quad * 4 + r;
                zrow[rw * 33 + k] = make_float2(zR[nt][r], zI[nt][r]);
            }
        }
    }
}

// ---------------------------------------------------------------------------
// Kernel 2a: MLP layer 1 + exact GELU -> hbuf.
// ---------------------------------------------------------------------------
__global__ __launch_bounds__(256) void k_mlp1(const float* __restrict__ w1r_g,
                                              const float* __restrict__ w1i_g,
                                              const float* __restrict__ b1r_g,
                                              const float* __restrict__ b1i_g,
                                              const float2* __restrict__ zm,
                                              float2* __restrict__ hbuf) {
    __shared__ float w1r[4096], w1i[4096];
    __shared__ float b1r[64], b1i[64];
    __shared__ float zr[4][64], zi[4][64];
    const int chunk = blockIdx.x;
    const int nb    = blockIdx.y;
    const int b     = blockIdx.z;
    const int tid   = threadIdx.x;
    const int lane  = tid & 63;
    const int q     = tid >> 6;

    for (int t = tid; t < 4096; t += 256) {
        w1r[t] = w1r_g[nb * 4096 + t];
        w1i[t] = w1i_g[nb * 4096 + t];
    }
    if (tid < 64) { b1r[tid] = b1r_g[nb * 64 + tid]; b1i[tid] = b1i_g[nb * 64 + tid]; }
    __syncthreads();

    for (int g = 0; g < 16; ++g) {
        int pos = chunk * 64 + g * 4 + q;
        int r = pos / 33;
        int k = pos - r * 33;
        size_t idx = ((size_t)((b * 512 + nb * 64 + lane) * 64 + r)) * 33 + k;
        float2 z = zm[idx];
        zr[q][lane] = z.x; zi[q][lane] = z.y;
        __syncthreads();
        float yr = b1r[lane], yi = b1i[lane];
        #pragma unroll 16
        for (int i = 0; i < 64; ++i) {
            float arv = zr[q][i], aiv = zi[q][i];
            float wr = w1r[i * 64 + lane], wi = w1i[i * 64 + lane];
            yr += arv * wr - aiv * wi;
            yi += arv * wi + aiv * wr;
        }
        hbuf[idx] = make_float2(gelu_exact(yr), gelu_exact(yi));
        __syncthreads();
    }
}

// ---------------------------------------------------------------------------
// Kernel 2b: MLP layer 2 + softshrink; zm <- delta = softshrink(y2) - z
// ---------------------------------------------------------------------------
__global__ __launch_bounds__(256) void k_mlp2(const float* __restrict__ w2r_g,
                                              const float* __restrict__ w2i_g,
                                              const float* __restrict__ b2r_g,
                                              const float* __restrict__ b2i_g,
                                              const float2* __restrict__ hbuf,
                                              float2* __restrict__ zm) {
    __shared__ float w2r[4096], w2i[4096];
    __shared__ float b2r[64], b2i[64];
    __shared__ float hr[4][64], hi[4][64];
    const int chunk = blockIdx.x;
    const int nb    = blockIdx.y;
    const int b     = blockIdx.z;
    const int tid   = threadIdx.x;
    const int lane  = tid & 63;
    const int q     = tid >> 6;

    for (int t = tid; t < 4096; t += 256) {
        w2r[t] = w2r_g[nb * 4096 + t];
        w2i[t] = w2i_g[nb * 4096 + t];
    }
    if (tid < 64) { b2r[tid] = b2r_g[nb * 64 + tid]; b2i[tid] = b2i_g[nb * 64 + tid]; }
    __syncthreads();

    for (int g = 0; g < 16; ++g) {
        int pos = chunk * 64 + g * 4 + q;
        int r = pos / 33;
        int k = pos - r * 33;
        size_t idx = ((size_t)((b * 512 + nb * 64 + lane) * 64 + r)) * 33 + k;
        float2 h = hbuf[idx];
        hr[q][lane] = h.x; hi[q][lane] = h.y;
        __syncthreads();
        float yr = b2r[lane], yi = b2i[lane];
        #pragma unroll 16
        for (int i = 0; i < 64; ++i) {
            float arv = hr[q][i], aiv = hi[q][i];
            float wr = w2r[i * 64 + lane], wi = w2i[i * 64 + lane];
            yr += arv * wr - aiv * wi;
            yi += arv * wi + aiv * wr;
        }
        float2 z = zm[idx];
        zm[idx] = make_float2(softshrink01(yr) - z.x, softshrink01(yi) - z.y);
        __syncthreads();
    }
}

// ---------------------------------------------------------------------------
// Kernel 3: inverse irfft2 on masked modes via fp16 MFMA; yy_bf = bf16(x + y).
// ---------------------------------------------------------------------------
__global__ __launch_bounds__(256) void k_inv(const float2* __restrict__ zm,
                                             const float* __restrict__ x,
                                             const _Float16* __restrict__ tw,
                                             unsigned short* __restrict__ yb) {
    __shared__ _Float16 Sh[16384];   // 32,768 B
    const int bc   = blockIdx.x;
    const int tid  = threadIdx.x;
    const int lane = tid & 63;
    const int wv   = tid >> 6;
    const int m15  = lane & 15;
    const int quad = lane >> 4;

    const _Float16* T1c  = tw;            // [128][64]
    const _Float16* T1s  = tw + 8192;
    const _Float16* T1sn = tw + 16384;
    const _Float16* Pt   = tw + 24576;    // [128][64]
    const _Float16* Qt   = tw + 32768;

    // ---- zero D^T staging region: Dr_T,Di_T = 2 x [48][64] f16 = 12,288 B
    for (int t = tid; t < 768; t += 256)
        *(float4*)&Sh[t * 8] = (float4){0.f, 0.f, 0.f, 0.f};
    __syncthreads();

    // ---- stage D^T as f16 (rows = k-col, XOR swizzle keeps b128 reads 2-way)
    const float2* src = zm + (size_t)bc * 2112;
    for (int t = tid; t < 2112; t += 256) {
        int r = t / 33;
        int k = t - r * 33;
        float2 d = src[t];
        int sidx = (k * 64 + r) ^ ((k & 7) << 3);
        Sh[sidx]        = (_Float16)d.x;
        Sh[3072 + sidx] = (_Float16)d.y;
    }
    __syncthreads();

    // ---- phase 1 MFMA: wave handles m-tiles {2wv, 2wv+1} x n-tiles 0..2
    f32x4 aR[2][3], aI[2][3];
    #pragma unroll
    for (int i = 0; i < 2; ++i)
        #pragma unroll
        for (int j = 0; j < 3; ++j) {
            aR[i][j] = (f32x4){0.f, 0.f, 0.f, 0.f};
            aI[i][j] = (f32x4){0.f, 0.f, 0.f, 0.f};
        }
    #pragma unroll
    for (int ks = 0; ks < 2; ++ks) {
        const int ko = ks * 32 + quad * 8;
        f16x8 ac[2], ass[2], asn[2];
        #pragma unroll
        for (int mt = 0; mt < 2; ++mt) {
            const int m = (wv * 2 + mt) * 16 + m15;
            ac[mt]  = *(const f16x8*)&T1c[m * 64 + ko];
            ass[mt] = *(const f16x8*)&T1s[m * 64 + ko];
            asn[mt] = *(const f16x8*)&T1sn[m * 64 + ko];
        }
        #pragma unroll
        for (int nt = 0; nt < 3; ++nt) {
            const int n  = nt * 16 + m15;
            const int sb = (n * 64 + ko) ^ ((n & 7) << 3);
            f16x8 br = *(const f16x8*)&Sh[sb];
            f16x8 bi = *(const f16x8*)&Sh[3072 + sb];
            #pragma unroll
            for (int mt = 0; mt < 2; ++mt) {
                aR[mt][nt] = __builtin_amdgcn_mfma_f32_16x16x32_f16(ac[mt],  br, aR[mt][nt], 0, 0, 0);
                aR[mt][nt] = __builtin_amdgcn_mfma_f32_16x16x32_f16(asn[mt], bi, aR[mt][nt], 0, 0, 0);
                aI[mt][nt] = __builtin_amdgcn_mfma_f32_16x16x32_f16(ac[mt],  bi, aI[mt][nt], 0, 0, 0);
                aI[mt][nt] = __builtin_amdgcn_mfma_f32_16x16x32_f16(ass[mt], br, aI[mt][nt], 0, 0, 0);
            }
        }
    }
    __syncthreads();

    // ---- zero T region (full 32,768 B; cols 48..63 must be 0)
    for (int t = tid; t < 2048; t += 256)
        *(float4*)&Sh[t * 8] = (float4){0.f, 0.f, 0.f, 0.f};
    __syncthreads();

    // ---- write T (f16, swizzled): Tr at 0, Ti at f16-offset 8192.
    #pragma unroll
    for (int mt = 0; mt < 2; ++mt)
        #pragma unroll
        for (int nt = 0; nt < 3; ++nt)
            #pragma unroll
            for (int r = 0; r < 4; ++r) {
                const int h  = (wv * 2 + mt) * 16 + quad * 4 + r;
                const int k  = nt * 16 + m15;
                const int si = (h * 64 + k) ^ ((h & 7) << 3);
                Sh[si]        = (_Float16)aR[mt][nt][r];
                Sh[8192 + si] = (_Float16)aI[mt][nt][r];
            }
    __syncthreads();

    // ---- phase 2 MFMA + epilogue: wave handles m-tiles {2wv,2wv+1} x 8 n-tiles
    const size_t base = (size_t)bc * 16384;
    #pragma unroll
    for (int mt = 0; mt < 2; ++mt) {
        const int h0 = (wv * 2 + mt) * 16;
        f32x4 acc[8];
        #pragma unroll
        for (int nt = 0; nt < 8; ++nt) acc[nt] = (f32x4){0.f, 0.f, 0.f, 0.f};
        #pragma unroll
        for (int ks = 0; ks < 2; ++ks) {
            const int hh = h0 + m15;
            const int sa = (hh * 64 + ks * 32 + quad * 8) ^ ((hh & 7) << 3);
            f16x8 atr = *(const f16x8*)&Sh[sa];
            f16x8 ati = *(const f16x8*)&Sh[8192 + sa];
            #pragma unroll
            for (int nt = 0; nt < 8; ++nt) {
                const int go = (nt * 16 + m15) * 64 + ks * 32 + quad * 8;
                f16x8 bp = *(const f16x8*)&Pt[go];
                f16x8 bq = *(const f16x8*)&Qt[go];
                acc[nt] = __builtin_amdgcn_mfma_f32_16x16x32_f16(atr, bp, acc[nt], 0, 0, 0);
                acc[nt] = __builtin_amdgcn_mfma_f32_16x16x32_f16(ati, bq, acc[nt], 0, 0, 0);
            }
        }
        #pragma unroll
        for (int nt = 0; nt < 8; ++nt)
            #pragma unroll
            for (int r = 0; r < 4; ++r) {
                const int h  = h0 + quad * 4 + r;
                const int wc = nt * 16 + m15;
                size_t idx = base + (size_t)h * 128 + wc;
                yb[idx] = f2bf(x[idx] + acc[nt][r]);
            }
    }
}

// ---------------------------------------------------------------------------
// Kernel 3b: transpose yy_bf[b][c][p] -> yy_t[b][p][c] (bf16), 64x64 tiles.
// ---------------------------------------------------------------------------
__global__ __launch_bounds__(256) void k_tr(const unsigned short* __restrict__ yb,
                                            unsigned short* __restrict__ yt) {
    __shared__ float ts[64][65];   // [p][c]
    const int p0 = blockIdx.x * 64;
    const int c0 = blockIdx.y * 64;
    const int b  = blockIdx.z;
    const int t  = threadIdx.x;
    const int lane = t & 63;

    const unsigned short* src = yb + (((size_t)(b * 512 + c0 + lane)) << 14) + p0;
    #pragma unroll
    for (int cc = 0; cc < 2; ++cc) {
        int ch = (t >> 6) * 2 + cc;          // p-chunk 0..7
        us8 v = *(const us8*)&src[ch * 8];
        #pragma unroll
        for (int j = 0; j < 8; ++j)
            ts[ch * 8 + j][lane] = __uint_as_float((unsigned)v[j] << 16);
    }
    __syncthreads();

    const int pr   = t >> 2;
    const int coff = (t & 3) * 16;
    us8 o0v, o1v;
    #pragma unroll
    for (int i = 0; i < 8; ++i) o0v[i] = f2bf(ts[pr][coff + i]);
    #pragma unroll
    for (int i = 0; i < 8; ++i) o1v[i] = f2bf(ts[pr][coff + 8 + i]);
    unsigned short* dst = yt + ((size_t)(b * 16384 + p0 + pr)) * 512 + c0 + coff;
    *(us8*)&dst[0] = o0v;
    *(us8*)&dst[8] = o1v;
}

// ---------------------------------------------------------------------------
// Kernel 3c: fw fp32 -> bf16 (row-major [o][c] unchanged).
// ---------------------------------------------------------------------------
__global__ __launch_bounds__(256) void k_prep(const float* __restrict__ fw,
                                              unsigned short* __restrict__ fb) {
    int i = (blockIdx.x * 256 + threadIdx.x) * 4;
    float4 v = *(const float4*)&fw[i];
    ushort4 o;
    o.x = f2bf(v.x); o.y = f2bf(v.y); o.z = f2bf(v.z); o.w = f2bf(v.w);
    *(ushort4*)&fb[i] = o;
}

// ---------------------------------------------------------------------------
// Kernel 4: MFMA conv GEMM. out[b][o][p] = x[b][o][p] + sum_c fb[o][c]*yt[b][p][c]
// 128x128 tile, BK=32, 4 waves (2x2 of 64x64), mfma_f32_16x16x32_bf16.
// ---------------------------------------------------------------------------
__global__ __launch_bounds__(256) void k_gemm(const unsigned short* __restrict__ fb,
                                              const unsigned short* __restrict__ yt,
                                              const float* __restrict__ x,
                                              float* __restrict__ out) {
    __shared__ short Al[128 * 40];
    __shared__ short Bl[128 * 40];
    const int p0  = blockIdx.x * 128;
    const int o0  = blockIdx.y * 128;
    const int b   = blockIdx.z;
    const int tid = threadIdx.x;
    const int lane = tid & 63;
    const int w    = tid >> 6;
    const int wo = (w >> 1) * 64, wp = (w & 1) * 64;

    f32x4 acc[4][4];
    #pragma unroll
    for (int i = 0; i < 4; ++i)
        #pragma unroll
        for (int j = 0; j < 4; ++j)
            acc[i][j] = (f32x4){0.f, 0.f, 0.f, 0.f};

    const int m15 = lane & 15, quad = lane >> 4;

    for (int kc = 0; kc < 512; kc += 32) {
        __syncthreads();
        #pragma unroll
        for (int cc = 0; cc < 2; ++cc) {
            int ch = tid + cc * 256;          // 0..511
            int r  = ch >> 2;                 // row 0..127
            int pt = ch & 3;                  // 8-bf16 part
            *(s8bf*)&Al[r * 40 + pt * 8] =
                *(const s8bf*)&fb[(size_t)(o0 + r) * 512 + kc + pt * 8];
            *(s8bf*)&Bl[r * 40 + pt * 8] =
                *(const s8bf*)&yt[((size_t)(b * 16384 + p0 + r)) * 512 + kc + pt * 8];
        }
        __syncthreads();

        s8bf af[4], bfr[4];
        #pragma unroll
        for (int i = 0; i < 4; ++i) {
            af[i]  = *(const s8bf*)&Al[(wo + i * 16 + m15) * 40 + quad * 8];
            bfr[i] = *(const s8bf*)&Bl[(wp + i * 16 + m15) * 40 + quad * 8];
        }
        #pragma unroll
        for (int mi = 0; mi < 4; ++mi)
            #pragma unroll
            for (int ni = 0; ni < 4; ++ni)
                acc[mi][ni] = __builtin_amdgcn_mfma_f32_16x16x32_bf16(
                    af[mi], bfr[ni], acc[mi][ni], 0, 0, 0);
    }

    #pragma unroll
    for (int mi = 0; mi < 4; ++mi) {
        #pragma unroll
        for (int ni = 0; ni < 4; ++ni) {
            #pragma unroll
            for (int r = 0; r < 4; ++r) {
                int o = o0 + wo + mi * 16 + quad * 4 + r;
                int p = p0 + wp + ni * 16 + m15;
                size_t idx = (((size_t)(b * 512 + o)) << 14) + p;
                out[idx] = x[idx] + acc[mi][ni][r];
            }
        }
    }
}

// ---------------------------------------------------------------------------
extern "C" void kernel_launch(void* const* d_in, const int* in_sizes, int n_in,
                              void* d_out, int out_size, void* d_ws, size_t ws_size,
                              hipStream_t stream) {
    const float* x   = (const float*)d_in[0];
    const float* w1r = (const float*)d_in[1];
    const float* w1i = (const float*)d_in[2];
    const float* b1r = (const float*)d_in[3];
    const float* b1i = (const float*)d_in[4];
    const float* w2r = (const float*)d_in[5];
    const float* w2i = (const float*)d_in[6];
    const float* b2r = (const float*)d_in[7];
    const float* b2i = (const float*)d_in[8];
    const float* fw  = (const float*)d_in[9];
    float* out = (float*)d_out;

    char* ws = (char*)d_ws;
    float2* zm          = (float2*)ws;                         // [0, 34.6MB)
    float2* hbuf        = (float2*)(ws + 34603008);            // dead after mlp2
    unsigned short* ybf = (unsigned short*)(ws + 34603008);    // dead after k_tr
    unsigned short* yt  = (unsigned short*)(ws + 101711872);   // [101.7MB, 168.8MB)
    unsigned short* fb  = (unsigned short*)(ws + 34603008);    // written after k_tr
    _Float16* tw        = (_Float16*)(ws + 168665088);         // tail of yt region

    k_tw<<<32, 256, 0, stream>>>(tw);
    k_fwdm<<<2048, 256, 0, stream>>>(x, tw, zm);
    k_mlp1<<<dim3(33, 8, 4), 256, 0, stream>>>(w1r, w1i, b1r, b1i, zm, hbuf);
    k_mlp2<<<dim3(33, 8, 4), 256, 0, stream>>>(w2r, w2i, b2r, b2i, hbuf, zm);
    k_inv<<<2048, 256, 0, stream>>>(zm, x, tw, ybf);
    k_tr<<<dim3(256, 8, 4), 256, 0, stream>>>(ybf, yt);
    k_prep<<<256, 256, 0, stream>>>(fw, fb);
    k_gemm<<<dim3(128, 4, 4), 256, 0, stream>>>(fb, yt, x, out);
}

// Round 6
// 544.375 us; speedup vs baseline: 2.0738x; 1.2964x over previous
//
#include <hip/hip_runtime.h>
#include <math.h>

// AFNO2D: out = x + fuse_w @ (x + irfft2(masked_delta))
// masked_delta = (softshrink(W2*gelu(W1*Z+b1)+b2) - Z) on modes [0:64, 0:33].
// Only the 64x33 masked modes are transformed (irfft2(rfft2(x)) == x).
// Forward DFT: fused single kernel, fp16 MFMA vs precomputed twiddle tables.
// Block-diag MLP: fused single kernel (both layers), fp16 MFMA.
// Inverse DFT: fp16 MFMA. Conv: bf16 MFMA GEMM.
//
// Workspace layout (bytes), peak 168,820,736:
//   zm    @ 0          : B*C*64*33 float2  = 34,603,008  (Z modes, then delta in-place)
//   yy_bf @ 34,603,008 : B*C*128*128 bf16  = 67,108,864  (y = x + D, bf16; dead after k_tr)
//   yy_t  @101,711,872 : B*16384*512 bf16  = 67,108,864  (y transposed [b][p][c])
//   fw_bf @ 34,603,008 : 512*512 bf16      = 524,288     (written after k_tr)
//   tw    @168,665,088 : 77,824 f16        = 155,648     (twiddles; tail of yt region:
//                        only k_tr overwrites it, which runs after k_fwdm/k_inv)
//
// tw f16 offsets: T1c 0, T1s 8192, T1sn 16384, Pt 24576, Qt 32768 (inv, [128][64])
//                 FWr 40960, FWi 47104 ([48][128]); FHc 53248, FHs 61440,
//                 FHsn 69632 ([64][128]).

#define LAMB 0.01f
#define TWO_PI_OVER_128 0.049087385212340517f

typedef __attribute__((ext_vector_type(8))) short s8bf;           // 8 bf16 (4 VGPRs)
typedef __attribute__((ext_vector_type(8))) unsigned short us8;
typedef __attribute__((ext_vector_type(4))) float f32x4;
typedef __attribute__((ext_vector_type(8))) _Float16 f16x8;       // 8 f16 (4 VGPRs)

static __device__ __forceinline__ float gelu_exact(float v) {
    return 0.5f * v * (1.0f + erff(v * 0.7071067811865475f));
}
static __device__ __forceinline__ float softshrink01(float v) {
    float a = fabsf(v) - LAMB;
    a = a > 0.0f ? a : 0.0f;
    return v >= 0.0f ? a : -a;
}
static __device__ __forceinline__ unsigned short f2bf(float f) {
    union { float f; unsigned int u; } v; v.f = f;
    unsigned int r = v.u + 0x7FFFu + ((v.u >> 16) & 1u);   // RNE
    return (unsigned short)(r >> 16);
}

// ---------------------------------------------------------------------------
// Kernel 0: precompute all twiddle tables (f16).
// ---------------------------------------------------------------------------
__global__ __launch_bounds__(256) void k_tw(_Float16* __restrict__ tw) {
    const int idx = blockIdx.x * 256 + threadIdx.x;   // 0..8191
    {
        const int h = idx >> 6, r = idx & 63;
        float ss, sc;
        sincosf((float)((h * r) & 127) * TWO_PI_OVER_128, &ss, &sc);
        tw[idx]         = (_Float16)sc;
        tw[8192 + idx]  = (_Float16)ss;
        tw[16384 + idx] = (_Float16)(-ss);
        const float wk = (r == 0) ? 0.5f : 1.0f;
        const float pv = (r <= 32) ? wk * sc * 0.015625f : 0.f;
        const float qv = (r <= 32) ? -wk * ss * 0.015625f : 0.f;
        tw[24576 + idx] = (_Float16)pv;
        tw[32768 + idx] = (_Float16)qv;
    }
    if (idx < 6144) {                                  // FW [48][128]
        const int k = idx >> 7, w = idx & 127;
        float ss, sc;
        sincosf((float)((w * k) & 127) * TWO_PI_OVER_128, &ss, &sc);
        tw[40960 + idx] = (_Float16)(sc * 0.0078125f);
        tw[47104 + idx] = (_Float16)(-ss * 0.0078125f);
    }
    {                                                  // FH [64][128]
        const int r = idx >> 7, h = idx & 127;
        float ss, sc;
        sincosf((float)((r * h) & 127) * TWO_PI_OVER_128, &ss, &sc);
        tw[53248 + idx] = (_Float16)sc;
        tw[61440 + idx] = (_Float16)ss;
        tw[69632 + idx] = (_Float16)(-ss);
    }
}

// ---------------------------------------------------------------------------
// Kernel 1: fused forward rfft2 (masked 64x33 modes) via fp16 MFMA.
// ---------------------------------------------------------------------------
__global__ __launch_bounds__(256) void k_fwdm(const float* __restrict__ x,
                                              const _Float16* __restrict__ tw,
                                              float2* __restrict__ zm) {
    __shared__ _Float16 Xs[16384];   // 32,768 B
    const int bc   = blockIdx.x;
    const int tid  = threadIdx.x;
    const int lane = tid & 63;
    const int wv   = tid >> 6;
    const int m15  = lane & 15;
    const int quad = lane >> 4;

    const _Float16* FWr  = tw + 40960;   // [48][128]
    const _Float16* FWi  = tw + 47104;
    const _Float16* FHc  = tw + 53248;   // [64][128]
    const _Float16* FHs  = tw + 61440;
    const _Float16* FHsn = tw + 69632;

    // ---- stage x -> f16, swizzled: idx = h*128+w ^ ((h&7)<<3)
    const float* xim = x + (size_t)bc * 16384;
    for (int t = tid; t < 2048; t += 256) {
        const int h  = t >> 4;
        const int w0 = (t & 15) * 8;
        float4 a = *(const float4*)&xim[h * 128 + w0];
        float4 b = *(const float4*)&xim[h * 128 + w0 + 4];
        f16x8 v;
        v[0] = (_Float16)a.x; v[1] = (_Float16)a.y;
        v[2] = (_Float16)a.z; v[3] = (_Float16)a.w;
        v[4] = (_Float16)b.x; v[5] = (_Float16)b.y;
        v[6] = (_Float16)b.z; v[7] = (_Float16)b.w;
        *(f16x8*)&Xs[(h * 128 + w0) ^ ((h & 7) << 3)] = v;
    }
    __syncthreads();

    // ---- phase A: m-tiles {2wv, 2wv+1}, n-tiles 0..2, K=128 (w)
    f32x4 yR[2][3], yI[2][3];
    #pragma unroll
    for (int i = 0; i < 2; ++i)
        #pragma unroll
        for (int j = 0; j < 3; ++j) {
            yR[i][j] = (f32x4){0.f, 0.f, 0.f, 0.f};
            yI[i][j] = (f32x4){0.f, 0.f, 0.f, 0.f};
        }
    #pragma unroll
    for (int ks = 0; ks < 4; ++ks) {
        const int ko = ks * 32 + quad * 8;
        f16x8 af[2];
        #pragma unroll
        for (int mt = 0; mt < 2; ++mt) {
            const int h = (wv * 2 + mt) * 16 + m15;
            af[mt] = *(const f16x8*)&Xs[(h * 128 + ko) ^ ((h & 7) << 3)];
        }
        #pragma unroll
        for (int nt = 0; nt < 3; ++nt) {
            const int n = nt * 16 + m15;
            f16x8 br = *(const f16x8*)&FWr[n * 128 + ko];
            f16x8 bi = *(const f16x8*)&FWi[n * 128 + ko];
            #pragma unroll
            for (int mt = 0; mt < 2; ++mt) {
                yR[mt][nt] = __builtin_amdgcn_mfma_f32_16x16x32_f16(af[mt], br, yR[mt][nt], 0, 0, 0);
                yI[mt][nt] = __builtin_amdgcn_mfma_f32_16x16x32_f16(af[mt], bi, yI[mt][nt], 0, 0, 0);
            }
        }
    }
    __syncthreads();             // all phase-A reads of Xs done

    // ---- write Y^T (f16, swizzled): Yr at 0, Yi at 8192; idx=k*128+h ^((k&7)<<3)
    #pragma unroll
    for (int mt = 0; mt < 2; ++mt)
        #pragma unroll
        for (int nt = 0; nt < 3; ++nt)
            #pragma unroll
            for (int r = 0; r < 4; ++r) {
                const int h = (wv * 2 + mt) * 16 + quad * 4 + r;
                const int k = nt * 16 + m15;
                const int si = (k * 128 + h) ^ ((k & 7) << 3);
                Xs[si]        = (_Float16)yR[mt][nt][r];
                Xs[8192 + si] = (_Float16)yI[mt][nt][r];
            }
    __syncthreads();

    // ---- phase B: m-tile = wv (r in [0,64)), n-tiles 0..2, K=128 (h)
    f32x4 zR[3], zI[3];
    #pragma unroll
    for (int j = 0; j < 3; ++j) {
        zR[j] = (f32x4){0.f, 0.f, 0.f, 0.f};
        zI[j] = (f32x4){0.f, 0.f, 0.f, 0.f};
    }
    const int rr = wv * 16 + m15;
    #pragma unroll
    for (int ks = 0; ks < 4; ++ks) {
        const int ko = ks * 32 + quad * 8;
        f16x8 ac  = *(const f16x8*)&FHc[rr * 128 + ko];
        f16x8 as2 = *(const f16x8*)&FHs[rr * 128 + ko];
        f16x8 asn = *(const f16x8*)&FHsn[rr * 128 + ko];
        #pragma unroll
        for (int nt = 0; nt < 3; ++nt) {
            const int n  = nt * 16 + m15;
            const int si = (n * 128 + ko) ^ ((n & 7) << 3);
            f16x8 br = *(const f16x8*)&Xs[si];
            f16x8 bi = *(const f16x8*)&Xs[8192 + si];
            zR[nt] = __builtin_amdgcn_mfma_f32_16x16x32_f16(ac,  br, zR[nt], 0, 0, 0);
            zR[nt] = __builtin_amdgcn_mfma_f32_16x16x32_f16(as2, bi, zR[nt], 0, 0, 0);
            zI[nt] = __builtin_amdgcn_mfma_f32_16x16x32_f16(ac,  bi, zI[nt], 0, 0, 0);
            zI[nt] = __builtin_amdgcn_mfma_f32_16x16x32_f16(asn, br, zI[nt], 0, 0, 0);
        }
    }

    // ---- store Z[r][k], k<33
    float2* zrow = zm + (size_t)bc * 2112;
    #pragma unroll
    for (int nt = 0; nt < 3; ++nt) {
        const int k = nt * 16 + m15;
        if (k < 33) {
            #pragma unroll
            for (int r = 0; r < 4; ++r) {
                const int rw = wv * 16 + quad * 4 + r;
                zrow[rw * 33 + k] = make_float2(zR[nt][r], zI[nt][r]);
            }
        }
    }
}

// ---------------------------------------------------------------------------
// Kernel 2: fused block-diag complex MLP via fp16 MFMA; zm <- delta in place.
//   H = gelu(Z @ W1 + b1); Y = W2-layer: delta = softshrink(H @ W2 + b2) - Z.
// Per (b, nb): GEMM M=2112 (positions p = r*33+k), N=K=64. Grid (33,8,4);
// block handles 64 positions, wave = one 16-row m-tile.
// LDS 64 KB: 6 W^T tables [j][i] f16 (W1r,W1i,-W1i,W2r,W2i,-W2i, XOR-swizzled)
// + Hr/Hi [64][64] f16. Complex mult via sign-folded tables (k_inv pattern):
//   Hr = Zr@W1r + Zi@(-W1i) ; Hi = Zr@W1i + Zi@W1r.
// A-frags: layer 1 direct from global (4x128B coalesced segments); layer 2
// from LDS H (wave-local rows -> lgkmcnt-ordered, barrier kept for safety).
// ---------------------------------------------------------------------------
__global__ __launch_bounds__(256) void k_mlp(const float* __restrict__ w1r_g,
                                             const float* __restrict__ w1i_g,
                                             const float* __restrict__ b1r_g,
                                             const float* __restrict__ b1i_g,
                                             const float* __restrict__ w2r_g,
                                             const float* __restrict__ w2i_g,
                                             const float* __restrict__ b2r_g,
                                             const float* __restrict__ b2i_g,
                                             float2* __restrict__ zm) {
    __shared__ _Float16 S[32768];   // 65,536 B
    // f16 offsets in S:
    //  W1R 0, W1I 4096, W1N 8192 (=-W1i), W2R 12288, W2I 16384, W2N 20480,
    //  HR 24576, HI 28672.  W tables are [j][i] (=W^T), swizzled ^((j&7)<<3).
    const int p0  = blockIdx.x * 64;
    const int nb  = blockIdx.y;
    const int b   = blockIdx.z;
    const int tid = threadIdx.x;
    const int lane = tid & 63;
    const int wv   = tid >> 6;
    const int m15  = lane & 15;
    const int quad = lane >> 4;

    // ---- stage W^T as f16 (thread t: column j = t&63, i-block = (t>>6)*16)
    {
        const int j  = tid & 63;
        const int i0 = (tid >> 6) * 16;
        const int swz = (j & 7) << 3;
        #pragma unroll
        for (int tbl = 0; tbl < 4; ++tbl) {
            const float* src = (tbl == 0) ? w1r_g : (tbl == 1) ? w1i_g
                             : (tbl == 2) ? w2r_g : w2i_g;
            src += nb * 4096;
            f16x8 v0, v1, n0, n1;
            #pragma unroll
            for (int ii = 0; ii < 8; ++ii) {
                float a = src[(i0 + ii) * 64 + j];
                float c = src[(i0 + 8 + ii) * 64 + j];
                v0[ii] = (_Float16)a; n0[ii] = (_Float16)(-a);
                v1[ii] = (_Float16)c; n1[ii] = (_Float16)(-c);
            }
            const int base = (tbl == 0) ? 0 : (tbl == 1) ? 4096
                           : (tbl == 2) ? 12288 : 16384;
            *(f16x8*)&S[base + ((j * 64 + i0) ^ swz)]     = v0;
            *(f16x8*)&S[base + ((j * 64 + i0 + 8) ^ swz)] = v1;
            if (tbl == 1) {
                *(f16x8*)&S[8192 + ((j * 64 + i0) ^ swz)]     = n0;
                *(f16x8*)&S[8192 + ((j * 64 + i0 + 8) ^ swz)] = n1;
            } else if (tbl == 3) {
                *(f16x8*)&S[20480 + ((j * 64 + i0) ^ swz)]     = n0;
                *(f16x8*)&S[20480 + ((j * 64 + i0 + 8) ^ swz)] = n1;
            }
        }
    }

    // ---- layer-1 A-frags straight from global: Z[p][i], p=p0+wv*16+m15
    const float2* zb = zm + (size_t)(b * 512 + nb * 64) * 2112;
    const int p = p0 + wv * 16 + m15;
    f16x8 azr[2], azi[2];
    #pragma unroll
    for (int ks = 0; ks < 2; ++ks) {
        #pragma unroll
        for (int jj = 0; jj < 8; ++jj) {
            float2 z = zb[(size_t)(ks * 32 + quad * 8 + jj) * 2112 + p];
            azr[ks][jj] = (_Float16)z.x;
            azi[ks][jj] = (_Float16)z.y;
        }
    }
    __syncthreads();   // W tables staged

    // ---- layer 1 MFMA: Hr = Zr@W1r + Zi@W1n ; Hi = Zr@W1i + Zi@W1r
    f32x4 hr[4], hi[4];
    #pragma unroll
    for (int nt = 0; nt < 4; ++nt) {
        hr[nt] = (f32x4){0.f, 0.f, 0.f, 0.f};
        hi[nt] = (f32x4){0.f, 0.f, 0.f, 0.f};
    }
    #pragma unroll
    for (int ks = 0; ks < 2; ++ks) {
        #pragma unroll
        for (int nt = 0; nt < 4; ++nt) {
            const int n  = nt * 16 + m15;
            const int sb = (n * 64 + ks * 32 + quad * 8) ^ ((n & 7) << 3);
            f16x8 bwr = *(const f16x8*)&S[sb];
            f16x8 bwi = *(const f16x8*)&S[4096 + sb];
            f16x8 bwn = *(const f16x8*)&S[8192 + sb];
            hr[nt] = __builtin_amdgcn_mfma_f32_16x16x32_f16(azr[ks], bwr, hr[nt], 0, 0, 0);
            hr[nt] = __builtin_amdgcn_mfma_f32_16x16x32_f16(azi[ks], bwn, hr[nt], 0, 0, 0);
            hi[nt] = __builtin_amdgcn_mfma_f32_16x16x32_f16(azr[ks], bwi, hi[nt], 0, 0, 0);
            hi[nt] = __builtin_amdgcn_mfma_f32_16x16x32_f16(azi[ks], bwr, hi[nt], 0, 0, 0);
        }
    }

    // ---- bias + exact GELU -> H (f16, [m][j] swizzled; wave-local rows)
    #pragma unroll
    for (int nt = 0; nt < 4; ++nt) {
        const int jj = nt * 16 + m15;
        const float br = b1r_g[nb * 64 + jj];
        const float bi = b1i_g[nb * 64 + jj];
        #pragma unroll
        for (int r = 0; r < 4; ++r) {
            const int m  = wv * 16 + quad * 4 + r;
            const int si = (m * 64 + jj) ^ ((m & 7) << 3);
            S[24576 + si] = (_Float16)gelu_exact(hr[nt][r] + br);
            S[28672 + si] = (_Float16)gelu_exact(hi[nt][r] + bi);
        }
    }
    __syncthreads();

    // ---- layer-2 A-frags from LDS H
    f16x8 ahr[2], ahi[2];
    #pragma unroll
    for (int ks = 0; ks < 2; ++ks) {
        const int m  = wv * 16 + m15;
        const int sa = (m * 64 + ks * 32 + quad * 8) ^ ((m & 7) << 3);
        ahr[ks] = *(const f16x8*)&S[24576 + sa];
        ahi[ks] = *(const f16x8*)&S[28672 + sa];
    }

    // ---- layer 2 MFMA: Yr = Hr@W2r + Hi@W2n ; Yi = Hr@W2i + Hi@W2r
    f32x4 yr[4], yi[4];
    #pragma unroll
    for (int nt = 0; nt < 4; ++nt) {
        yr[nt] = (f32x4){0.f, 0.f, 0.f, 0.f};
        yi[nt] = (f32x4){0.f, 0.f, 0.f, 0.f};
    }
    #pragma unroll
    for (int ks = 0; ks < 2; ++ks) {
        #pragma unroll
        for (int nt = 0; nt < 4; ++nt) {
            const int n  = nt * 16 + m15;
            const int sb = (n * 64 + ks * 32 + quad * 8) ^ ((n & 7) << 3);
            f16x8 bwr = *(const f16x8*)&S[12288 + sb];
            f16x8 bwi = *(const f16x8*)&S[16384 + sb];
            f16x8 bwn = *(const f16x8*)&S[20480 + sb];
            yr[nt] = __builtin_amdgcn_mfma_f32_16x16x32_f16(ahr[ks], bwr, yr[nt], 0, 0, 0);
            yr[nt] = __builtin_amdgcn_mfma_f32_16x16x32_f16(ahi[ks], bwn, yr[nt], 0, 0, 0);
            yi[nt] = __builtin_amdgcn_mfma_f32_16x16x32_f16(ahr[ks], bwi, yi[nt], 0, 0, 0);
            yi[nt] = __builtin_amdgcn_mfma_f32_16x16x32_f16(ahi[ks], bwr, yi[nt], 0, 0, 0);
        }
    }

    // ---- epilogue: bias, softshrink, delta = ss(y) - z; write zm in place
    float2* zw = zm + (size_t)(b * 512 + nb * 64) * 2112;
    #pragma unroll
    for (int nt = 0; nt < 4; ++nt) {
        const int jj = nt * 16 + m15;
        const float br = b2r_g[nb * 64 + jj];
        const float bi = b2i_g[nb * 64 + jj];
        #pragma unroll
        for (int r = 0; r < 4; ++r) {
            const int pp = p0 + wv * 16 + quad * 4 + r;
            const size_t gi = (size_t)jj * 2112 + pp;
            float2 z = zw[gi];
            zw[gi] = make_float2(softshrink01(yr[nt][r] + br) - z.x,
                                 softshrink01(yi[nt][r] + bi) - z.y);
        }
    }
}

// ---------------------------------------------------------------------------
// Kernel 3: inverse irfft2 on masked modes via fp16 MFMA; yy_bf = bf16(x + y).
// ---------------------------------------------------------------------------
__global__ __launch_bounds__(256) void k_inv(const float2* __restrict__ zm,
                                             const float* __restrict__ x,
                                             const _Float16* __restrict__ tw,
                                             unsigned short* __restrict__ yb) {
    __shared__ _Float16 Sh[16384];   // 32,768 B
    const int bc   = blockIdx.x;
    const int tid  = threadIdx.x;
    const int lane = tid & 63;
    const int wv   = tid >> 6;
    const int m15  = lane & 15;
    const int quad = lane >> 4;

    const _Float16* T1c  = tw;            // [128][64]
    const _Float16* T1s  = tw + 8192;
    const _Float16* T1sn = tw + 16384;
    const _Float16* Pt   = tw + 24576;    // [128][64]
    const _Float16* Qt   = tw + 32768;

    // ---- zero D^T staging region: Dr_T,Di_T = 2 x [48][64] f16 = 12,288 B
    for (int t = tid; t < 768; t += 256)
        *(float4*)&Sh[t * 8] = (float4){0.f, 0.f, 0.f, 0.f};
    __syncthreads();

    // ---- stage D^T as f16 (rows = k-col, XOR swizzle keeps b128 reads 2-way)
    const float2* src = zm + (size_t)bc * 2112;
    for (int t = tid; t < 2112; t += 256) {
        int r = t / 33;
        int k = t - r * 33;
        float2 d = src[r * 33 + k];
        int sidx = (k * 64 + r) ^ ((k & 7) << 3);
        Sh[sidx]        = (_Float16)d.x;
        Sh[3072 + sidx] = (_Float16)d.y;
    }
    __syncthreads();

    // ---- phase 1 MFMA: wave handles m-tiles {2wv, 2wv+1} x n-tiles 0..2
    f32x4 aR[2][3], aI[2][3];
    #pragma unroll
    for (int i = 0; i < 2; ++i)
        #pragma unroll
        for (int j = 0; j < 3; ++j) {
            aR[i][j] = (f32x4){0.f, 0.f, 0.f, 0.f};
            aI[i][j] = (f32x4){0.f, 0.f, 0.f, 0.f};
        }
    #pragma unroll
    for (int ks = 0; ks < 2; ++ks) {
        const int ko = ks * 32 + quad * 8;
        f16x8 ac[2], ass[2], asn[2];
        #pragma unroll
        for (int mt = 0; mt < 2; ++mt) {
            const int m = (wv * 2 + mt) * 16 + m15;
            ac[mt]  = *(const f16x8*)&T1c[m * 64 + ko];
            ass[mt] = *(const f16x8*)&T1s[m * 64 + ko];
            asn[mt] = *(const f16x8*)&T1sn[m * 64 + ko];
        }
        #pragma unroll
        for (int nt = 0; nt < 3; ++nt) {
            const int n  = nt * 16 + m15;
            const int sb = (n * 64 + ko) ^ ((n & 7) << 3);
            f16x8 br = *(const f16x8*)&Sh[sb];
            f16x8 bi = *(const f16x8*)&Sh[3072 + sb];
            #pragma unroll
            for (int mt = 0; mt < 2; ++mt) {
                aR[mt][nt] = __builtin_amdgcn_mfma_f32_16x16x32_f16(ac[mt],  br, aR[mt][nt], 0, 0, 0);
                aR[mt][nt] = __builtin_amdgcn_mfma_f32_16x16x32_f16(asn[mt], bi, aR[mt][nt], 0, 0, 0);
                aI[mt][nt] = __builtin_amdgcn_mfma_f32_16x16x32_f16(ac[mt],  bi, aI[mt][nt], 0, 0, 0);
                aI[mt][nt] = __builtin_amdgcn_mfma_f32_16x16x32_f16(ass[mt], br, aI[mt][nt], 0, 0, 0);
            }
        }
    }
    __syncthreads();

    // ---- zero T region (full 32,768 B; cols 48..63 must be 0)
    for (int t = tid; t < 2048; t += 256)
        *(float4*)&Sh[t * 8] = (float4){0.f, 0.f, 0.f, 0.f};
    __syncthreads();

    // ---- write T (f16, swizzled): Tr at 0, Ti at f16-offset 8192.
    #pragma unroll
    for (int mt = 0; mt < 2; ++mt)
        #pragma unroll
        for (int nt = 0; nt < 3; ++nt)
            #pragma unroll
            for (int r = 0; r < 4; ++r) {
                const int h  = (wv * 2 + mt) * 16 + quad * 4 + r;
                const int k  = nt * 16 + m15;
                const int si = (h * 64 + k) ^ ((h & 7) << 3);
                Sh[si]        = (_Float16)aR[mt][nt][r];
                Sh[8192 + si] = (_Float16)aI[mt][nt][r];
            }
    __syncthreads();

    // ---- phase 2 MFMA + epilogue: wave handles m-tiles {2wv,2wv+1} x 8 n-tiles
    const size_t base = (size_t)bc * 16384;
    #pragma unroll
    for (int mt = 0; mt < 2; ++mt) {
        const int h0 = (wv * 2 + mt) * 16;
        f32x4 acc[8];
        #pragma unroll
        for (int nt = 0; nt < 8; ++nt) acc[nt] = (f32x4){0.f, 0.f, 0.f, 0.f};
        #pragma unroll
        for (int ks = 0; ks < 2; ++ks) {
            const int hh = h0 + m15;
            const int sa = (hh * 64 + ks * 32 + quad * 8) ^ ((hh & 7) << 3);
            f16x8 atr = *(const f16x8*)&Sh[sa];
            f16x8 ati = *(const f16x8*)&Sh[8192 + sa];
            #pragma unroll
            for (int nt = 0; nt < 8; ++nt) {
                const int go = (nt * 16 + m15) * 64 + ks * 32 + quad * 8;
                f16x8 bp = *(const f16x8*)&Pt[go];
                f16x8 bq = *(const f16x8*)&Qt[go];
                acc[nt] = __builtin_amdgcn_mfma_f32_16x16x32_f16(atr, bp, acc[nt], 0, 0, 0);
                acc[nt] = __builtin_amdgcn_mfma_f32_16x16x32_f16(ati, bq, acc[nt], 0, 0, 0);
            }
        }
        #pragma unroll
        for (int nt = 0; nt < 8; ++nt)
            #pragma unroll
            for (int r = 0; r < 4; ++r) {
                const int h  = h0 + quad * 4 + r;
                const int wc = nt * 16 + m15;
                size_t idx = base + (size_t)h * 128 + wc;
                yb[idx] = f2bf(x[idx] + acc[nt][r]);
            }
    }
}

// ---------------------------------------------------------------------------
// Kernel 3b: transpose yy_bf[b][c][p] -> yy_t[b][p][c] (bf16), 64x64 tiles.
// ---------------------------------------------------------------------------
__global__ __launch_bounds__(256) void k_tr(const unsigned short* __restrict__ yb,
                                            unsigned short* __restrict__ yt) {
    __shared__ float ts[64][65];   // [p][c]
    const int p0 = blockIdx.x * 64;
    const int c0 = blockIdx.y * 64;
    const int b  = blockIdx.z;
    const int t  = threadIdx.x;
    const int lane = t & 63;

    const unsigned short* src = yb + (((size_t)(b * 512 + c0 + lane)) << 14) + p0;
    #pragma unroll
    for (int cc = 0; cc < 2; ++cc) {
        int ch = (t >> 6) * 2 + cc;          // p-chunk 0..7
        us8 v = *(const us8*)&src[ch * 8];
        #pragma unroll
        for (int j = 0; j < 8; ++j)
            ts[ch * 8 + j][lane] = __uint_as_float((unsigned)v[j] << 16);
    }
    __syncthreads();

    const int pr   = t >> 2;
    const int coff = (t & 3) * 16;
    us8 o0v, o1v;
    #pragma unroll
    for (int i = 0; i < 8; ++i) o0v[i] = f2bf(ts[pr][coff + i]);
    #pragma unroll
    for (int i = 0; i < 8; ++i) o1v[i] = f2bf(ts[pr][coff + 8 + i]);
    unsigned short* dst = yt + ((size_t)(b * 16384 + p0 + pr)) * 512 + c0 + coff;
    *(us8*)&dst[0] = o0v;
    *(us8*)&dst[8] = o1v;
}

// ---------------------------------------------------------------------------
// Kernel 3c: fw fp32 -> bf16 (row-major [o][c] unchanged).
// ---------------------------------------------------------------------------
__global__ __launch_bounds__(256) void k_prep(const float* __restrict__ fw,
                                              unsigned short* __restrict__ fb) {
    int i = (blockIdx.x * 256 + threadIdx.x) * 4;
    float4 v = *(const float4*)&fw[i];
    ushort4 o;
    o.x = f2bf(v.x); o.y = f2bf(v.y); o.z = f2bf(v.z); o.w = f2bf(v.w);
    *(ushort4*)&fb[i] = o;
}

// ---------------------------------------------------------------------------
// Kernel 4: MFMA conv GEMM. out[b][o][p] = x[b][o][p] + sum_c fb[o][c]*yt[b][p][c]
// 128x128 tile, BK=32, 4 waves (2x2 of 64x64), mfma_f32_16x16x32_bf16.
// ---------------------------------------------------------------------------
__global__ __launch_bounds__(256) void k_gemm(const unsigned short* __restrict__ fb,
                                              const unsigned short* __restrict__ yt,
                                              const float* __restrict__ x,
                                              float* __restrict__ out) {
    __shared__ short Al[128 * 40];
    __shared__ short Bl[128 * 40];
    const int p0  = blockIdx.x * 128;
    const int o0  = blockIdx.y * 128;
    const int b   = blockIdx.z;
    const int tid = threadIdx.x;
    const int lane = tid & 63;
    const int w    = tid >> 6;
    const int wo = (w >> 1) * 64, wp = (w & 1) * 64;

    f32x4 acc[4][4];
    #pragma unroll
    for (int i = 0; i < 4; ++i)
        #pragma unroll
        for (int j = 0; j < 4; ++j)
            acc[i][j] = (f32x4){0.f, 0.f, 0.f, 0.f};

    const int m15 = lane & 15, quad = lane >> 4;

    for (int kc = 0; kc < 512; kc += 32) {
        __syncthreads();
        #pragma unroll
        for (int cc = 0; cc < 2; ++cc) {
            int ch = tid + cc * 256;          // 0..511
            int r  = ch >> 2;                 // row 0..127
            int pt = ch & 3;                  // 8-bf16 part
            *(s8bf*)&Al[r * 40 + pt * 8] =
                *(const s8bf*)&fb[(size_t)(o0 + r) * 512 + kc + pt * 8];
            *(s8bf*)&Bl[r * 40 + pt * 8] =
                *(const s8bf*)&yt[((size_t)(b * 16384 + p0 + r)) * 512 + kc + pt * 8];
        }
        __syncthreads();

        s8bf af[4], bfr[4];
        #pragma unroll
        for (int i = 0; i < 4; ++i) {
            af[i]  = *(const s8bf*)&Al[(wo + i * 16 + m15) * 40 + quad * 8];
            bfr[i] = *(const s8bf*)&Bl[(wp + i * 16 + m15) * 40 + quad * 8];
        }
        #pragma unroll
        for (int mi = 0; mi < 4; ++mi)
            #pragma unroll
            for (int ni = 0; ni < 4; ++ni)
                acc[mi][ni] = __builtin_amdgcn_mfma_f32_16x16x32_bf16(
                    af[mi], bfr[ni], acc[mi][ni], 0, 0, 0);
    }

    #pragma unroll
    for (int mi = 0; mi < 4; ++mi) {
        #pragma unroll
        for (int ni = 0; ni < 4; ++ni) {
            #pragma unroll
            for (int r = 0; r < 4; ++r) {
                int o = o0 + wo + mi * 16 + quad * 4 + r;
                int p = p0 + wp + ni * 16 + m15;
                size_t idx = (((size_t)(b * 512 + o)) << 14) + p;
                out[idx] = x[idx] + acc[mi][ni][r];
            }
        }
    }
}

// ---------------------------------------------------------------------------
extern "C" void kernel_launch(void* const* d_in, const int* in_sizes, int n_in,
                              void* d_out, int out_size, void* d_ws, size_t ws_size,
                              hipStream_t stream) {
    const float* x   = (const float*)d_in[0];
    const float* w1r = (const float*)d_in[1];
    const float* w1i = (const float*)d_in[2];
    const float* b1r = (const float*)d_in[3];
    const float* b1i = (const float*)d_in[4];
    const float* w2r = (const float*)d_in[5];
    const float* w2i = (const float*)d_in[6];
    const float* b2r = (const float*)d_in[7];
    const float* b2i = (const float*)d_in[8];
    const float* fw  = (const float*)d_in[9];
    float* out = (float*)d_out;

    char* ws = (char*)d_ws;
    float2* zm          = (float2*)ws;                         // [0, 34.6MB)
    unsigned short* ybf = (unsigned short*)(ws + 34603008);    // dead after k_tr
    unsigned short* yt  = (unsigned short*)(ws + 101711872);   // [101.7MB, 168.8MB)
    unsigned short* fb  = (unsigned short*)(ws + 34603008);    // written after k_tr
    _Float16* tw        = (_Float16*)(ws + 168665088);         // tail of yt region

    k_tw<<<32, 256, 0, stream>>>(tw);
    k_fwdm<<<2048, 256, 0, stream>>>(x, tw, zm);
    k_mlp<<<dim3(33, 8, 4), 256, 0, stream>>>(w1r, w1i, b1r, b1i,
                                              w2r, w2i, b2r, b2i, zm);
    k_inv<<<2048, 256, 0, stream>>>(zm, x, tw, ybf);
    k_tr<<<dim3(256, 8, 4), 256, 0, stream>>>(ybf, yt);
    k_prep<<<256, 256, 0, stream>>>(fw, fb);
    k_gemm<<<dim3(128, 4, 4), 256, 0, stream>>>(fb, yt, x, out);
}

// Round 7
// 527.653 us; speedup vs baseline: 2.1395x; 1.0317x over previous
//
#include <hip/hip_runtime.h>
#include <math.h>

// AFNO2D: out = x + fuse_w @ (x + irfft2(masked_delta))
// masked_delta = (softshrink(W2*gelu(W1*Z+b1)+b2) - Z) on modes [0:64, 0:33].
// Only the 64x33 masked modes are transformed (irfft2(rfft2(x)) == x).
// Forward DFT: fused single kernel, fp16 MFMA vs precomputed twiddle tables.
// Block-diag MLP: fused single kernel (both layers), fp16 MFMA.
// Inverse DFT: fp16 MFMA + coalesced LDS-bounce epilogue. Conv: bf16 MFMA GEMM.
//
// Workspace layout (bytes), peak 168,820,736:
//   zm    @ 0          : B*C*64*33 float2  = 34,603,008  (Z modes, then delta in-place)
//   yy_bf @ 34,603,008 : B*C*128*128 bf16  = 67,108,864  (y = x + D, bf16; dead after k_tr)
//   yy_t  @101,711,872 : B*16384*512 bf16  = 67,108,864  (y transposed [b][p][c])
//   fw_bf @ 34,603,008 : 512*512 bf16      = 524,288     (written after k_tr)
//   tw    @168,665,088 : 77,824 f16        = 155,648     (twiddles; tail of yt region:
//                        only k_tr overwrites it, which runs after k_fwdm/k_inv)
//
// tw f16 offsets: T1c 0, T1s 8192, T1sn 16384, Pt 24576, Qt 32768 (inv, [128][64])
//                 FWr 40960, FWi 47104 ([48][128]); FHc 53248, FHs 61440,
//                 FHsn 69632 ([64][128]).

#define LAMB 0.01f
#define TWO_PI_OVER_128 0.049087385212340517f

typedef __attribute__((ext_vector_type(8))) short s8bf;           // 8 bf16 (4 VGPRs)
typedef __attribute__((ext_vector_type(8))) unsigned short us8;
typedef __attribute__((ext_vector_type(4))) float f32x4;
typedef __attribute__((ext_vector_type(8))) _Float16 f16x8;       // 8 f16 (4 VGPRs)

static __device__ __forceinline__ float gelu_exact(float v) {
    return 0.5f * v * (1.0f + erff(v * 0.7071067811865475f));
}
static __device__ __forceinline__ float softshrink01(float v) {
    float a = fabsf(v) - LAMB;
    a = a > 0.0f ? a : 0.0f;
    return v >= 0.0f ? a : -a;
}
static __device__ __forceinline__ unsigned short f2bf(float f) {
    union { float f; unsigned int u; } v; v.f = f;
    unsigned int r = v.u + 0x7FFFu + ((v.u >> 16) & 1u);   // RNE
    return (unsigned short)(r >> 16);
}

// ---------------------------------------------------------------------------
// Kernel 0: precompute all twiddle tables (f16).
// ---------------------------------------------------------------------------
__global__ __launch_bounds__(256) void k_tw(_Float16* __restrict__ tw) {
    const int idx = blockIdx.x * 256 + threadIdx.x;   // 0..8191
    {
        const int h = idx >> 6, r = idx & 63;
        float ss, sc;
        sincosf((float)((h * r) & 127) * TWO_PI_OVER_128, &ss, &sc);
        tw[idx]         = (_Float16)sc;
        tw[8192 + idx]  = (_Float16)ss;
        tw[16384 + idx] = (_Float16)(-ss);
        const float wk = (r == 0) ? 0.5f : 1.0f;
        const float pv = (r <= 32) ? wk * sc * 0.015625f : 0.f;
        const float qv = (r <= 32) ? -wk * ss * 0.015625f : 0.f;
        tw[24576 + idx] = (_Float16)pv;
        tw[32768 + idx] = (_Float16)qv;
    }
    if (idx < 6144) {                                  // FW [48][128]
        const int k = idx >> 7, w = idx & 127;
        float ss, sc;
        sincosf((float)((w * k) & 127) * TWO_PI_OVER_128, &ss, &sc);
        tw[40960 + idx] = (_Float16)(sc * 0.0078125f);
        tw[47104 + idx] = (_Float16)(-ss * 0.0078125f);
    }
    {                                                  // FH [64][128]
        const int r = idx >> 7, h = idx & 127;
        float ss, sc;
        sincosf((float)((r * h) & 127) * TWO_PI_OVER_128, &ss, &sc);
        tw[53248 + idx] = (_Float16)sc;
        tw[61440 + idx] = (_Float16)ss;
        tw[69632 + idx] = (_Float16)(-ss);
    }
}

// ---------------------------------------------------------------------------
// Kernel 1: fused forward rfft2 (masked 64x33 modes) via fp16 MFMA.
// ---------------------------------------------------------------------------
__global__ __launch_bounds__(256) void k_fwdm(const float* __restrict__ x,
                                              const _Float16* __restrict__ tw,
                                              float2* __restrict__ zm) {
    __shared__ _Float16 Xs[16384];   // 32,768 B
    const int bc   = blockIdx.x;
    const int tid  = threadIdx.x;
    const int lane = tid & 63;
    const int wv   = tid >> 6;
    const int m15  = lane & 15;
    const int quad = lane >> 4;

    const _Float16* FWr  = tw + 40960;   // [48][128]
    const _Float16* FWi  = tw + 47104;
    const _Float16* FHc  = tw + 53248;   // [64][128]
    const _Float16* FHs  = tw + 61440;
    const _Float16* FHsn = tw + 69632;

    // ---- stage x -> f16, swizzled: idx = h*128+w ^ ((h&7)<<3)
    const float* xim = x + (size_t)bc * 16384;
    for (int t = tid; t < 2048; t += 256) {
        const int h  = t >> 4;
        const int w0 = (t & 15) * 8;
        float4 a = *(const float4*)&xim[h * 128 + w0];
        float4 b = *(const float4*)&xim[h * 128 + w0 + 4];
        f16x8 v;
        v[0] = (_Float16)a.x; v[1] = (_Float16)a.y;
        v[2] = (_Float16)a.z; v[3] = (_Float16)a.w;
        v[4] = (_Float16)b.x; v[5] = (_Float16)b.y;
        v[6] = (_Float16)b.z; v[7] = (_Float16)b.w;
        *(f16x8*)&Xs[(h * 128 + w0) ^ ((h & 7) << 3)] = v;
    }
    __syncthreads();

    // ---- phase A: m-tiles {2wv, 2wv+1}, n-tiles 0..2, K=128 (w)
    f32x4 yR[2][3], yI[2][3];
    #pragma unroll
    for (int i = 0; i < 2; ++i)
        #pragma unroll
        for (int j = 0; j < 3; ++j) {
            yR[i][j] = (f32x4){0.f, 0.f, 0.f, 0.f};
            yI[i][j] = (f32x4){0.f, 0.f, 0.f, 0.f};
        }
    #pragma unroll
    for (int ks = 0; ks < 4; ++ks) {
        const int ko = ks * 32 + quad * 8;
        f16x8 af[2];
        #pragma unroll
        for (int mt = 0; mt < 2; ++mt) {
            const int h = (wv * 2 + mt) * 16 + m15;
            af[mt] = *(const f16x8*)&Xs[(h * 128 + ko) ^ ((h & 7) << 3)];
        }
        #pragma unroll
        for (int nt = 0; nt < 3; ++nt) {
            const int n = nt * 16 + m15;
            f16x8 br = *(const f16x8*)&FWr[n * 128 + ko];
            f16x8 bi = *(const f16x8*)&FWi[n * 128 + ko];
            #pragma unroll
            for (int mt = 0; mt < 2; ++mt) {
                yR[mt][nt] = __builtin_amdgcn_mfma_f32_16x16x32_f16(af[mt], br, yR[mt][nt], 0, 0, 0);
                yI[mt][nt] = __builtin_amdgcn_mfma_f32_16x16x32_f16(af[mt], bi, yI[mt][nt], 0, 0, 0);
            }
        }
    }
    __syncthreads();             // all phase-A reads of Xs done

    // ---- write Y^T (f16, swizzled): Yr at 0, Yi at 8192; idx=k*128+h ^((k&7)<<3)
    #pragma unroll
    for (int mt = 0; mt < 2; ++mt)
        #pragma unroll
        for (int nt = 0; nt < 3; ++nt)
            #pragma unroll
            for (int r = 0; r < 4; ++r) {
                const int h = (wv * 2 + mt) * 16 + quad * 4 + r;
                const int k = nt * 16 + m15;
                const int si = (k * 128 + h) ^ ((k & 7) << 3);
                Xs[si]        = (_Float16)yR[mt][nt][r];
                Xs[8192 + si] = (_Float16)yI[mt][nt][r];
            }
    __syncthreads();

    // ---- phase B: m-tile = wv (r in [0,64)), n-tiles 0..2, K=128 (h)
    f32x4 zR[3], zI[3];
    #pragma unroll
    for (int j = 0; j < 3; ++j) {
        zR[j] = (f32x4){0.f, 0.f, 0.f, 0.f};
        zI[j] = (f32x4){0.f, 0.f, 0.f, 0.f};
    }
    const int rr = wv * 16 + m15;
    #pragma unroll
    for (int ks = 0; ks < 4; ++ks) {
        const int ko = ks * 32 + quad * 8;
        f16x8 ac  = *(const f16x8*)&FHc[rr * 128 + ko];
        f16x8 as2 = *(const f16x8*)&FHs[rr * 128 + ko];
        f16x8 asn = *(const f16x8*)&FHsn[rr * 128 + ko];
        #pragma unroll
        for (int nt = 0; nt < 3; ++nt) {
            const int n  = nt * 16 + m15;
            const int si = (n * 128 + ko) ^ ((n & 7) << 3);
            f16x8 br = *(const f16x8*)&Xs[si];
            f16x8 bi = *(const f16x8*)&Xs[8192 + si];
            zR[nt] = __builtin_amdgcn_mfma_f32_16x16x32_f16(ac,  br, zR[nt], 0, 0, 0);
            zR[nt] = __builtin_amdgcn_mfma_f32_16x16x32_f16(as2, bi, zR[nt], 0, 0, 0);
            zI[nt] = __builtin_amdgcn_mfma_f32_16x16x32_f16(ac,  bi, zI[nt], 0, 0, 0);
            zI[nt] = __builtin_amdgcn_mfma_f32_16x16x32_f16(asn, br, zI[nt], 0, 0, 0);
        }
    }

    // ---- store Z[r][k], k<33
    float2* zrow = zm + (size_t)bc * 2112;
    #pragma unroll
    for (int nt = 0; nt < 3; ++nt) {
        const int k = nt * 16 + m15;
        if (k < 33) {
            #pragma unroll
            for (int r = 0; r < 4; ++r) {
                const int rw = wv * 16 + quad * 4 + r;
                zrow[rw * 33 + k] = make_float2(zR[nt][r], zI[nt][r]);
            }
        }
    }
}

// ---------------------------------------------------------------------------
// Kernel 2: fused block-diag complex MLP via fp16 MFMA; zm <- delta in place.
// ---------------------------------------------------------------------------
__global__ __launch_bounds__(256) void k_mlp(const float* __restrict__ w1r_g,
                                             const float* __restrict__ w1i_g,
                                             const float* __restrict__ b1r_g,
                                             const float* __restrict__ b1i_g,
                                             const float* __restrict__ w2r_g,
                                             const float* __restrict__ w2i_g,
                                             const float* __restrict__ b2r_g,
                                             const float* __restrict__ b2i_g,
                                             float2* __restrict__ zm) {
    __shared__ _Float16 S[32768];   // 65,536 B
    // f16 offsets in S:
    //  W1R 0, W1I 4096, W1N 8192 (=-W1i), W2R 12288, W2I 16384, W2N 20480,
    //  HR 24576, HI 28672.  W tables are [j][i] (=W^T), swizzled ^((j&7)<<3).
    const int p0  = blockIdx.x * 64;
    const int nb  = blockIdx.y;
    const int b   = blockIdx.z;
    const int tid = threadIdx.x;
    const int lane = tid & 63;
    const int wv   = tid >> 6;
    const int m15  = lane & 15;
    const int quad = lane >> 4;

    // ---- stage W^T as f16 (thread t: column j = t&63, i-block = (t>>6)*16)
    {
        const int j  = tid & 63;
        const int i0 = (tid >> 6) * 16;
        const int swz = (j & 7) << 3;
        #pragma unroll
        for (int tbl = 0; tbl < 4; ++tbl) {
            const float* src = (tbl == 0) ? w1r_g : (tbl == 1) ? w1i_g
                             : (tbl == 2) ? w2r_g : w2i_g;
            src += nb * 4096;
            f16x8 v0, v1, n0, n1;
            #pragma unroll
            for (int ii = 0; ii < 8; ++ii) {
                float a = src[(i0 + ii) * 64 + j];
                float c = src[(i0 + 8 + ii) * 64 + j];
                v0[ii] = (_Float16)a; n0[ii] = (_Float16)(-a);
                v1[ii] = (_Float16)c; n1[ii] = (_Float16)(-c);
            }
            const int base = (tbl == 0) ? 0 : (tbl == 1) ? 4096
                           : (tbl == 2) ? 12288 : 16384;
            *(f16x8*)&S[base + ((j * 64 + i0) ^ swz)]     = v0;
            *(f16x8*)&S[base + ((j * 64 + i0 + 8) ^ swz)] = v1;
            if (tbl == 1) {
                *(f16x8*)&S[8192 + ((j * 64 + i0) ^ swz)]     = n0;
                *(f16x8*)&S[8192 + ((j * 64 + i0 + 8) ^ swz)] = n1;
            } else if (tbl == 3) {
                *(f16x8*)&S[20480 + ((j * 64 + i0) ^ swz)]     = n0;
                *(f16x8*)&S[20480 + ((j * 64 + i0 + 8) ^ swz)] = n1;
            }
        }
    }

    // ---- layer-1 A-frags straight from global: Z[p][i], p=p0+wv*16+m15
    const float2* zb = zm + (size_t)(b * 512 + nb * 64) * 2112;
    const int p = p0 + wv * 16 + m15;
    f16x8 azr[2], azi[2];
    #pragma unroll
    for (int ks = 0; ks < 2; ++ks) {
        #pragma unroll
        for (int jj = 0; jj < 8; ++jj) {
            float2 z = zb[(size_t)(ks * 32 + quad * 8 + jj) * 2112 + p];
            azr[ks][jj] = (_Float16)z.x;
            azi[ks][jj] = (_Float16)z.y;
        }
    }
    __syncthreads();   // W tables staged

    // ---- layer 1 MFMA: Hr = Zr@W1r + Zi@W1n ; Hi = Zr@W1i + Zi@W1r
    f32x4 hr[4], hi[4];
    #pragma unroll
    for (int nt = 0; nt < 4; ++nt) {
        hr[nt] = (f32x4){0.f, 0.f, 0.f, 0.f};
        hi[nt] = (f32x4){0.f, 0.f, 0.f, 0.f};
    }
    #pragma unroll
    for (int ks = 0; ks < 2; ++ks) {
        #pragma unroll
        for (int nt = 0; nt < 4; ++nt) {
            const int n  = nt * 16 + m15;
            const int sb = (n * 64 + ks * 32 + quad * 8) ^ ((n & 7) << 3);
            f16x8 bwr = *(const f16x8*)&S[sb];
            f16x8 bwi = *(const f16x8*)&S[4096 + sb];
            f16x8 bwn = *(const f16x8*)&S[8192 + sb];
            hr[nt] = __builtin_amdgcn_mfma_f32_16x16x32_f16(azr[ks], bwr, hr[nt], 0, 0, 0);
            hr[nt] = __builtin_amdgcn_mfma_f32_16x16x32_f16(azi[ks], bwn, hr[nt], 0, 0, 0);
            hi[nt] = __builtin_amdgcn_mfma_f32_16x16x32_f16(azr[ks], bwi, hi[nt], 0, 0, 0);
            hi[nt] = __builtin_amdgcn_mfma_f32_16x16x32_f16(azi[ks], bwr, hi[nt], 0, 0, 0);
        }
    }

    // ---- bias + exact GELU -> H (f16, [m][j] swizzled; wave-local rows)
    #pragma unroll
    for (int nt = 0; nt < 4; ++nt) {
        const int jj = nt * 16 + m15;
        const float br = b1r_g[nb * 64 + jj];
        const float bi = b1i_g[nb * 64 + jj];
        #pragma unroll
        for (int r = 0; r < 4; ++r) {
            const int m  = wv * 16 + quad * 4 + r;
            const int si = (m * 64 + jj) ^ ((m & 7) << 3);
            S[24576 + si] = (_Float16)gelu_exact(hr[nt][r] + br);
            S[28672 + si] = (_Float16)gelu_exact(hi[nt][r] + bi);
        }
    }
    __syncthreads();

    // ---- layer-2 A-frags from LDS H
    f16x8 ahr[2], ahi[2];
    #pragma unroll
    for (int ks = 0; ks < 2; ++ks) {
        const int m  = wv * 16 + m15;
        const int sa = (m * 64 + ks * 32 + quad * 8) ^ ((m & 7) << 3);
        ahr[ks] = *(const f16x8*)&S[24576 + sa];
        ahi[ks] = *(const f16x8*)&S[28672 + sa];
    }

    // ---- layer 2 MFMA: Yr = Hr@W2r + Hi@W2n ; Yi = Hr@W2i + Hi@W2r
    f32x4 yr[4], yi[4];
    #pragma unroll
    for (int nt = 0; nt < 4; ++nt) {
        yr[nt] = (f32x4){0.f, 0.f, 0.f, 0.f};
        yi[nt] = (f32x4){0.f, 0.f, 0.f, 0.f};
    }
    #pragma unroll
    for (int ks = 0; ks < 2; ++ks) {
        #pragma unroll
        for (int nt = 0; nt < 4; ++nt) {
            const int n  = nt * 16 + m15;
            const int sb = (n * 64 + ks * 32 + quad * 8) ^ ((n & 7) << 3);
            f16x8 bwr = *(const f16x8*)&S[12288 + sb];
            f16x8 bwi = *(const f16x8*)&S[16384 + sb];
            f16x8 bwn = *(const f16x8*)&S[20480 + sb];
            yr[nt] = __builtin_amdgcn_mfma_f32_16x16x32_f16(ahr[ks], bwr, yr[nt], 0, 0, 0);
            yr[nt] = __builtin_amdgcn_mfma_f32_16x16x32_f16(ahi[ks], bwn, yr[nt], 0, 0, 0);
            yi[nt] = __builtin_amdgcn_mfma_f32_16x16x32_f16(ahr[ks], bwi, yi[nt], 0, 0, 0);
            yi[nt] = __builtin_amdgcn_mfma_f32_16x16x32_f16(ahi[ks], bwr, yi[nt], 0, 0, 0);
        }
    }

    // ---- epilogue: bias, softshrink, delta = ss(y) - z; write zm in place
    float2* zw = zm + (size_t)(b * 512 + nb * 64) * 2112;
    #pragma unroll
    for (int nt = 0; nt < 4; ++nt) {
        const int jj = nt * 16 + m15;
        const float br = b2r_g[nb * 64 + jj];
        const float bi = b2i_g[nb * 64 + jj];
        #pragma unroll
        for (int r = 0; r < 4; ++r) {
            const int pp = p0 + wv * 16 + quad * 4 + r;
            const size_t gi = (size_t)jj * 2112 + pp;
            float2 z = zw[gi];
            zw[gi] = make_float2(softshrink01(yr[nt][r] + br) - z.x,
                                 softshrink01(yi[nt][r] + bi) - z.y);
        }
    }
}

// ---------------------------------------------------------------------------
// Kernel 3: inverse irfft2 on masked modes via fp16 MFMA; yy_bf = bf16(x + y).
//   phase 1: T = twiddle@D (M=128,N=48,K=64); T -> LDS f16 swizzled.
//   phase 2: A-frags for BOTH m-tiles pre-read to registers; T region then
//   reused as f32 bounce strip [64][132] so the x-read / yb-write pass is
//   fully coalesced (2 KB/1 KB per wave-instr vs 64/32 B segments before —
//   round-6 counters showed WRITE_SIZE 84 MB vs 67 ideal from partial lines).
// LDS 33,792 B -> 4 blocks/CU (16 waves, 50%).
// ---------------------------------------------------------------------------
__global__ __launch_bounds__(256) void k_inv(const float2* __restrict__ zm,
                                             const float* __restrict__ x,
                                             const _Float16* __restrict__ tw,
                                             unsigned short* __restrict__ yb) {
    __shared__ char SB[33792];       // max(32768 f16 region, 64*132*4 bounce)
    _Float16* Sh = (_Float16*)SB;    // 16384 f16
    float*    Sb = (float*)SB;       // bounce [64][132]
    const int bc   = blockIdx.x;
    const int tid  = threadIdx.x;
    const int lane = tid & 63;
    const int wv   = tid >> 6;
    const int m15  = lane & 15;
    const int quad = lane >> 4;

    const _Float16* T1c  = tw;            // [128][64]
    const _Float16* T1s  = tw + 8192;
    const _Float16* T1sn = tw + 16384;
    const _Float16* Pt   = tw + 24576;    // [128][64]
    const _Float16* Qt   = tw + 32768;

    // ---- zero D^T staging region: Dr_T,Di_T = 2 x [48][64] f16 = 12,288 B
    for (int t = tid; t < 768; t += 256)
        *(float4*)&Sh[t * 8] = (float4){0.f, 0.f, 0.f, 0.f};
    __syncthreads();

    // ---- stage D^T as f16 (rows = k-col, XOR swizzle keeps b128 reads 2-way)
    const float2* src = zm + (size_t)bc * 2112;
    for (int t = tid; t < 2112; t += 256) {
        int r = t / 33;
        int k = t - r * 33;
        float2 d = src[t];
        int sidx = (k * 64 + r) ^ ((k & 7) << 3);
        Sh[sidx]        = (_Float16)d.x;
        Sh[3072 + sidx] = (_Float16)d.y;
    }
    __syncthreads();

    // ---- phase 1 MFMA: wave handles m-tiles {2wv, 2wv+1} x n-tiles 0..2
    f32x4 aR[2][3], aI[2][3];
    #pragma unroll
    for (int i = 0; i < 2; ++i)
        #pragma unroll
        for (int j = 0; j < 3; ++j) {
            aR[i][j] = (f32x4){0.f, 0.f, 0.f, 0.f};
            aI[i][j] = (f32x4){0.f, 0.f, 0.f, 0.f};
        }
    #pragma unroll
    for (int ks = 0; ks < 2; ++ks) {
        const int ko = ks * 32 + quad * 8;
        f16x8 ac[2], ass[2], asn[2];
        #pragma unroll
        for (int mt = 0; mt < 2; ++mt) {
            const int m = (wv * 2 + mt) * 16 + m15;
            ac[mt]  = *(const f16x8*)&T1c[m * 64 + ko];
            ass[mt] = *(const f16x8*)&T1s[m * 64 + ko];
            asn[mt] = *(const f16x8*)&T1sn[m * 64 + ko];
        }
        #pragma unroll
        for (int nt = 0; nt < 3; ++nt) {
            const int n  = nt * 16 + m15;
            const int sb = (n * 64 + ko) ^ ((n & 7) << 3);
            f16x8 br = *(const f16x8*)&Sh[sb];
            f16x8 bi = *(const f16x8*)&Sh[3072 + sb];
            #pragma unroll
            for (int mt = 0; mt < 2; ++mt) {
                aR[mt][nt] = __builtin_amdgcn_mfma_f32_16x16x32_f16(ac[mt],  br, aR[mt][nt], 0, 0, 0);
                aR[mt][nt] = __builtin_amdgcn_mfma_f32_16x16x32_f16(asn[mt], bi, aR[mt][nt], 0, 0, 0);
                aI[mt][nt] = __builtin_amdgcn_mfma_f32_16x16x32_f16(ac[mt],  bi, aI[mt][nt], 0, 0, 0);
                aI[mt][nt] = __builtin_amdgcn_mfma_f32_16x16x32_f16(ass[mt], br, aI[mt][nt], 0, 0, 0);
            }
        }
    }
    __syncthreads();

    // ---- zero T region (full 32,768 B; cols 48..63 must be 0)
    for (int t = tid; t < 2048; t += 256)
        *(float4*)&Sh[t * 8] = (float4){0.f, 0.f, 0.f, 0.f};
    __syncthreads();

    // ---- write T (f16, swizzled): Tr at 0, Ti at f16-offset 8192.
    #pragma unroll
    for (int mt = 0; mt < 2; ++mt)
        #pragma unroll
        for (int nt = 0; nt < 3; ++nt)
            #pragma unroll
            for (int r = 0; r < 4; ++r) {
                const int h  = (wv * 2 + mt) * 16 + quad * 4 + r;
                const int k  = nt * 16 + m15;
                const int si = (h * 64 + k) ^ ((h & 7) << 3);
                Sh[si]        = (_Float16)aR[mt][nt][r];
                Sh[8192 + si] = (_Float16)aI[mt][nt][r];
            }
    __syncthreads();

    // ---- pre-read ALL phase-2 A-frags (both m-tiles) so T region can be
    // reused as the f32 bounce. __syncthreads drains lgkm -> reads complete.
    f16x8 atr[2][2], ati[2][2];   // [mt][ks]
    #pragma unroll
    for (int mt = 0; mt < 2; ++mt) {
        const int hh = (wv * 2 + mt) * 16 + m15;
        #pragma unroll
        for (int ks = 0; ks < 2; ++ks) {
            const int sa = (hh * 64 + ks * 32 + quad * 8) ^ ((hh & 7) << 3);
            atr[mt][ks] = *(const f16x8*)&Sh[sa];
            ati[mt][ks] = *(const f16x8*)&Sh[8192 + sa];
        }
    }
    __syncthreads();

    // ---- phase 2 per m-tile: MFMA -> bounce strip -> coalesced epilogue
    const size_t base = (size_t)bc * 16384;
    #pragma unroll
    for (int mt = 0; mt < 2; ++mt) {
        f32x4 acc[8];
        #pragma unroll
        for (int nt = 0; nt < 8; ++nt) acc[nt] = (f32x4){0.f, 0.f, 0.f, 0.f};
        #pragma unroll
        for (int ks = 0; ks < 2; ++ks) {
            #pragma unroll
            for (int nt = 0; nt < 8; ++nt) {
                const int go = (nt * 16 + m15) * 64 + ks * 32 + quad * 8;
                f16x8 bp = *(const f16x8*)&Pt[go];
                f16x8 bq = *(const f16x8*)&Qt[go];
                acc[nt] = __builtin_amdgcn_mfma_f32_16x16x32_f16(atr[mt][ks], bp, acc[nt], 0, 0, 0);
                acc[nt] = __builtin_amdgcn_mfma_f32_16x16x32_f16(ati[mt][ks], bq, acc[nt], 0, 0, 0);
            }
        }
        // bounce write: wave wv's 16 rows at strip rows [wv*16, wv*16+16)
        // banks: quad rows offset 16 words -> 2-way (free); stride 132.
        #pragma unroll
        for (int nt = 0; nt < 8; ++nt)
            #pragma unroll
            for (int r = 0; r < 4; ++r)
                Sb[(wv * 16 + quad * 4 + r) * 132 + nt * 16 + m15] = acc[nt][r];
        __syncthreads();

        // coalesced pass: 64 rows x 128 cols; lane handles 8 consecutive floats
        for (int it = 0; it < 4; ++it) {
            const int off = (it * 256 + tid) * 8;       // 0..8191
            const int rbl = off >> 7;                   // bounce row 0..63
            const int col = off & 127;
            const int h   = ((rbl >> 4) * 2 + mt) * 16 + (rbl & 15);
            const size_t gx = base + (size_t)h * 128 + col;
            float4 s0 = *(const float4*)&Sb[rbl * 132 + col];
            float4 s1 = *(const float4*)&Sb[rbl * 132 + col + 4];
            float4 x0 = *(const float4*)&x[gx];
            float4 x1 = *(const float4*)&x[gx + 4];
            us8 o;
            o[0] = f2bf(x0.x + s0.x); o[1] = f2bf(x0.y + s0.y);
            o[2] = f2bf(x0.z + s0.z); o[3] = f2bf(x0.w + s0.w);
            o[4] = f2bf(x1.x + s1.x); o[5] = f2bf(x1.y + s1.y);
            o[6] = f2bf(x1.z + s1.z); o[7] = f2bf(x1.w + s1.w);
            *(us8*)&yb[gx] = o;
        }
        __syncthreads();
    }
}

// ---------------------------------------------------------------------------
// Kernel 3b: transpose yy_bf[b][c][p] -> yy_t[b][p][c] (bf16), 64x64 tiles.
// ---------------------------------------------------------------------------
__global__ __launch_bounds__(256) void k_tr(const unsigned short* __restrict__ yb,
                                            unsigned short* __restrict__ yt) {
    __shared__ float ts[64][65];   // [p][c]
    const int p0 = blockIdx.x * 64;
    const int c0 = blockIdx.y * 64;
    const int b  = blockIdx.z;
    const int t  = threadIdx.x;
    const int lane = t & 63;

    const unsigned short* src = yb + (((size_t)(b * 512 + c0 + lane)) << 14) + p0;
    #pragma unroll
    for (int cc = 0; cc < 2; ++cc) {
        int ch = (t >> 6) * 2 + cc;          // p-chunk 0..7
        us8 v = *(const us8*)&src[ch * 8];
        #pragma unroll
        for (int j = 0; j < 8; ++j)
            ts[ch * 8 + j][lane] = __uint_as_float((unsigned)v[j] << 16);
    }
    __syncthreads();

    const int pr   = t >> 2;
    const int coff = (t & 3) * 16;
    us8 o0v, o1v;
    #pragma unroll
    for (int i = 0; i < 8; ++i) o0v[i] = f2bf(ts[pr][coff + i]);
    #pragma unroll
    for (int i = 0; i < 8; ++i) o1v[i] = f2bf(ts[pr][coff + 8 + i]);
    unsigned short* dst = yt + ((size_t)(b * 16384 + p0 + pr)) * 512 + c0 + coff;
    *(us8*)&dst[0] = o0v;
    *(us8*)&dst[8] = o1v;
}

// ---------------------------------------------------------------------------
// Kernel 3c: fw fp32 -> bf16 (row-major [o][c] unchanged).
// ---------------------------------------------------------------------------
__global__ __launch_bounds__(256) void k_prep(const float* __restrict__ fw,
                                              unsigned short* __restrict__ fb) {
    int i = (blockIdx.x * 256 + threadIdx.x) * 4;
    float4 v = *(const float4*)&fw[i];
    ushort4 o;
    o.x = f2bf(v.x); o.y = f2bf(v.y); o.z = f2bf(v.z); o.w = f2bf(v.w);
    *(ushort4*)&fb[i] = o;
}

// ---------------------------------------------------------------------------
// Kernel 4: MFMA conv GEMM. out[b][o][p] = x[b][o][p] + sum_c fb[o][c]*yt[b][p][c]
// 128x128 tile, BK=32, 4 waves (2x2 of 64x64), mfma_f32_16x16x32_bf16.
// ---------------------------------------------------------------------------
__global__ __launch_bounds__(256) void k_gemm(const unsigned short* __restrict__ fb,
                                              const unsigned short* __restrict__ yt,
                                              const float* __restrict__ x,
                                              float* __restrict__ out) {
    __shared__ short Al[128 * 40];
    __shared__ short Bl[128 * 40];
    const int p0  = blockIdx.x * 128;
    const int o0  = blockIdx.y * 128;
    const int b   = blockIdx.z;
    const int tid = threadIdx.x;
    const int lane = tid & 63;
    const int w    = tid >> 6;
    const int wo = (w >> 1) * 64, wp = (w & 1) * 64;

    f32x4 acc[4][4];
    #pragma unroll
    for (int i = 0; i < 4; ++i)
        #pragma unroll
        for (int j = 0; j < 4; ++j)
            acc[i][j] = (f32x4){0.f, 0.f, 0.f, 0.f};

    const int m15 = lane & 15, quad = lane >> 4;

    for (int kc = 0; kc < 512; kc += 32) {
        __syncthreads();
        #pragma unroll
        for (int cc = 0; cc < 2; ++cc) {
            int ch = tid + cc * 256;          // 0..511
            int r  = ch >> 2;                 // row 0..127
            int pt = ch & 3;                  // 8-bf16 part
            *(s8bf*)&Al[r * 40 + pt * 8] =
                *(const s8bf*)&fb[(size_t)(o0 + r) * 512 + kc + pt * 8];
            *(s8bf*)&Bl[r * 40 + pt * 8] =
                *(const s8bf*)&yt[((size_t)(b * 16384 + p0 + r)) * 512 + kc + pt * 8];
        }
        __syncthreads();

        s8bf af[4], bfr[4];
        #pragma unroll
        for (int i = 0; i < 4; ++i) {
            af[i]  = *(const s8bf*)&Al[(wo + i * 16 + m15) * 40 + quad * 8];
            bfr[i] = *(const s8bf*)&Bl[(wp + i * 16 + m15) * 40 + quad * 8];
        }
        #pragma unroll
        for (int mi = 0; mi < 4; ++mi)
            #pragma unroll
            for (int ni = 0; ni < 4; ++ni)
                acc[mi][ni] = __builtin_amdgcn_mfma_f32_16x16x32_bf16(
                    af[mi], bfr[ni], acc[mi][ni], 0, 0, 0);
    }

    #pragma unroll
    for (int mi = 0; mi < 4; ++mi) {
        #pragma unroll
        for (int ni = 0; ni < 4; ++ni) {
            #pragma unroll
            for (int r = 0; r < 4; ++r) {
                int o = o0 + wo + mi * 16 + quad * 4 + r;
                int p = p0 + wp + ni * 16 + m15;
                size_t idx = (((size_t)(b * 512 + o)) << 14) + p;
                out[idx] = x[idx] + acc[mi][ni][r];
            }
        }
    }
}

// ---------------------------------------------------------------------------
extern "C" void kernel_launch(void* const* d_in, const int* in_sizes, int n_in,
                              void* d_out, int out_size, void* d_ws, size_t ws_size,
                              hipStream_t stream) {
    const float* x   = (const float*)d_in[0];
    const float* w1r = (const float*)d_in[1];
    const float* w1i = (const float*)d_in[2];
    const float* b1r = (const float*)d_in[3];
    const float* b1i = (const float*)d_in[4];
    const float* w2r = (const float*)d_in[5];
    const float* w2i = (const float*)d_in[6];
    const float* b2r = (const float*)d_in[7];
    const float* b2i = (const float*)d_in[8];
    const float* fw  = (const float*)d_in[9];
    float* out = (float*)d_out;

    char* ws = (char*)d_ws;
    float2* zm          = (float2*)ws;                         // [0, 34.6MB)
    unsigned short* ybf = (unsigned short*)(ws + 34603008);    // dead after k_tr
    unsigned short* yt  = (unsigned short*)(ws + 101711872);   // [101.7MB, 168.8MB)
    unsigned short* fb  = (unsigned short*)(ws + 34603008);    // written after k_tr
    _Float16* tw        = (_Float16*)(ws + 168665088);         // tail of yt region

    k_tw<<<32, 256, 0, stream>>>(tw);
    k_fwdm<<<2048, 256, 0, stream>>>(x, tw, zm);
    k_mlp<<<dim3(33, 8, 4), 256, 0, stream>>>(w1r, w1i, b1r, b1i,
                                              w2r, w2i, b2r, b2i, zm);
    k_inv<<<2048, 256, 0, stream>>>(zm, x, tw, ybf);
    k_tr<<<dim3(256, 8, 4), 256, 0, stream>>>(ybf, yt);
    k_prep<<<256, 256, 0, stream>>>(fw, fb);
    k_gemm<<<dim3(128, 4, 4), 256, 0, stream>>>(fb, yt, x, out);
}

// Round 8
// 508.400 us; speedup vs baseline: 2.2205x; 1.0379x over previous
//
#include <hip/hip_runtime.h>
#include <math.h>

// AFNO2D: out = x + fuse_w @ (x + irfft2(masked_delta))
// masked_delta = (softshrink(W2*gelu(W1*Z+b1)+b2) - Z) on modes [0:64, 0:33].
// Only the 64x33 masked modes are transformed (irfft2(rfft2(x)) == x).
// Forward DFT: fused single kernel, fp16 MFMA vs precomputed twiddle tables.
// Block-diag MLP: fused single kernel (both layers), fp16 MFMA.
// Inverse DFT: fp16 MFMA + coalesced LDS-bounce epilogue.
// Conv: bf16 MFMA GEMM, double-buffered LDS + register prefetch (1 barrier/k-step).
//
// Workspace layout (bytes), peak 168,820,736:
//   zm    @ 0          : B*C*64*33 float2  = 34,603,008  (Z modes, then delta in-place)
//   yy_bf @ 34,603,008 : B*C*128*128 bf16  = 67,108,864  (y = x + D, bf16; dead after k_tr)
//   yy_t  @101,711,872 : B*16384*512 bf16  = 67,108,864  (y transposed [b][p][c])
//   fw_bf @ 34,603,008 : 512*512 bf16      = 524,288     (written after k_tr)
//   tw    @168,665,088 : 77,824 f16        = 155,648     (twiddles; tail of yt region:
//                        only k_tr overwrites it, which runs after k_fwdm/k_inv)
//
// tw f16 offsets: T1c 0, T1s 8192, T1sn 16384, Pt 24576, Qt 32768 (inv, [128][64])
//                 FWr 40960, FWi 47104 ([48][128]); FHc 53248, FHs 61440,
//                 FHsn 69632 ([64][128]).

#define LAMB 0.01f
#define TWO_PI_OVER_128 0.049087385212340517f

typedef __attribute__((ext_vector_type(8))) short s8bf;           // 8 bf16 (4 VGPRs)
typedef __attribute__((ext_vector_type(8))) unsigned short us8;
typedef __attribute__((ext_vector_type(4))) float f32x4;
typedef __attribute__((ext_vector_type(8))) _Float16 f16x8;       // 8 f16 (4 VGPRs)

static __device__ __forceinline__ float gelu_exact(float v) {
    return 0.5f * v * (1.0f + erff(v * 0.7071067811865475f));
}
static __device__ __forceinline__ float softshrink01(float v) {
    float a = fabsf(v) - LAMB;
    a = a > 0.0f ? a : 0.0f;
    return v >= 0.0f ? a : -a;
}
static __device__ __forceinline__ unsigned short f2bf(float f) {
    union { float f; unsigned int u; } v; v.f = f;
    unsigned int r = v.u + 0x7FFFu + ((v.u >> 16) & 1u);   // RNE
    return (unsigned short)(r >> 16);
}

// ---------------------------------------------------------------------------
// Kernel 0: precompute all twiddle tables (f16).
// ---------------------------------------------------------------------------
__global__ __launch_bounds__(256) void k_tw(_Float16* __restrict__ tw) {
    const int idx = blockIdx.x * 256 + threadIdx.x;   // 0..8191
    {
        const int h = idx >> 6, r = idx & 63;
        float ss, sc;
        sincosf((float)((h * r) & 127) * TWO_PI_OVER_128, &ss, &sc);
        tw[idx]         = (_Float16)sc;
        tw[8192 + idx]  = (_Float16)ss;
        tw[16384 + idx] = (_Float16)(-ss);
        const float wk = (r == 0) ? 0.5f : 1.0f;
        const float pv = (r <= 32) ? wk * sc * 0.015625f : 0.f;
        const float qv = (r <= 32) ? -wk * ss * 0.015625f : 0.f;
        tw[24576 + idx] = (_Float16)pv;
        tw[32768 + idx] = (_Float16)qv;
    }
    if (idx < 6144) {                                  // FW [48][128]
        const int k = idx >> 7, w = idx & 127;
        float ss, sc;
        sincosf((float)((w * k) & 127) * TWO_PI_OVER_128, &ss, &sc);
        tw[40960 + idx] = (_Float16)(sc * 0.0078125f);
        tw[47104 + idx] = (_Float16)(-ss * 0.0078125f);
    }
    {                                                  // FH [64][128]
        const int r = idx >> 7, h = idx & 127;
        float ss, sc;
        sincosf((float)((r * h) & 127) * TWO_PI_OVER_128, &ss, &sc);
        tw[53248 + idx] = (_Float16)sc;
        tw[61440 + idx] = (_Float16)ss;
        tw[69632 + idx] = (_Float16)(-ss);
    }
}

// ---------------------------------------------------------------------------
// Kernel 1: fused forward rfft2 (masked 64x33 modes) via fp16 MFMA.
// ---------------------------------------------------------------------------
__global__ __launch_bounds__(256) void k_fwdm(const float* __restrict__ x,
                                              const _Float16* __restrict__ tw,
                                              float2* __restrict__ zm) {
    __shared__ _Float16 Xs[16384];   // 32,768 B
    const int bc   = blockIdx.x;
    const int tid  = threadIdx.x;
    const int lane = tid & 63;
    const int wv   = tid >> 6;
    const int m15  = lane & 15;
    const int quad = lane >> 4;

    const _Float16* FWr  = tw + 40960;   // [48][128]
    const _Float16* FWi  = tw + 47104;
    const _Float16* FHc  = tw + 53248;   // [64][128]
    const _Float16* FHs  = tw + 61440;
    const _Float16* FHsn = tw + 69632;

    // ---- stage x -> f16, swizzled: idx = h*128+w ^ ((h&7)<<3)
    const float* xim = x + (size_t)bc * 16384;
    for (int t = tid; t < 2048; t += 256) {
        const int h  = t >> 4;
        const int w0 = (t & 15) * 8;
        float4 a = *(const float4*)&xim[h * 128 + w0];
        float4 b = *(const float4*)&xim[h * 128 + w0 + 4];
        f16x8 v;
        v[0] = (_Float16)a.x; v[1] = (_Float16)a.y;
        v[2] = (_Float16)a.z; v[3] = (_Float16)a.w;
        v[4] = (_Float16)b.x; v[5] = (_Float16)b.y;
        v[6] = (_Float16)b.z; v[7] = (_Float16)b.w;
        *(f16x8*)&Xs[(h * 128 + w0) ^ ((h & 7) << 3)] = v;
    }
    __syncthreads();

    // ---- phase A: m-tiles {2wv, 2wv+1}, n-tiles 0..2, K=128 (w)
    f32x4 yR[2][3], yI[2][3];
    #pragma unroll
    for (int i = 0; i < 2; ++i)
        #pragma unroll
        for (int j = 0; j < 3; ++j) {
            yR[i][j] = (f32x4){0.f, 0.f, 0.f, 0.f};
            yI[i][j] = (f32x4){0.f, 0.f, 0.f, 0.f};
        }
    #pragma unroll
    for (int ks = 0; ks < 4; ++ks) {
        const int ko = ks * 32 + quad * 8;
        f16x8 af[2];
        #pragma unroll
        for (int mt = 0; mt < 2; ++mt) {
            const int h = (wv * 2 + mt) * 16 + m15;
            af[mt] = *(const f16x8*)&Xs[(h * 128 + ko) ^ ((h & 7) << 3)];
        }
        #pragma unroll
        for (int nt = 0; nt < 3; ++nt) {
            const int n = nt * 16 + m15;
            f16x8 br = *(const f16x8*)&FWr[n * 128 + ko];
            f16x8 bi = *(const f16x8*)&FWi[n * 128 + ko];
            #pragma unroll
            for (int mt = 0; mt < 2; ++mt) {
                yR[mt][nt] = __builtin_amdgcn_mfma_f32_16x16x32_f16(af[mt], br, yR[mt][nt], 0, 0, 0);
                yI[mt][nt] = __builtin_amdgcn_mfma_f32_16x16x32_f16(af[mt], bi, yI[mt][nt], 0, 0, 0);
            }
        }
    }
    __syncthreads();             // all phase-A reads of Xs done

    // ---- write Y^T (f16, swizzled): Yr at 0, Yi at 8192; idx=k*128+h ^((k&7)<<3)
    #pragma unroll
    for (int mt = 0; mt < 2; ++mt)
        #pragma unroll
        for (int nt = 0; nt < 3; ++nt)
            #pragma unroll
            for (int r = 0; r < 4; ++r) {
                const int h = (wv * 2 + mt) * 16 + quad * 4 + r;
                const int k = nt * 16 + m15;
                const int si = (k * 128 + h) ^ ((k & 7) << 3);
                Xs[si]        = (_Float16)yR[mt][nt][r];
                Xs[8192 + si] = (_Float16)yI[mt][nt][r];
            }
    __syncthreads();

    // ---- phase B: m-tile = wv (r in [0,64)), n-tiles 0..2, K=128 (h)
    f32x4 zR[3], zI[3];
    #pragma unroll
    for (int j = 0; j < 3; ++j) {
        zR[j] = (f32x4){0.f, 0.f, 0.f, 0.f};
        zI[j] = (f32x4){0.f, 0.f, 0.f, 0.f};
    }
    const int rr = wv * 16 + m15;
    #pragma unroll
    for (int ks = 0; ks < 4; ++ks) {
        const int ko = ks * 32 + quad * 8;
        f16x8 ac  = *(const f16x8*)&FHc[rr * 128 + ko];
        f16x8 as2 = *(const f16x8*)&FHs[rr * 128 + ko];
        f16x8 asn = *(const f16x8*)&FHsn[rr * 128 + ko];
        #pragma unroll
        for (int nt = 0; nt < 3; ++nt) {
            const int n  = nt * 16 + m15;
            const int si = (n * 128 + ko) ^ ((n & 7) << 3);
            f16x8 br = *(const f16x8*)&Xs[si];
            f16x8 bi = *(const f16x8*)&Xs[8192 + si];
            zR[nt] = __builtin_amdgcn_mfma_f32_16x16x32_f16(ac,  br, zR[nt], 0, 0, 0);
            zR[nt] = __builtin_amdgcn_mfma_f32_16x16x32_f16(as2, bi, zR[nt], 0, 0, 0);
            zI[nt] = __builtin_amdgcn_mfma_f32_16x16x32_f16(ac,  bi, zI[nt], 0, 0, 0);
            zI[nt] = __builtin_amdgcn_mfma_f32_16x16x32_f16(asn, br, zI[nt], 0, 0, 0);
        }
    }

    // ---- store Z[r][k], k<33
    float2* zrow = zm + (size_t)bc * 2112;
    #pragma unroll
    for (int nt = 0; nt < 3; ++nt) {
        const int k = nt * 16 + m15;
        if (k < 33) {
            #pragma unroll
            for (int r = 0; r < 4; ++r) {
                const int rw = wv * 16 + quad * 4 + r;
                zrow[rw * 33 + k] = make_float2(zR[nt][r], zI[nt][r]);
            }
        }
    }
}

// ---------------------------------------------------------------------------
// Kernel 2: fused block-diag complex MLP via fp16 MFMA; zm <- delta in place.
// ---------------------------------------------------------------------------
__global__ __launch_bounds__(256) void k_mlp(const float* __restrict__ w1r_g,
                                             const float* __restrict__ w1i_g,
                                             const float* __restrict__ b1r_g,
                                             const float* __restrict__ b1i_g,
                                             const float* __restrict__ w2r_g,
                                             const float* __restrict__ w2i_g,
                                             const float* __restrict__ b2r_g,
                                             const float* __restrict__ b2i_g,
                                             float2* __restrict__ zm) {
    __shared__ _Float16 S[32768];   // 65,536 B
    // f16 offsets in S:
    //  W1R 0, W1I 4096, W1N 8192 (=-W1i), W2R 12288, W2I 16384, W2N 20480,
    //  HR 24576, HI 28672.  W tables are [j][i] (=W^T), swizzled ^((j&7)<<3).
    const int p0  = blockIdx.x * 64;
    const int nb  = blockIdx.y;
    const int b   = blockIdx.z;
    const int tid = threadIdx.x;
    const int lane = tid & 63;
    const int wv   = tid >> 6;
    const int m15  = lane & 15;
    const int quad = lane >> 4;

    // ---- stage W^T as f16 (thread t: column j = t&63, i-block = (t>>6)*16)
    {
        const int j  = tid & 63;
        const int i0 = (tid >> 6) * 16;
        const int swz = (j & 7) << 3;
        #pragma unroll
        for (int tbl = 0; tbl < 4; ++tbl) {
            const float* src = (tbl == 0) ? w1r_g : (tbl == 1) ? w1i_g
                             : (tbl == 2) ? w2r_g : w2i_g;
            src += nb * 4096;
            f16x8 v0, v1, n0, n1;
            #pragma unroll
            for (int ii = 0; ii < 8; ++ii) {
                float a = src[(i0 + ii) * 64 + j];
                float c = src[(i0 + 8 + ii) * 64 + j];
                v0[ii] = (_Float16)a; n0[ii] = (_Float16)(-a);
                v1[ii] = (_Float16)c; n1[ii] = (_Float16)(-c);
            }
            const int base = (tbl == 0) ? 0 : (tbl == 1) ? 4096
                           : (tbl == 2) ? 12288 : 16384;
            *(f16x8*)&S[base + ((j * 64 + i0) ^ swz)]     = v0;
            *(f16x8*)&S[base + ((j * 64 + i0 + 8) ^ swz)] = v1;
            if (tbl == 1) {
                *(f16x8*)&S[8192 + ((j * 64 + i0) ^ swz)]     = n0;
                *(f16x8*)&S[8192 + ((j * 64 + i0 + 8) ^ swz)] = n1;
            } else if (tbl == 3) {
                *(f16x8*)&S[20480 + ((j * 64 + i0) ^ swz)]     = n0;
                *(f16x8*)&S[20480 + ((j * 64 + i0 + 8) ^ swz)] = n1;
            }
        }
    }

    // ---- layer-1 A-frags straight from global: Z[p][i], p=p0+wv*16+m15
    const float2* zb = zm + (size_t)(b * 512 + nb * 64) * 2112;
    const int p = p0 + wv * 16 + m15;
    f16x8 azr[2], azi[2];
    #pragma unroll
    for (int ks = 0; ks < 2; ++ks) {
        #pragma unroll
        for (int jj = 0; jj < 8; ++jj) {
            float2 z = zb[(size_t)(ks * 32 + quad * 8 + jj) * 2112 + p];
            azr[ks][jj] = (_Float16)z.x;
            azi[ks][jj] = (_Float16)z.y;
        }
    }
    __syncthreads();   // W tables staged

    // ---- layer 1 MFMA: Hr = Zr@W1r + Zi@W1n ; Hi = Zr@W1i + Zi@W1r
    f32x4 hr[4], hi[4];
    #pragma unroll
    for (int nt = 0; nt < 4; ++nt) {
        hr[nt] = (f32x4){0.f, 0.f, 0.f, 0.f};
        hi[nt] = (f32x4){0.f, 0.f, 0.f, 0.f};
    }
    #pragma unroll
    for (int ks = 0; ks < 2; ++ks) {
        #pragma unroll
        for (int nt = 0; nt < 4; ++nt) {
            const int n  = nt * 16 + m15;
            const int sb = (n * 64 + ks * 32 + quad * 8) ^ ((n & 7) << 3);
            f16x8 bwr = *(const f16x8*)&S[sb];
            f16x8 bwi = *(const f16x8*)&S[4096 + sb];
            f16x8 bwn = *(const f16x8*)&S[8192 + sb];
            hr[nt] = __builtin_amdgcn_mfma_f32_16x16x32_f16(azr[ks], bwr, hr[nt], 0, 0, 0);
            hr[nt] = __builtin_amdgcn_mfma_f32_16x16x32_f16(azi[ks], bwn, hr[nt], 0, 0, 0);
            hi[nt] = __builtin_amdgcn_mfma_f32_16x16x32_f16(azr[ks], bwi, hi[nt], 0, 0, 0);
            hi[nt] = __builtin_amdgcn_mfma_f32_16x16x32_f16(azi[ks], bwr, hi[nt], 0, 0, 0);
        }
    }

    // ---- bias + exact GELU -> H (f16, [m][j] swizzled; wave-local rows)
    #pragma unroll
    for (int nt = 0; nt < 4; ++nt) {
        const int jj = nt * 16 + m15;
        const float br = b1r_g[nb * 64 + jj];
        const float bi = b1i_g[nb * 64 + jj];
        #pragma unroll
        for (int r = 0; r < 4; ++r) {
            const int m  = wv * 16 + quad * 4 + r;
            const int si = (m * 64 + jj) ^ ((m & 7) << 3);
            S[24576 + si] = (_Float16)gelu_exact(hr[nt][r] + br);
            S[28672 + si] = (_Float16)gelu_exact(hi[nt][r] + bi);
        }
    }
    __syncthreads();

    // ---- layer-2 A-frags from LDS H
    f16x8 ahr[2], ahi[2];
    #pragma unroll
    for (int ks = 0; ks < 2; ++ks) {
        const int m  = wv * 16 + m15;
        const int sa = (m * 64 + ks * 32 + quad * 8) ^ ((m & 7) << 3);
        ahr[ks] = *(const f16x8*)&S[24576 + sa];
        ahi[ks] = *(const f16x8*)&S[28672 + sa];
    }

    // ---- layer 2 MFMA: Yr = Hr@W2r + Hi@W2n ; Yi = Hr@W2i + Hi@W2r
    f32x4 yr[4], yi[4];
    #pragma unroll
    for (int nt = 0; nt < 4; ++nt) {
        yr[nt] = (f32x4){0.f, 0.f, 0.f, 0.f};
        yi[nt] = (f32x4){0.f, 0.f, 0.f, 0.f};
    }
    #pragma unroll
    for (int ks = 0; ks < 2; ++ks) {
        #pragma unroll
        for (int nt = 0; nt < 4; ++nt) {
            const int n  = nt * 16 + m15;
            const int sb = (n * 64 + ks * 32 + quad * 8) ^ ((n & 7) << 3);
            f16x8 bwr = *(const f16x8*)&S[12288 + sb];
            f16x8 bwi = *(const f16x8*)&S[16384 + sb];
            f16x8 bwn = *(const f16x8*)&S[20480 + sb];
            yr[nt] = __builtin_amdgcn_mfma_f32_16x16x32_f16(ahr[ks], bwr, yr[nt], 0, 0, 0);
            yr[nt] = __builtin_amdgcn_mfma_f32_16x16x32_f16(ahi[ks], bwn, yr[nt], 0, 0, 0);
            yi[nt] = __builtin_amdgcn_mfma_f32_16x16x32_f16(ahr[ks], bwi, yi[nt], 0, 0, 0);
            yi[nt] = __builtin_amdgcn_mfma_f32_16x16x32_f16(ahi[ks], bwr, yi[nt], 0, 0, 0);
        }
    }

    // ---- epilogue: bias, softshrink, delta = ss(y) - z; write zm in place
    float2* zw = zm + (size_t)(b * 512 + nb * 64) * 2112;
    #pragma unroll
    for (int nt = 0; nt < 4; ++nt) {
        const int jj = nt * 16 + m15;
        const float br = b2r_g[nb * 64 + jj];
        const float bi = b2i_g[nb * 64 + jj];
        #pragma unroll
        for (int r = 0; r < 4; ++r) {
            const int pp = p0 + wv * 16 + quad * 4 + r;
            const size_t gi = (size_t)jj * 2112 + pp;
            float2 z = zw[gi];
            zw[gi] = make_float2(softshrink01(yr[nt][r] + br) - z.x,
                                 softshrink01(yi[nt][r] + bi) - z.y);
        }
    }
}

// ---------------------------------------------------------------------------
// Kernel 3: inverse irfft2 on masked modes via fp16 MFMA; yy_bf = bf16(x + y).
// ---------------------------------------------------------------------------
__global__ __launch_bounds__(256) void k_inv(const float2* __restrict__ zm,
                                             const float* __restrict__ x,
                                             const _Float16* __restrict__ tw,
                                             unsigned short* __restrict__ yb) {
    __shared__ char SB[33792];       // max(32768 f16 region, 64*132*4 bounce)
    _Float16* Sh = (_Float16*)SB;    // 16384 f16
    float*    Sb = (float*)SB;       // bounce [64][132]
    const int bc   = blockIdx.x;
    const int tid  = threadIdx.x;
    const int lane = tid & 63;
    const int wv   = tid >> 6;
    const int m15  = lane & 15;
    const int quad = lane >> 4;

    const _Float16* T1c  = tw;            // [128][64]
    const _Float16* T1s  = tw + 8192;
    const _Float16* T1sn = tw + 16384;
    const _Float16* Pt   = tw + 24576;    // [128][64]
    const _Float16* Qt   = tw + 32768;

    // ---- zero D^T staging region: Dr_T,Di_T = 2 x [48][64] f16 = 12,288 B
    for (int t = tid; t < 768; t += 256)
        *(float4*)&Sh[t * 8] = (float4){0.f, 0.f, 0.f, 0.f};
    __syncthreads();

    // ---- stage D^T as f16 (rows = k-col, XOR swizzle keeps b128 reads 2-way)
    const float2* src = zm + (size_t)bc * 2112;
    for (int t = tid; t < 2112; t += 256) {
        int r = t / 33;
        int k = t - r * 33;
        float2 d = src[t];
        int sidx = (k * 64 + r) ^ ((k & 7) << 3);
        Sh[sidx]        = (_Float16)d.x;
        Sh[3072 + sidx] = (_Float16)d.y;
    }
    __syncthreads();

    // ---- phase 1 MFMA: wave handles m-tiles {2wv, 2wv+1} x n-tiles 0..2
    f32x4 aR[2][3], aI[2][3];
    #pragma unroll
    for (int i = 0; i < 2; ++i)
        #pragma unroll
        for (int j = 0; j < 3; ++j) {
            aR[i][j] = (f32x4){0.f, 0.f, 0.f, 0.f};
            aI[i][j] = (f32x4){0.f, 0.f, 0.f, 0.f};
        }
    #pragma unroll
    for (int ks = 0; ks < 2; ++ks) {
        const int ko = ks * 32 + quad * 8;
        f16x8 ac[2], ass[2], asn[2];
        #pragma unroll
        for (int mt = 0; mt < 2; ++mt) {
            const int m = (wv * 2 + mt) * 16 + m15;
            ac[mt]  = *(const f16x8*)&T1c[m * 64 + ko];
            ass[mt] = *(const f16x8*)&T1s[m * 64 + ko];
            asn[mt] = *(const f16x8*)&T1sn[m * 64 + ko];
        }
        #pragma unroll
        for (int nt = 0; nt < 3; ++nt) {
            const int n  = nt * 16 + m15;
            const int sb = (n * 64 + ko) ^ ((n & 7) << 3);
            f16x8 br = *(const f16x8*)&Sh[sb];
            f16x8 bi = *(const f16x8*)&Sh[3072 + sb];
            #pragma unroll
            for (int mt = 0; mt < 2; ++mt) {
                aR[mt][nt] = __builtin_amdgcn_mfma_f32_16x16x32_f16(ac[mt],  br, aR[mt][nt], 0, 0, 0);
                aR[mt][nt] = __builtin_amdgcn_mfma_f32_16x16x32_f16(asn[mt], bi, aR[mt][nt], 0, 0, 0);
                aI[mt][nt] = __builtin_amdgcn_mfma_f32_16x16x32_f16(ac[mt],  bi, aI[mt][nt], 0, 0, 0);
                aI[mt][nt] = __builtin_amdgcn_mfma_f32_16x16x32_f16(ass[mt], br, aI[mt][nt], 0, 0, 0);
            }
        }
    }
    __syncthreads();

    // ---- zero T region (full 32,768 B; cols 48..63 must be 0)
    for (int t = tid; t < 2048; t += 256)
        *(float4*)&Sh[t * 8] = (float4){0.f, 0.f, 0.f, 0.f};
    __syncthreads();

    // ---- write T (f16, swizzled): Tr at 0, Ti at f16-offset 8192.
    #pragma unroll
    for (int mt = 0; mt < 2; ++mt)
        #pragma unroll
        for (int nt = 0; nt < 3; ++nt)
            #pragma unroll
            for (int r = 0; r < 4; ++r) {
                const int h  = (wv * 2 + mt) * 16 + quad * 4 + r;
                const int k  = nt * 16 + m15;
                const int si = (h * 64 + k) ^ ((h & 7) << 3);
                Sh[si]        = (_Float16)aR[mt][nt][r];
                Sh[8192 + si] = (_Float16)aI[mt][nt][r];
            }
    __syncthreads();

    // ---- pre-read ALL phase-2 A-frags (both m-tiles) so T region can be
    // reused as the f32 bounce. __syncthreads drains lgkm -> reads complete.
    f16x8 atr[2][2], ati[2][2];   // [mt][ks]
    #pragma unroll
    for (int mt = 0; mt < 2; ++mt) {
        const int hh = (wv * 2 + mt) * 16 + m15;
        #pragma unroll
        for (int ks = 0; ks < 2; ++ks) {
            const int sa = (hh * 64 + ks * 32 + quad * 8) ^ ((hh & 7) << 3);
            atr[mt][ks] = *(const f16x8*)&Sh[sa];
            ati[mt][ks] = *(const f16x8*)&Sh[8192 + sa];
        }
    }
    __syncthreads();

    // ---- phase 2 per m-tile: MFMA -> bounce strip -> coalesced epilogue
    const size_t base = (size_t)bc * 16384;
    #pragma unroll
    for (int mt = 0; mt < 2; ++mt) {
        f32x4 acc[8];
        #pragma unroll
        for (int nt = 0; nt < 8; ++nt) acc[nt] = (f32x4){0.f, 0.f, 0.f, 0.f};
        #pragma unroll
        for (int ks = 0; ks < 2; ++ks) {
            #pragma unroll
            for (int nt = 0; nt < 8; ++nt) {
                const int go = (nt * 16 + m15) * 64 + ks * 32 + quad * 8;
                f16x8 bp = *(const f16x8*)&Pt[go];
                f16x8 bq = *(const f16x8*)&Qt[go];
                acc[nt] = __builtin_amdgcn_mfma_f32_16x16x32_f16(atr[mt][ks], bp, acc[nt], 0, 0, 0);
                acc[nt] = __builtin_amdgcn_mfma_f32_16x16x32_f16(ati[mt][ks], bq, acc[nt], 0, 0, 0);
            }
        }
        // bounce write: wave wv's 16 rows at strip rows [wv*16, wv*16+16)
        #pragma unroll
        for (int nt = 0; nt < 8; ++nt)
            #pragma unroll
            for (int r = 0; r < 4; ++r)
                Sb[(wv * 16 + quad * 4 + r) * 132 + nt * 16 + m15] = acc[nt][r];
        __syncthreads();

        // coalesced pass: 64 rows x 128 cols; lane handles 8 consecutive floats
        for (int it = 0; it < 4; ++it) {
            const int off = (it * 256 + tid) * 8;       // 0..8191
            const int rbl = off >> 7;                   // bounce row 0..63
            const int col = off & 127;
            const int h   = ((rbl >> 4) * 2 + mt) * 16 + (rbl & 15);
            const size_t gx = base + (size_t)h * 128 + col;
            float4 s0 = *(const float4*)&Sb[rbl * 132 + col];
            float4 s1 = *(const float4*)&Sb[rbl * 132 + col + 4];
            float4 x0 = *(const float4*)&x[gx];
            float4 x1 = *(const float4*)&x[gx + 4];
            us8 o;
            o[0] = f2bf(x0.x + s0.x); o[1] = f2bf(x0.y + s0.y);
            o[2] = f2bf(x0.z + s0.z); o[3] = f2bf(x0.w + s0.w);
            o[4] = f2bf(x1.x + s1.x); o[5] = f2bf(x1.y + s1.y);
            o[6] = f2bf(x1.z + s1.z); o[7] = f2bf(x1.w + s1.w);
            *(us8*)&yb[gx] = o;
        }
        __syncthreads();
    }
}

// ---------------------------------------------------------------------------
// Kernel 3b: transpose yy_bf[b][c][p] -> yy_t[b][p][c] (bf16), 64x64 tiles.
// ---------------------------------------------------------------------------
__global__ __launch_bounds__(256) void k_tr(const unsigned short* __restrict__ yb,
                                            unsigned short* __restrict__ yt) {
    __shared__ float ts[64][65];   // [p][c]
    const int p0 = blockIdx.x * 64;
    const int c0 = blockIdx.y * 64;
    const int b  = blockIdx.z;
    const int t  = threadIdx.x;
    const int lane = t & 63;

    const unsigned short* src = yb + (((size_t)(b * 512 + c0 + lane)) << 14) + p0;
    #pragma unroll
    for (int cc = 0; cc < 2; ++cc) {
        int ch = (t >> 6) * 2 + cc;          // p-chunk 0..7
        us8 v = *(const us8*)&src[ch * 8];
        #pragma unroll
        for (int j = 0; j < 8; ++j)
            ts[ch * 8 + j][lane] = __uint_as_float((unsigned)v[j] << 16);
    }
    __syncthreads();

    const int pr   = t >> 2;
    const int coff = (t & 3) * 16;
    us8 o0v, o1v;
    #pragma unroll
    for (int i = 0; i < 8; ++i) o0v[i] = f2bf(ts[pr][coff + i]);
    #pragma unroll
    for (int i = 0; i < 8; ++i) o1v[i] = f2bf(ts[pr][coff + 8 + i]);
    unsigned short* dst = yt + ((size_t)(b * 16384 + p0 + pr)) * 512 + c0 + coff;
    *(us8*)&dst[0] = o0v;
    *(us8*)&dst[8] = o1v;
}

// ---------------------------------------------------------------------------
// Kernel 3c: fw fp32 -> bf16 (row-major [o][c] unchanged).
// ---------------------------------------------------------------------------
__global__ __launch_bounds__(256) void k_prep(const float* __restrict__ fw,
                                              unsigned short* __restrict__ fb) {
    int i = (blockIdx.x * 256 + threadIdx.x) * 4;
    float4 v = *(const float4*)&fw[i];
    ushort4 o;
    o.x = f2bf(v.x); o.y = f2bf(v.y); o.z = f2bf(v.z); o.w = f2bf(v.w);
    *(ushort4*)&fb[i] = o;
}

// ---------------------------------------------------------------------------
// Kernel 4: MFMA conv GEMM. out[b][o][p] = x[b][o][p] + sum_c fb[o][c]*yt[b][p][c]
// 128x128 tile, BK=32, 4 waves (2x2 of 64x64), mfma_f32_16x16x32_bf16.
// v2: double-buffered LDS + register prefetch -> ONE barrier per k-step; loads
// for tile t+1 stay in flight under tile-t MFMAs (round-7 counters: all-idle
// latency-bound, 2 barriers/step with vmcnt(0) drain was the critical path).
// LDS [128][32] shorts per matrix per buffer, 16B-slot XOR swizzle
// (slot ^= row&3): frag reads 2-way bank aliasing (free), no pad.
// ---------------------------------------------------------------------------
__global__ __launch_bounds__(256) void k_gemm(const unsigned short* __restrict__ fb,
                                              const unsigned short* __restrict__ yt,
                                              const float* __restrict__ x,
                                              float* __restrict__ out) {
    __shared__ short Al[2][128 * 32];
    __shared__ short Bl[2][128 * 32];
    const int p0  = blockIdx.x * 128;
    const int o0  = blockIdx.y * 128;
    const int b   = blockIdx.z;
    const int tid = threadIdx.x;
    const int lane = tid & 63;
    const int w    = tid >> 6;
    const int wo = (w >> 1) * 64, wp = (w & 1) * 64;

    f32x4 acc[4][4];
    #pragma unroll
    for (int i = 0; i < 4; ++i)
        #pragma unroll
        for (int j = 0; j < 4; ++j)
            acc[i][j] = (f32x4){0.f, 0.f, 0.f, 0.f};

    const int m15 = lane & 15, quad = lane >> 4;

    // staging geometry: thread covers rows r0 and r0+64, 16B part pt.
    const int r0 = tid >> 2;          // 0..63
    const int pt = tid & 3;           // 0..3
    const int sw = (pt ^ (r0 & 3)) * 8;               // swizzled slot (shorts)
    const size_t gA0 = (size_t)(o0 + r0) * 512 + pt * 8;
    const size_t gA1 = (size_t)(o0 + r0 + 64) * 512 + pt * 8;
    const size_t gB0 = ((size_t)(b * 16384 + p0 + r0)) * 512 + pt * 8;
    const size_t gB1 = ((size_t)(b * 16384 + p0 + r0 + 64)) * 512 + pt * 8;
    const int l0 = r0 * 32 + sw;                      // (r0+64)&3 == r0&3
    const int l1 = (r0 + 64) * 32 + sw;

    s8bf ra0, ra1, rb0, rb1;

    // prologue: tile 0
    ra0 = *(const s8bf*)&fb[gA0];
    ra1 = *(const s8bf*)&fb[gA1];
    rb0 = *(const s8bf*)&yt[gB0];
    rb1 = *(const s8bf*)&yt[gB1];
    *(s8bf*)&Al[0][l0] = ra0;  *(s8bf*)&Al[0][l1] = ra1;
    *(s8bf*)&Bl[0][l0] = rb0;  *(s8bf*)&Bl[0][l1] = rb1;
    __syncthreads();

    int cur = 0;
    for (int t = 0; t < 16; ++t) {
        if (t < 15) {                 // issue next-tile loads (in flight under MFMA)
            const int kc = (t + 1) * 32;
            ra0 = *(const s8bf*)&fb[gA0 + kc];
            ra1 = *(const s8bf*)&fb[gA1 + kc];
            rb0 = *(const s8bf*)&yt[gB0 + kc];
            rb1 = *(const s8bf*)&yt[gB1 + kc];
        }

        s8bf af[4], bfr[4];
        #pragma unroll
        for (int i = 0; i < 4; ++i) {
            const int ra = wo + i * 16 + m15;
            const int rb = wp + i * 16 + m15;
            af[i]  = *(const s8bf*)&Al[cur][ra * 32 + ((quad ^ (ra & 3)) * 8)];
            bfr[i] = *(const s8bf*)&Bl[cur][rb * 32 + ((quad ^ (rb & 3)) * 8)];
        }
        #pragma unroll
        for (int mi = 0; mi < 4; ++mi)
            #pragma unroll
            for (int ni = 0; ni < 4; ++ni)
                acc[mi][ni] = __builtin_amdgcn_mfma_f32_16x16x32_bf16(
                    af[mi], bfr[ni], acc[mi][ni], 0, 0, 0);

        if (t < 15) {                 // land next tile in the other buffer
            const int nx = cur ^ 1;
            *(s8bf*)&Al[nx][l0] = ra0;  *(s8bf*)&Al[nx][l1] = ra1;
            *(s8bf*)&Bl[nx][l0] = rb0;  *(s8bf*)&Bl[nx][l1] = rb1;
            __syncthreads();
            cur = nx;
        }
    }

    #pragma unroll
    for (int mi = 0; mi < 4; ++mi) {
        #pragma unroll
        for (int ni = 0; ni < 4; ++ni) {
            #pragma unroll
            for (int r = 0; r < 4; ++r) {
                int o = o0 + wo + mi * 16 + quad * 4 + r;
                int p = p0 + wp + ni * 16 + m15;
                size_t idx = (((size_t)(b * 512 + o)) << 14) + p;
                out[idx] = x[idx] + acc[mi][ni][r];
            }
        }
    }
}

// ---------------------------------------------------------------------------
extern "C" void kernel_launch(void* const* d_in, const int* in_sizes, int n_in,
                              void* d_out, int out_size, void* d_ws, size_t ws_size,
                              hipStream_t stream) {
    const float* x   = (const float*)d_in[0];
    const float* w1r = (const float*)d_in[1];
    const float* w1i = (const float*)d_in[2];
    const float* b1r = (const float*)d_in[3];
    const float* b1i = (const float*)d_in[4];
    const float* w2r = (const float*)d_in[5];
    const float* w2i = (const float*)d_in[6];
    const float* b2r = (const float*)d_in[7];
    const float* b2i = (const float*)d_in[8];
    const float* fw  = (const float*)d_in[9];
    float* out = (float*)d_out;

    char* ws = (char*)d_ws;
    float2* zm          = (float2*)ws;                         // [0, 34.6MB)
    unsigned short* ybf = (unsigned short*)(ws + 34603008);    // dead after k_tr
    unsigned short* yt  = (unsigned short*)(ws + 101711872);   // [101.7MB, 168.8MB)
    unsigned short* fb  = (unsigned short*)(ws + 34603008);    // written after k_tr
    _Float16* tw        = (_Float16*)(ws + 168665088);         // tail of yt region

    k_tw<<<32, 256, 0, stream>>>(tw);
    k_fwdm<<<2048, 256, 0, stream>>>(x, tw, zm);
    k_mlp<<<dim3(33, 8, 4), 256, 0, stream>>>(w1r, w1i, b1r, b1i,
                                              w2r, w2i, b2r, b2i, zm);
    k_inv<<<2048, 256, 0, stream>>>(zm, x, tw, ybf);
    k_tr<<<dim3(256, 8, 4), 256, 0, stream>>>(ybf, yt);
    k_prep<<<256, 256, 0, stream>>>(fw, fb);
    k_gemm<<<dim3(128, 4, 4), 256, 0, stream>>>(fb, yt, x, out);
}